// Round 4
// baseline (564.907 us; speedup 1.0000x reference)
//
#include <hip/hip_runtime.h>
#include <math.h>

#define NPTS 32768
#define NB 2
#define CIN 32
#define H 32
#define D 64
#define DOUT 128
#define BN_RS 0.99999500003749981f   // 1/sqrt(1 + 1e-5)

// ---------------- Kernel 1: f_pc = relu(bn(w_mlp1 @ feature)) ----------------
// feature: (B,32,N) channel-major. f_pc out: point-major (B*N, 32).
__global__ __launch_bounds__(256, 4) void k1_mlp1(
    const float* __restrict__ feature, const float* __restrict__ w_mlp1,
    const float* __restrict__ g_mlp1, const float* __restrict__ b_mlp1,
    float* __restrict__ f_pc)
{
    int tid = threadIdx.x;
    int pg = blockIdx.x * 256 + tid;
    int b = pg >> 15, n = pg & (NPTS - 1);

    float x[CIN];
#pragma unroll
    for (int c = 0; c < CIN; ++c)
        x[c] = feature[((b * CIN + c) << 15) + n];

    float outv[CIN];
#pragma unroll
    for (int o = 0; o < CIN; ++o) {
        float s0 = 0.f, s1 = 0.f, s2 = 0.f, s3 = 0.f;
        const float* w = w_mlp1 + o * CIN;   // uniform -> s_load
#pragma unroll
        for (int c = 0; c < CIN; c += 4) {
            s0 = fmaf(w[c + 0], x[c + 0], s0);
            s1 = fmaf(w[c + 1], x[c + 1], s1);
            s2 = fmaf(w[c + 2], x[c + 2], s2);
            s3 = fmaf(w[c + 3], x[c + 3], s3);
        }
        float acc = (s0 + s1) + (s2 + s3);
        outv[o] = fmaxf(fmaf(acc, g_mlp1[o] * BN_RS, b_mlp1[o]), 0.f);
    }
    float4* dst = (float4*)(f_pc + ((size_t)pg << 5));
#pragma unroll
    for (int j = 0; j < CIN / 4; ++j)
        dst[j] = make_float4(outv[4 * j], outv[4 * j + 1], outv[4 * j + 2], outv[4 * j + 3]);
}

// ---------------- Kernel 2: stage-1 building block -> f_agg (B*N, 32) ----------------
// 256 thr = 4 waves; wave = 4 points x 16 neighbors. Block = 16 points.
__global__ __launch_bounds__(256, 4) void k2_stage1(
    const float* __restrict__ xyz, const int* __restrict__ nidx,
    const float* __restrict__ f_pc,
    const float* __restrict__ bb_w1, const float* __restrict__ bb_g1, const float* __restrict__ bb_b1,
    const float* __restrict__ att_fc,
    const float* __restrict__ att_w, const float* __restrict__ att_g, const float* __restrict__ att_b,
    float* __restrict__ f_agg)
{
    __shared__ float awT[D * H];          // folded att_w^T: [c][o]
    __shared__ float aggb[16][D + 1];     // per-point pooled features

    int tid = threadIdx.x;
    for (int i = tid; i < D * H; i += 256) {
        int o = i & (H - 1), c = i >> 5;
        awT[i] = att_w[o * D + c] * (att_g[o] * BN_RS);
    }
    __syncthreads();

    int wid = tid >> 6, lane = tid & 63;
    int p4 = lane >> 4, kk = lane & 15;
    int pt = (wid << 2) + p4;
    int p = (blockIdx.x << 4) + pt;
    int b = p >> 15, n = p & (NPTS - 1);

    int nb = nidx[((size_t)p << 4) + kk];

    float feat[D];
    {   // f_xyz first (keeps peak register liveness low)
        const float* cx = xyz + (size_t)(b * NPTS + n) * 3;
        const float* nx = xyz + (size_t)(b * NPTS + nb) * 3;
        float c0 = cx[0], c1 = cx[1], c2 = cx[2];
        float x0 = nx[0], x1 = nx[1], x2 = nx[2];
        float r0 = c0 - x0, r1 = c1 - x1, r2 = c2 - x2;
        float dist = sqrtf(r0 * r0 + r1 * r1 + r2 * r2);
        float in10[10] = {dist, r0, r1, r2, c0, c1, c2, x0, x1, x2};
#pragma unroll
        for (int c = 0; c < H; ++c) {     // channels 32..63
            float a = 0.f;
            const float* w = bb_w1 + c * 10;  // uniform -> s_load
#pragma unroll
            for (int t = 0; t < 10; ++t) a = fmaf(w[t], in10[t], a);
            feat[H + c] = fmaxf(fmaf(a, bb_g1[c] * BN_RS, bb_b1[c]), 0.f);
        }
    }
    {   // f_nb gather (channels 0..31)
        const float4* src = (const float4*)(f_pc + (((size_t)(b * NPTS + nb)) << 5));
#pragma unroll
        for (int j = 0; j < 8; ++j) {
            float4 v = src[j];
            feat[4 * j + 0] = v.x; feat[4 * j + 1] = v.y;
            feat[4 * j + 2] = v.z; feat[4 * j + 3] = v.w;
        }
    }

    // scores conv + softmax-over-k + pool, fused per output channel o
#pragma unroll
    for (int o = 0; o < D; ++o) {
        float s0 = 0.f, s1 = 0.f, s2 = 0.f, s3 = 0.f;
        const float* w = att_fc + o * D;  // uniform -> s_load
#pragma unroll
        for (int c = 0; c < D; c += 4) {
            s0 = fmaf(w[c + 0], feat[c + 0], s0);
            s1 = fmaf(w[c + 1], feat[c + 1], s1);
            s2 = fmaf(w[c + 2], feat[c + 2], s2);
            s3 = fmaf(w[c + 3], feat[c + 3], s3);
        }
        float e = __expf((s0 + s1) + (s2 + s3));   // logits small: no max-sub needed
        float pe = feat[o] * e;
#pragma unroll
        for (int m = 1; m <= 8; m <<= 1) {
            e  += __shfl_xor(e, m);
            pe += __shfl_xor(pe, m);
        }
        if (kk == (o & 15)) aggb[pt][o] = __fdividef(pe, e);
    }

    // output MLP: lane kk computes o = 2kk, 2kk+1
    float a00 = 0.f, a01 = 0.f, a10 = 0.f, a11 = 0.f;
#pragma unroll
    for (int c = 0; c < D; c += 2) {
        float xv0 = aggb[pt][c], xv1 = aggb[pt][c + 1];
        float2 w0 = ((const float2*)awT)[c * (H / 2) + kk];
        float2 w1 = ((const float2*)awT)[(c + 1) * (H / 2) + kk];
        a00 = fmaf(w0.x, xv0, a00); a01 = fmaf(w0.y, xv0, a01);
        a10 = fmaf(w1.x, xv1, a10); a11 = fmaf(w1.y, xv1, a11);
    }
    float2 bb = ((const float2*)att_b)[kk];
    float v0 = fmaxf(a00 + a10 + bb.x, 0.f);
    float v1 = fmaxf(a01 + a11 + bb.y, 0.f);
    ((float2*)(f_agg + ((size_t)p << 5)))[kk] = make_float2(v0, v1);
}

// ---------------- Kernel 3: stage-2 building block -> f_agg2 point-major (B*N, 64) ----------------
__global__ __launch_bounds__(256, 3) void k3_stage2(
    const float* __restrict__ xyz, const int* __restrict__ nidx,
    const float* __restrict__ f_agg,
    const float* __restrict__ bb_w1, const float* __restrict__ bb_g1, const float* __restrict__ bb_b1,
    const float* __restrict__ bb_w2, const float* __restrict__ bb_g2, const float* __restrict__ bb_b2,
    const float* __restrict__ att_fc,
    const float* __restrict__ att_w, const float* __restrict__ att_g, const float* __restrict__ att_b,
    float* __restrict__ fagg2)
{
    __shared__ float awT[D * D];          // folded att2_w^T: [c][o]
    __shared__ float aggb[16][D + 1];

    int tid = threadIdx.x;
    for (int i = tid; i < D * D; i += 256) {
        int o = i & (D - 1), c = i >> 6;
        awT[i] = att_w[o * D + c] * (att_g[o] * BN_RS);
    }
    __syncthreads();

    int wid = tid >> 6, lane = tid & 63;
    int p4 = lane >> 4, kk = lane & 15;
    int pt = (wid << 2) + p4;
    int p = (blockIdx.x << 4) + pt;
    int b = p >> 15, n = p & (NPTS - 1);

    int nb = nidx[((size_t)p << 4) + kk];

    float feat[D];
    {   // rel-pos + bb_w1 + bb_w2 first (fx dies before gather)
        const float* cx = xyz + (size_t)(b * NPTS + n) * 3;
        const float* nx = xyz + (size_t)(b * NPTS + nb) * 3;
        float c0 = cx[0], c1 = cx[1], c2 = cx[2];
        float x0 = nx[0], x1 = nx[1], x2 = nx[2];
        float r0 = c0 - x0, r1 = c1 - x1, r2 = c2 - x2;
        float dist = sqrtf(r0 * r0 + r1 * r1 + r2 * r2);
        float in10[10] = {dist, r0, r1, r2, c0, c1, c2, x0, x1, x2};

        float fx[H];
#pragma unroll
        for (int c = 0; c < H; ++c) {
            float a = 0.f;
            const float* w = bb_w1 + c * 10;
#pragma unroll
            for (int t = 0; t < 10; ++t) a = fmaf(w[t], in10[t], a);
            fx[c] = fmaxf(fmaf(a, bb_g1[c] * BN_RS, bb_b1[c]), 0.f);
        }
        // f_xyz2 = relu(bn(bb_w2 @ fx)) (channels 32..63)
#pragma unroll
        for (int j = 0; j < H; ++j) {
            float s0 = 0.f, s1 = 0.f, s2 = 0.f, s3 = 0.f;
            const float* w = bb_w2 + j * H;
#pragma unroll
            for (int c = 0; c < H; c += 4) {
                s0 = fmaf(w[c + 0], fx[c + 0], s0);
                s1 = fmaf(w[c + 1], fx[c + 1], s1);
                s2 = fmaf(w[c + 2], fx[c + 2], s2);
                s3 = fmaf(w[c + 3], fx[c + 3], s3);
            }
            float a = (s0 + s1) + (s2 + s3);
            feat[H + j] = fmaxf(fmaf(a, bb_g2[j] * BN_RS, bb_b2[j]), 0.f);
        }
    }
    {   // f_nb2 gather from f_agg (channels 0..31)
        const float4* src = (const float4*)(f_agg + (((size_t)(b * NPTS + nb)) << 5));
#pragma unroll
        for (int j = 0; j < 8; ++j) {
            float4 v = src[j];
            feat[4 * j + 0] = v.x; feat[4 * j + 1] = v.y;
            feat[4 * j + 2] = v.z; feat[4 * j + 3] = v.w;
        }
    }

    // scores conv (att2_fc) + softmax + pool
#pragma unroll
    for (int o = 0; o < D; ++o) {
        float s0 = 0.f, s1 = 0.f, s2 = 0.f, s3 = 0.f;
        const float* w = att_fc + o * D;
#pragma unroll
        for (int c = 0; c < D; c += 4) {
            s0 = fmaf(w[c + 0], feat[c + 0], s0);
            s1 = fmaf(w[c + 1], feat[c + 1], s1);
            s2 = fmaf(w[c + 2], feat[c + 2], s2);
            s3 = fmaf(w[c + 3], feat[c + 3], s3);
        }
        float e = __expf((s0 + s1) + (s2 + s3));
        float pe = feat[o] * e;
#pragma unroll
        for (int m = 1; m <= 8; m <<= 1) {
            e  += __shfl_xor(e, m);
            pe += __shfl_xor(pe, m);
        }
        if (kk == (o & 15)) aggb[pt][o] = __fdividef(pe, e);
    }

    // output MLP: lane kk computes o = 4kk..4kk+3
    float a0 = 0.f, a1 = 0.f, a2 = 0.f, a3 = 0.f;
#pragma unroll
    for (int c = 0; c < D; ++c) {
        float xv = aggb[pt][c];
        float4 w4 = ((const float4*)awT)[c * (D / 4) + kk];
        a0 = fmaf(w4.x, xv, a0); a1 = fmaf(w4.y, xv, a1);
        a2 = fmaf(w4.z, xv, a2); a3 = fmaf(w4.w, xv, a3);
    }
    float4 bb = ((const float4*)att_b)[kk];
    float4 r;
    r.x = fmaxf(a0 + bb.x, 0.f);
    r.y = fmaxf(a1 + bb.y, 0.f);
    r.z = fmaxf(a2 + bb.z, 0.f);
    r.w = fmaxf(a3 + bb.w, 0.f);
    ((float4*)(fagg2 + ((size_t)p << 6)))[kk] = r;
}

// ---------------- Kernel 4: out = leaky(bn(mlp2@f_agg2) + bn(sc@feature)) ----------------
// Grid = 1024 blocks: (256 point-tiles of 256 pts) x (4 output-quarters).
// Thread = one point; o depends only on blockIdx + loop counter -> s_load weights.
__global__ __launch_bounds__(256) void k4_final(
    const float* __restrict__ fagg2, const float* __restrict__ feature,
    const float* __restrict__ w_mlp2, const float* __restrict__ g_mlp2, const float* __restrict__ b_mlp2,
    const float* __restrict__ w_sc, const float* __restrict__ g_sc, const float* __restrict__ b_sc,
    float* __restrict__ out)
{
    int tid = threadIdx.x;
    int gb = blockIdx.x;
    int o0 = (gb & 3) << 5;                 // 0,32,64,96 — uniform (SGPR)
    int p  = ((gb >> 2) << 8) + tid;
    int b = p >> 15, n = p & (NPTS - 1);

    float xr[D];
    {
        const float4* src = (const float4*)(fagg2 + ((size_t)p << 6));
#pragma unroll
        for (int j = 0; j < D / 4; ++j) {
            float4 v = src[j];
            xr[4 * j + 0] = v.x; xr[4 * j + 1] = v.y;
            xr[4 * j + 2] = v.z; xr[4 * j + 3] = v.w;
        }
    }
    float xf[CIN];
#pragma unroll
    for (int c = 0; c < CIN; ++c)
        xf[c] = feature[((b * CIN + c) << 15) + n];

#pragma unroll 4
    for (int j = 0; j < 32; ++j) {
        int o = o0 + j;                     // uniform -> s_load weight rows
        float s0 = 0.f, s1 = 0.f, s2 = 0.f, s3 = 0.f;
        const float* wm = w_mlp2 + o * D;
#pragma unroll
        for (int c = 0; c < D; c += 4) {
            s0 = fmaf(wm[c + 0], xr[c + 0], s0);
            s1 = fmaf(wm[c + 1], xr[c + 1], s1);
            s2 = fmaf(wm[c + 2], xr[c + 2], s2);
            s3 = fmaf(wm[c + 3], xr[c + 3], s3);
        }
        float aA = (s0 + s1) + (s2 + s3);
        float t0 = 0.f, t1 = 0.f, t2 = 0.f, t3 = 0.f;
        const float* ws = w_sc + o * CIN;
#pragma unroll
        for (int c = 0; c < CIN; c += 4) {
            t0 = fmaf(ws[c + 0], xf[c + 0], t0);
            t1 = fmaf(ws[c + 1], xf[c + 1], t1);
            t2 = fmaf(ws[c + 2], xf[c + 2], t2);
            t3 = fmaf(ws[c + 3], xf[c + 3], t3);
        }
        float aB = (t0 + t1) + (t2 + t3);
        float v = fmaf(aA, g_mlp2[o] * BN_RS, b_mlp2[o])
                + fmaf(aB, g_sc[o] * BN_RS, b_sc[o]);
        v = (v >= 0.0f) ? v : 0.2f * v;
        out[((b * DOUT + o) << 15) + n] = v;
    }
}

extern "C" void kernel_launch(void* const* d_in, const int* in_sizes, int n_in,
                              void* d_out, int out_size, void* d_ws, size_t ws_size,
                              hipStream_t stream) {
    const float* feature = (const float*)d_in[0];
    const float* xyz     = (const float*)d_in[1];
    const float* w_mlp1  = (const float*)d_in[2];
    const float* g_mlp1  = (const float*)d_in[3];
    const float* b_mlp1  = (const float*)d_in[4];
    const float* bb_w1   = (const float*)d_in[5];
    const float* bb_g1   = (const float*)d_in[6];
    const float* bb_b1   = (const float*)d_in[7];
    const float* att1_fc = (const float*)d_in[8];
    const float* att1_w  = (const float*)d_in[9];
    const float* att1_g  = (const float*)d_in[10];
    const float* att1_b  = (const float*)d_in[11];
    const float* bb_w2   = (const float*)d_in[12];
    const float* bb_g2   = (const float*)d_in[13];
    const float* bb_b2   = (const float*)d_in[14];
    const float* att2_fc = (const float*)d_in[15];
    const float* att2_w  = (const float*)d_in[16];
    const float* att2_g  = (const float*)d_in[17];
    const float* att2_b  = (const float*)d_in[18];
    const float* w_mlp2  = (const float*)d_in[19];
    const float* g_mlp2  = (const float*)d_in[20];
    const float* b_mlp2  = (const float*)d_in[21];
    const float* w_sc    = (const float*)d_in[22];
    const float* g_sc    = (const float*)d_in[23];
    const float* b_sc    = (const float*)d_in[24];
    const int*   nidx    = (const int*)d_in[25];
    float* out = (float*)d_out;

    float* f_pc  = (float*)d_ws;                   // B*N*32
    float* f_agg = f_pc + (size_t)NB * NPTS * H;   // B*N*32
    float* fagg2 = f_agg + (size_t)NB * NPTS * H;  // B*N*64 point-major

    k1_mlp1<<<NB * NPTS / 256, 256, 0, stream>>>(feature, w_mlp1, g_mlp1, b_mlp1, f_pc);
    k2_stage1<<<NB * NPTS / 16, 256, 0, stream>>>(xyz, nidx, f_pc,
                                                  bb_w1, bb_g1, bb_b1,
                                                  att1_fc, att1_w, att1_g, att1_b, f_agg);
    k3_stage2<<<NB * NPTS / 16, 256, 0, stream>>>(xyz, nidx, f_agg,
                                                  bb_w1, bb_g1, bb_b1,
                                                  bb_w2, bb_g2, bb_b2,
                                                  att2_fc, att2_w, att2_g, att2_b, fagg2);
    k4_final<<<NB * NPTS * 4 / 256, 256, 0, stream>>>(fagg2, feature,
                                                      w_mlp2, g_mlp2, b_mlp2,
                                                      w_sc, g_sc, b_sc, out);
}

// Round 5
// 560.344 us; speedup vs baseline: 1.0081x; 1.0081x over previous
//
#include <hip/hip_runtime.h>
#include <math.h>

#define NPTS 32768
#define NB 2
#define CIN 32
#define H 32
#define D 64
#define DOUT 128
#define BN_RS 0.99999500003749981f   // 1/sqrt(1 + 1e-5)

// ---- macro library: fully static-indexed inner phases (no unroll heuristics) ----

// relative-pos encoding channel c -> DST (uses dist,r0..r2,c0..c2,x0..x2, bb_w1/g1/b1 in scope)
#define FXYZ(c, DST) { const float* w = bb_w1 + (c) * 10;                        \
    float a = w[0] * dist; a = fmaf(w[1], r0, a); a = fmaf(w[2], r1, a);         \
    a = fmaf(w[3], r2, a); a = fmaf(w[4], c0, a); a = fmaf(w[5], c1, a);         \
    a = fmaf(w[6], c2, a); a = fmaf(w[7], x0, a); a = fmaf(w[8], x1, a);         \
    a = fmaf(w[9], x2, a);                                                       \
    DST = fmaxf(fmaf(a, bb_g1[(c)] * BN_RS, bb_b1[(c)]), 0.f); }

// score conv output channel o from FC weights + softmax partial + pool (uses feat[], kk, pt, aggb)
#define SCORE(o, FC) {                                                           \
    const float* w = (FC) + (o) * D;                                             \
    float s0 = w[0]*feat[0], s1 = w[1]*feat[1], s2 = w[2]*feat[2], s3 = w[3]*feat[3]; \
    _Pragma("unroll")                                                            \
    for (int c = 4; c < D; c += 4) {                                             \
        s0 = fmaf(w[c+0], feat[c+0], s0);                                        \
        s1 = fmaf(w[c+1], feat[c+1], s1);                                        \
        s2 = fmaf(w[c+2], feat[c+2], s2);                                        \
        s3 = fmaf(w[c+3], feat[c+3], s3);                                        \
    }                                                                            \
    float e = __expf((s0 + s1) + (s2 + s3));                                     \
    float pe = feat[(o)] * e;                                                    \
    e  += __shfl_xor(e, 1);  pe += __shfl_xor(pe, 1);                            \
    e  += __shfl_xor(e, 2);  pe += __shfl_xor(pe, 2);                            \
    e  += __shfl_xor(e, 4);  pe += __shfl_xor(pe, 4);                            \
    e  += __shfl_xor(e, 8);  pe += __shfl_xor(pe, 8);                            \
    if (kk == ((o) & 15)) aggb[pt][(o)] = __fdividef(pe, e); }
#define SC4(o, FC)  SCORE(o, FC) SCORE((o)+1, FC) SCORE((o)+2, FC) SCORE((o)+3, FC)
#define SC16(o, FC) SC4(o, FC) SC4((o)+4, FC) SC4((o)+8, FC) SC4((o)+12, FC)

// k3: f_xyz2 channel j = relu(bn(bb_w2 @ fx))
#define FX2(j) { const float* w = bb_w2 + (j) * H;                               \
    float s0 = w[0]*fx[0], s1 = w[1]*fx[1], s2 = w[2]*fx[2], s3 = w[3]*fx[3];    \
    _Pragma("unroll")                                                            \
    for (int c = 4; c < H; c += 4) {                                             \
        s0 = fmaf(w[c+0], fx[c+0], s0);                                          \
        s1 = fmaf(w[c+1], fx[c+1], s1);                                          \
        s2 = fmaf(w[c+2], fx[c+2], s2);                                          \
        s3 = fmaf(w[c+3], fx[c+3], s3);                                          \
    }                                                                            \
    feat[H + (j)] = fmaxf(fmaf((s0+s1)+(s2+s3), bb_g2[(j)] * BN_RS, bb_b2[(j)]), 0.f); }
#define FX2x4(j) FX2(j) FX2((j)+1) FX2((j)+2) FX2((j)+3)

// ---------------- Kernel 1: f_pc = relu(bn(w_mlp1 @ feature)) ----------------
__global__ __launch_bounds__(256, 4) void k1_mlp1(
    const float* __restrict__ feature, const float* __restrict__ w_mlp1,
    const float* __restrict__ g_mlp1, const float* __restrict__ b_mlp1,
    float* __restrict__ f_pc)
{
    int tid = threadIdx.x;
    int pg = blockIdx.x * 256 + tid;
    int b = pg >> 15, n = pg & (NPTS - 1);

    float x[CIN];
#pragma unroll
    for (int c = 0; c < CIN; ++c)
        x[c] = feature[((b * CIN + c) << 15) + n];

    float outv[CIN];
#pragma unroll
    for (int o = 0; o < CIN; ++o) {
        float s0 = 0.f, s1 = 0.f, s2 = 0.f, s3 = 0.f;
        const float* w = w_mlp1 + o * CIN;
#pragma unroll
        for (int c = 0; c < CIN; c += 4) {
            s0 = fmaf(w[c + 0], x[c + 0], s0);
            s1 = fmaf(w[c + 1], x[c + 1], s1);
            s2 = fmaf(w[c + 2], x[c + 2], s2);
            s3 = fmaf(w[c + 3], x[c + 3], s3);
        }
        float acc = (s0 + s1) + (s2 + s3);
        outv[o] = fmaxf(fmaf(acc, g_mlp1[o] * BN_RS, b_mlp1[o]), 0.f);
    }
    float4* dst = (float4*)(f_pc + ((size_t)pg << 5));
#pragma unroll
    for (int j = 0; j < CIN / 4; ++j)
        dst[j] = make_float4(outv[4 * j], outv[4 * j + 1], outv[4 * j + 2], outv[4 * j + 3]);
}

// ---------------- Kernel 2: stage-1 building block -> f_agg (B*N, 32) ----------------
// 256 thr = 4 waves; wave = 4 points x 16 neighbors. Block = 16 points.
__global__ __launch_bounds__(256, 3) void k2_stage1(
    const float* __restrict__ xyz, const int* __restrict__ nidx,
    const float* __restrict__ f_pc,
    const float* __restrict__ bb_w1, const float* __restrict__ bb_g1, const float* __restrict__ bb_b1,
    const float* __restrict__ att_fc,
    const float* __restrict__ att_w, const float* __restrict__ att_g, const float* __restrict__ att_b,
    float* __restrict__ f_agg)
{
    __shared__ float awT[D * H];          // folded att_w^T: [c][o]
    __shared__ float aggb[16][D + 1];

    int tid = threadIdx.x;
    for (int i = tid; i < D * H; i += 256) {
        int o = i & (H - 1), c = i >> 5;
        awT[i] = att_w[o * D + c] * (att_g[o] * BN_RS);
    }
    __syncthreads();

    int wid = tid >> 6, lane = tid & 63;
    int p4 = lane >> 4, kk = lane & 15;
    int pt = (wid << 2) + p4;
    int p = (blockIdx.x << 4) + pt;
    int b = p >> 15, n = p & (NPTS - 1);

    int nb = nidx[((size_t)p << 4) + kk];

    float feat[D];
    {   // f_xyz (channels 32..63), fully static
        const float* cx = xyz + (size_t)(b * NPTS + n) * 3;
        const float* nx = xyz + (size_t)(b * NPTS + nb) * 3;
        float c0 = cx[0], c1 = cx[1], c2 = cx[2];
        float x0 = nx[0], x1 = nx[1], x2 = nx[2];
        float r0 = c0 - x0, r1 = c1 - x1, r2 = c2 - x2;
        float dist = sqrtf(r0 * r0 + r1 * r1 + r2 * r2);
#define FXYZ4F(c) FXYZ(c, feat[H+(c)]) FXYZ((c)+1, feat[H+(c)+1]) FXYZ((c)+2, feat[H+(c)+2]) FXYZ((c)+3, feat[H+(c)+3])
        FXYZ4F(0) FXYZ4F(4) FXYZ4F(8) FXYZ4F(12)
        FXYZ4F(16) FXYZ4F(20) FXYZ4F(24) FXYZ4F(28)
    }
    {   // f_nb gather (channels 0..31)
        const float4* src = (const float4*)(f_pc + (((size_t)(b * NPTS + nb)) << 5));
#pragma unroll
        for (int j = 0; j < 8; ++j) {
            float4 v = src[j];
            feat[4 * j + 0] = v.x; feat[4 * j + 1] = v.y;
            feat[4 * j + 2] = v.z; feat[4 * j + 3] = v.w;
        }
    }

    // scores conv + softmax-over-k + pool: 64 static expansions
    SC16(0, att_fc) SC16(16, att_fc) SC16(32, att_fc) SC16(48, att_fc)

    __syncthreads();

    // output MLP: lane kk computes o = 2kk, 2kk+1
    float a00 = 0.f, a01 = 0.f, a10 = 0.f, a11 = 0.f;
#pragma unroll 8
    for (int c = 0; c < D; c += 2) {
        float xv0 = aggb[pt][c], xv1 = aggb[pt][c + 1];
        float2 w0 = ((const float2*)awT)[c * (H / 2) + kk];
        float2 w1 = ((const float2*)awT)[(c + 1) * (H / 2) + kk];
        a00 = fmaf(w0.x, xv0, a00); a01 = fmaf(w0.y, xv0, a01);
        a10 = fmaf(w1.x, xv1, a10); a11 = fmaf(w1.y, xv1, a11);
    }
    float2 bb = ((const float2*)att_b)[kk];
    float v0 = fmaxf(a00 + a10 + bb.x, 0.f);
    float v1 = fmaxf(a01 + a11 + bb.y, 0.f);
    ((float2*)(f_agg + ((size_t)p << 5)))[kk] = make_float2(v0, v1);
}

// ---------------- Kernel 3: stage-2 building block -> f_agg2 point-major (B*N, 64) ----------------
__global__ __launch_bounds__(256, 3) void k3_stage2(
    const float* __restrict__ xyz, const int* __restrict__ nidx,
    const float* __restrict__ f_agg,
    const float* __restrict__ bb_w1, const float* __restrict__ bb_g1, const float* __restrict__ bb_b1,
    const float* __restrict__ bb_w2, const float* __restrict__ bb_g2, const float* __restrict__ bb_b2,
    const float* __restrict__ att_fc,
    const float* __restrict__ att_w, const float* __restrict__ att_g, const float* __restrict__ att_b,
    float* __restrict__ fagg2)
{
    __shared__ float awT[D * D];          // folded att2_w^T: [c][o]
    __shared__ float aggb[16][D + 1];

    int tid = threadIdx.x;
    for (int i = tid; i < D * D; i += 256) {
        int o = i & (D - 1), c = i >> 6;
        awT[i] = att_w[o * D + c] * (att_g[o] * BN_RS);
    }
    __syncthreads();

    int wid = tid >> 6, lane = tid & 63;
    int p4 = lane >> 4, kk = lane & 15;
    int pt = (wid << 2) + p4;
    int p = (blockIdx.x << 4) + pt;
    int b = p >> 15, n = p & (NPTS - 1);

    int nb = nidx[((size_t)p << 4) + kk];

    float feat[D];
    {   // rel-pos + bb_w1 -> fx, then bb_w2 -> feat[32..63]; fx dies here
        const float* cx = xyz + (size_t)(b * NPTS + n) * 3;
        const float* nx = xyz + (size_t)(b * NPTS + nb) * 3;
        float c0 = cx[0], c1 = cx[1], c2 = cx[2];
        float x0 = nx[0], x1 = nx[1], x2 = nx[2];
        float r0 = c0 - x0, r1 = c1 - x1, r2 = c2 - x2;
        float dist = sqrtf(r0 * r0 + r1 * r1 + r2 * r2);

        float fx[H];
#define FXYZ4X(c) FXYZ(c, fx[(c)]) FXYZ((c)+1, fx[(c)+1]) FXYZ((c)+2, fx[(c)+2]) FXYZ((c)+3, fx[(c)+3])
        FXYZ4X(0) FXYZ4X(4) FXYZ4X(8) FXYZ4X(12)
        FXYZ4X(16) FXYZ4X(20) FXYZ4X(24) FXYZ4X(28)

        FX2x4(0) FX2x4(4) FX2x4(8) FX2x4(12)
        FX2x4(16) FX2x4(20) FX2x4(24) FX2x4(28)
    }
    {   // f_nb2 gather from f_agg (channels 0..31)
        const float4* src = (const float4*)(f_agg + (((size_t)(b * NPTS + nb)) << 5));
#pragma unroll
        for (int j = 0; j < 8; ++j) {
            float4 v = src[j];
            feat[4 * j + 0] = v.x; feat[4 * j + 1] = v.y;
            feat[4 * j + 2] = v.z; feat[4 * j + 3] = v.w;
        }
    }

    // scores conv (att2_fc) + softmax + pool: 64 static expansions
    SC16(0, att_fc) SC16(16, att_fc) SC16(32, att_fc) SC16(48, att_fc)

    __syncthreads();

    // output MLP: lane kk computes o = 4kk..4kk+3
    float a0 = 0.f, a1 = 0.f, a2 = 0.f, a3 = 0.f;
#pragma unroll 8
    for (int c = 0; c < D; ++c) {
        float xv = aggb[pt][c];
        float4 w4 = ((const float4*)awT)[c * (D / 4) + kk];
        a0 = fmaf(w4.x, xv, a0); a1 = fmaf(w4.y, xv, a1);
        a2 = fmaf(w4.z, xv, a2); a3 = fmaf(w4.w, xv, a3);
    }
    float4 bb = ((const float4*)att_b)[kk];
    float4 r;
    r.x = fmaxf(a0 + bb.x, 0.f);
    r.y = fmaxf(a1 + bb.y, 0.f);
    r.z = fmaxf(a2 + bb.z, 0.f);
    r.w = fmaxf(a3 + bb.w, 0.f);
    ((float4*)(fagg2 + ((size_t)p << 6)))[kk] = r;
}

// ---------------- Kernel 4: out = leaky(bn(mlp2@f_agg2) + bn(sc@feature)) ----------------
__global__ __launch_bounds__(256) void k4_final(
    const float* __restrict__ fagg2, const float* __restrict__ feature,
    const float* __restrict__ w_mlp2, const float* __restrict__ g_mlp2, const float* __restrict__ b_mlp2,
    const float* __restrict__ w_sc, const float* __restrict__ g_sc, const float* __restrict__ b_sc,
    float* __restrict__ out)
{
    int tid = threadIdx.x;
    int gb = blockIdx.x;
    int o0 = (gb & 3) << 5;                 // uniform (SGPR)
    int p  = ((gb >> 2) << 8) + tid;
    int b = p >> 15, n = p & (NPTS - 1);

    float xr[D];
    {
        const float4* src = (const float4*)(fagg2 + ((size_t)p << 6));
#pragma unroll
        for (int j = 0; j < D / 4; ++j) {
            float4 v = src[j];
            xr[4 * j + 0] = v.x; xr[4 * j + 1] = v.y;
            xr[4 * j + 2] = v.z; xr[4 * j + 3] = v.w;
        }
    }
    float xf[CIN];
#pragma unroll
    for (int c = 0; c < CIN; ++c)
        xf[c] = feature[((b * CIN + c) << 15) + n];

#pragma unroll 4
    for (int j = 0; j < 32; ++j) {
        int o = o0 + j;
        float s0 = 0.f, s1 = 0.f, s2 = 0.f, s3 = 0.f;
        const float* wm = w_mlp2 + o * D;
#pragma unroll
        for (int c = 0; c < D; c += 4) {
            s0 = fmaf(wm[c + 0], xr[c + 0], s0);
            s1 = fmaf(wm[c + 1], xr[c + 1], s1);
            s2 = fmaf(wm[c + 2], xr[c + 2], s2);
            s3 = fmaf(wm[c + 3], xr[c + 3], s3);
        }
        float aA = (s0 + s1) + (s2 + s3);
        float t0 = 0.f, t1 = 0.f, t2 = 0.f, t3 = 0.f;
        const float* ws = w_sc + o * CIN;
#pragma unroll
        for (int c = 0; c < CIN; c += 4) {
            t0 = fmaf(ws[c + 0], xf[c + 0], t0);
            t1 = fmaf(ws[c + 1], xf[c + 1], t1);
            t2 = fmaf(ws[c + 2], xf[c + 2], t2);
            t3 = fmaf(ws[c + 3], xf[c + 3], t3);
        }
        float aB = (t0 + t1) + (t2 + t3);
        float v = fmaf(aA, g_mlp2[o] * BN_RS, b_mlp2[o])
                + fmaf(aB, g_sc[o] * BN_RS, b_sc[o]);
        v = (v >= 0.0f) ? v : 0.2f * v;
        out[((b * DOUT + o) << 15) + n] = v;
    }
}

extern "C" void kernel_launch(void* const* d_in, const int* in_sizes, int n_in,
                              void* d_out, int out_size, void* d_ws, size_t ws_size,
                              hipStream_t stream) {
    const float* feature = (const float*)d_in[0];
    const float* xyz     = (const float*)d_in[1];
    const float* w_mlp1  = (const float*)d_in[2];
    const float* g_mlp1  = (const float*)d_in[3];
    const float* b_mlp1  = (const float*)d_in[4];
    const float* bb_w1   = (const float*)d_in[5];
    const float* bb_g1   = (const float*)d_in[6];
    const float* bb_b1   = (const float*)d_in[7];
    const float* att1_fc = (const float*)d_in[8];
    const float* att1_w  = (const float*)d_in[9];
    const float* att1_g  = (const float*)d_in[10];
    const float* att1_b  = (const float*)d_in[11];
    const float* bb_w2   = (const float*)d_in[12];
    const float* bb_g2   = (const float*)d_in[13];
    const float* bb_b2   = (const float*)d_in[14];
    const float* att2_fc = (const float*)d_in[15];
    const float* att2_w  = (const float*)d_in[16];
    const float* att2_g  = (const float*)d_in[17];
    const float* att2_b  = (const float*)d_in[18];
    const float* w_mlp2  = (const float*)d_in[19];
    const float* g_mlp2  = (const float*)d_in[20];
    const float* b_mlp2  = (const float*)d_in[21];
    const float* w_sc    = (const float*)d_in[22];
    const float* g_sc    = (const float*)d_in[23];
    const float* b_sc    = (const float*)d_in[24];
    const int*   nidx    = (const int*)d_in[25];
    float* out = (float*)d_out;

    float* f_pc  = (float*)d_ws;                   // B*N*32
    float* f_agg = f_pc + (size_t)NB * NPTS * H;   // B*N*32
    float* fagg2 = f_agg + (size_t)NB * NPTS * H;  // B*N*64 point-major

    k1_mlp1<<<NB * NPTS / 256, 256, 0, stream>>>(feature, w_mlp1, g_mlp1, b_mlp1, f_pc);
    k2_stage1<<<NB * NPTS / 16, 256, 0, stream>>>(xyz, nidx, f_pc,
                                                  bb_w1, bb_g1, bb_b1,
                                                  att1_fc, att1_w, att1_g, att1_b, f_agg);
    k3_stage2<<<NB * NPTS / 16, 256, 0, stream>>>(xyz, nidx, f_agg,
                                                  bb_w1, bb_g1, bb_b1,
                                                  bb_w2, bb_g2, bb_b2,
                                                  att2_fc, att2_w, att2_g, att2_b, fagg2);
    k4_final<<<NB * NPTS * 4 / 256, 256, 0, stream>>>(fagg2, feature,
                                                      w_mlp2, g_mlp2, b_mlp2,
                                                      w_sc, g_sc, b_sc, out);
}

// Round 6
// 346.432 us; speedup vs baseline: 1.6306x; 1.6175x over previous
//
#include <hip/hip_runtime.h>
#include <math.h>

#define NPTS 32768
#define NB 2
#define CIN 32
#define H 32
#define D 64
#define DOUT 128
#define BN_RS 0.99999500003749981f   // 1/sqrt(1 + 1e-5)

typedef __attribute__((ext_vector_type(8))) short bf16x8;
typedef __attribute__((ext_vector_type(4))) short bf16x4;
typedef __attribute__((ext_vector_type(4))) float f32x4;

__device__ __forceinline__ ushort f2b(float f) {
    union { float f; unsigned u; } v; v.f = f;
    unsigned r = v.u + 0x7fffu + ((v.u >> 16) & 1u);   // RNE
    return (ushort)(r >> 16);
}
__device__ __forceinline__ float b2f(ushort u) {
    union { unsigned u; float f; } v; v.u = ((unsigned)u) << 16; return v.f;
}
#define MF(a, b, c) __builtin_amdgcn_mfma_f32_16x16x32_bf16(a, b, c, 0, 0, 0)

// relative-pos encoding channel c -> DST (dist,r0..r2,c0..c2,x0..x2, bb_w1/g1/b1 in scope)
#define FXYZ(c, DST) { const float* _w = bb_w1 + (c) * 10;                        \
    float _a = _w[0] * dist; _a = fmaf(_w[1], r0, _a); _a = fmaf(_w[2], r1, _a);  \
    _a = fmaf(_w[3], r2, _a); _a = fmaf(_w[4], c0, _a); _a = fmaf(_w[5], c1, _a); \
    _a = fmaf(_w[6], c2, _a); _a = fmaf(_w[7], x0, _a); _a = fmaf(_w[8], x1, _a); \
    _a = fmaf(_w[9], x2, _a);                                                     \
    DST = fmaxf(fmaf(_a, bb_g1[(c)] * BN_RS, bb_b1[(c)]), 0.f); }
#define FXYZ4X(c) FXYZ(c, fx[(c)]) FXYZ((c)+1, fx[(c)+1]) FXYZ((c)+2, fx[(c)+2]) FXYZ((c)+3, fx[(c)+3])

// ---- attention core: MFMA logits -> exp -> 16-lane shuffle reduce -> agg (bf16 LDS) ----
#define RED(E, Q) E += __shfl_xor(E, 1); Q += __shfl_xor(Q, 1);                   \
                  E += __shfl_xor(E, 2); Q += __shfl_xor(Q, 2);                   \
                  E += __shfl_xor(E, 4); Q += __shfl_xor(Q, 4);                   \
                  E += __shfl_xor(E, 8); Q += __shfl_xor(Q, 8);
#define AWR(mi, r, E, Q) if (c16 == (mi) * 4 + (r)) aggb[ptl][(mi) * 16 + g4 + (r)] = f2b(__fdividef(Q, E));
#define ATT_MI(mi, AC) {                                                          \
    float e0 = __expf(AC[0]), e1 = __expf(AC[1]), e2 = __expf(AC[2]), e3 = __expf(AC[3]); \
    bf16x4 fv = *(const bf16x4*)&feat[wid][prow][(mi) * 16 + g4];                 \
    float q0 = e0 * b2f((ushort)fv[0]), q1 = e1 * b2f((ushort)fv[1]);             \
    float q2 = e2 * b2f((ushort)fv[2]), q3 = e3 * b2f((ushort)fv[3]);             \
    RED(e0, q0) RED(e1, q1) RED(e2, q2) RED(e3, q3)                               \
    AWR(mi, 0, e0, q0) AWR(mi, 1, e1, q1) AWR(mi, 2, e2, q2) AWR(mi, 3, e3, q3) }
#define ATT_NI(ni) {                                                              \
    int prow = (ni) * 16 + c16;                                                   \
    int ptl  = (wid << 2) + (ni);                                                 \
    bf16x8 b0 = *(const bf16x8*)&feat[wid][prow][g8];                             \
    bf16x8 b1 = *(const bf16x8*)&feat[wid][prow][32 + g8];                        \
    f32x4 ac0 = zf4, ac1 = zf4, ac2 = zf4, ac3 = zf4;                             \
    ac0 = MF(afc0_0, b0, ac0); ac1 = MF(afc1_0, b0, ac1);                         \
    ac2 = MF(afc2_0, b0, ac2); ac3 = MF(afc3_0, b0, ac3);                         \
    ac0 = MF(afc0_1, b1, ac0); ac1 = MF(afc1_1, b1, ac1);                         \
    ac2 = MF(afc2_1, b1, ac2); ac3 = MF(afc3_1, b1, ac3);                         \
    ATT_MI(0, ac0) ATT_MI(1, ac1) ATT_MI(2, ac2) ATT_MI(3, ac3) }

// ---------------- Kernel 1: f_pc = relu(bn(w_mlp1 @ feature)) -> bf16 (B*N,32) ----------------
__global__ __launch_bounds__(256, 4) void k1_mlp1(
    const float* __restrict__ feature, const float* __restrict__ w_mlp1,
    const float* __restrict__ g_mlp1, const float* __restrict__ b_mlp1,
    ushort* __restrict__ f_pc)
{
    int tid = threadIdx.x;
    int pg = blockIdx.x * 256 + tid;
    int b = pg >> 15, n = pg & (NPTS - 1);

    float x[CIN];
#pragma unroll
    for (int c = 0; c < CIN; ++c)
        x[c] = feature[((b * CIN + c) << 15) + n];

    float outv[CIN];
#pragma unroll
    for (int o = 0; o < CIN; ++o) {
        float s0 = 0.f, s1 = 0.f, s2 = 0.f, s3 = 0.f;
        const float* w = w_mlp1 + o * CIN;
#pragma unroll
        for (int c = 0; c < CIN; c += 4) {
            s0 = fmaf(w[c + 0], x[c + 0], s0);
            s1 = fmaf(w[c + 1], x[c + 1], s1);
            s2 = fmaf(w[c + 2], x[c + 2], s2);
            s3 = fmaf(w[c + 3], x[c + 3], s3);
        }
        float acc = (s0 + s1) + (s2 + s3);
        outv[o] = fmaxf(fmaf(acc, g_mlp1[o] * BN_RS, b_mlp1[o]), 0.f);
    }
    uint4* dst = (uint4*)(f_pc + ((size_t)pg << 5));
#pragma unroll
    for (int j = 0; j < 4; ++j) {
        uint4 u;
        u.x = ((unsigned)f2b(outv[8 * j + 1]) << 16) | f2b(outv[8 * j + 0]);
        u.y = ((unsigned)f2b(outv[8 * j + 3]) << 16) | f2b(outv[8 * j + 2]);
        u.z = ((unsigned)f2b(outv[8 * j + 5]) << 16) | f2b(outv[8 * j + 4]);
        u.w = ((unsigned)f2b(outv[8 * j + 7]) << 16) | f2b(outv[8 * j + 6]);
        dst[j] = u;
    }
}

// ---------------- Kernel 2: stage-1 -> f_agg bf16 (B*N, 32) ----------------
// Block = 16 points, 4 waves; wave = 4 points x 16 neighbors (64 positions).
__global__ __launch_bounds__(256, 3) void k2_stage1(
    const float* __restrict__ xyz, const int* __restrict__ nidx,
    const ushort* __restrict__ f_pc,
    const float* __restrict__ bb_w1, const float* __restrict__ bb_g1, const float* __restrict__ bb_b1,
    const float* __restrict__ att_fc,
    const float* __restrict__ att_w, const float* __restrict__ att_g, const float* __restrict__ att_b,
    ushort* __restrict__ f_agg)
{
    __shared__ __align__(16) ushort feat[4][64][72];   // per-wave 64 pos x 64 ch bf16 (pad 72)
    __shared__ __align__(16) ushort fcb[64][72];       // att1_fc bf16
    __shared__ __align__(16) ushort aggb[16][72];      // pooled agg bf16 per point
    __shared__ __align__(16) float  abf[H];

    int tid = threadIdx.x;
    for (int i = tid; i < D * D; i += 256) fcb[i >> 6][i & 63] = f2b(att_fc[i]);
    if (tid < H) abf[tid] = att_b[tid];
    __syncthreads();

    int wid = tid >> 6, lane = tid & 63;
    int g = lane >> 4, c16 = lane & 15;
    int g4 = g << 2, g8 = g << 3;
    f32x4 zf4 = {0.f, 0.f, 0.f, 0.f};

    int pb = (blockIdx.x << 4) + (wid << 2) + g;       // this lane's build point
    int b = pb >> 15, n = pb & (NPTS - 1);
    int nb = nidx[((size_t)pb << 4) + c16];

    // issue neighbor-feature gather early (bf16, 64B row)
    const bf16x8* gsrc = (const bf16x8*)(f_pc + (((size_t)(b * NPTS + nb)) << 5));
    bf16x8 gv0 = gsrc[0], gv1 = gsrc[1], gv2 = gsrc[2], gv3 = gsrc[3];

    // f_xyz (ch 32..63)
    const float* cx = xyz + (size_t)(b * NPTS + n) * 3;
    const float* nx = xyz + (size_t)(b * NPTS + nb) * 3;
    float c0 = cx[0], c1 = cx[1], c2 = cx[2];
    float x0 = nx[0], x1 = nx[1], x2 = nx[2];
    float r0 = c0 - x0, r1 = c1 - x1, r2 = c2 - x2;
    float dist = sqrtf(r0 * r0 + r1 * r1 + r2 * r2);
    float fx[H];
    FXYZ4X(0) FXYZ4X(4) FXYZ4X(8) FXYZ4X(12) FXYZ4X(16) FXYZ4X(20) FXYZ4X(24) FXYZ4X(28)
#pragma unroll
    for (int j = 0; j < 4; ++j) {
        bf16x8 v;
#pragma unroll
        for (int i = 0; i < 8; ++i) v[i] = (short)f2b(fx[8 * j + i]);
        *(bf16x8*)&feat[wid][lane][32 + 8 * j] = v;
    }
    // gathered neighbor features (ch 0..31)
    *(bf16x8*)&feat[wid][lane][0]  = gv0;
    *(bf16x8*)&feat[wid][lane][8]  = gv1;
    *(bf16x8*)&feat[wid][lane][16] = gv2;
    *(bf16x8*)&feat[wid][lane][24] = gv3;

    // fc A-fragments (row = c16, k = g*8+j (+32 for ks=1))
    bf16x8 afc0_0 = *(const bf16x8*)&fcb[ 0 + c16][     g8];
    bf16x8 afc0_1 = *(const bf16x8*)&fcb[ 0 + c16][32 + g8];
    bf16x8 afc1_0 = *(const bf16x8*)&fcb[16 + c16][     g8];
    bf16x8 afc1_1 = *(const bf16x8*)&fcb[16 + c16][32 + g8];
    bf16x8 afc2_0 = *(const bf16x8*)&fcb[32 + c16][     g8];
    bf16x8 afc2_1 = *(const bf16x8*)&fcb[32 + c16][32 + g8];
    bf16x8 afc3_0 = *(const bf16x8*)&fcb[48 + c16][     g8];
    bf16x8 afc3_1 = *(const bf16x8*)&fcb[48 + c16][32 + g8];

    ATT_NI(0) ATT_NI(1) ATT_NI(2) ATT_NI(3)
    __syncthreads();

    // out-MLP via MFMA: out[32 x 16pts] = fold(att_w)[32x64] @ aggb[64x16]; waves 0,1 -> mi
    if (wid < 2) {
        int o = (wid << 4) + c16;
        float sc = att_g[o] * BN_RS;
        const float* wr0 = att_w + o * D + g8;
        const float* wr1 = att_w + o * D + 32 + g8;
        bf16x8 aw0, aw1;
#pragma unroll
        for (int i = 0; i < 8; ++i) {
            aw0[i] = (short)f2b(wr0[i] * sc);
            aw1[i] = (short)f2b(wr1[i] * sc);
        }
        bf16x8 bb0 = *(const bf16x8*)&aggb[c16][     g8];
        bf16x8 bb1 = *(const bf16x8*)&aggb[c16][32 + g8];
        f32x4 acc = *(const f32x4*)&abf[(wid << 4) + g4];
        acc = MF(aw0, bb0, acc);
        acc = MF(aw1, bb1, acc);
        int p = (blockIdx.x << 4) + c16;
        int o0 = (wid << 4) + g4;
        bf16x4 st;
        st[0] = (short)f2b(fmaxf(acc[0], 0.f));
        st[1] = (short)f2b(fmaxf(acc[1], 0.f));
        st[2] = (short)f2b(fmaxf(acc[2], 0.f));
        st[3] = (short)f2b(fmaxf(acc[3], 0.f));
        *(bf16x4*)(f_agg + (((size_t)p) << 5) + o0) = st;
    }
}

// ---------------- Kernel 3: stage-2 -> f_agg2 f32 point-major (B*N, 64) ----------------
__global__ __launch_bounds__(256, 3) void k3_stage2(
    const float* __restrict__ xyz, const int* __restrict__ nidx,
    const ushort* __restrict__ f_agg,
    const float* __restrict__ bb_w1, const float* __restrict__ bb_g1, const float* __restrict__ bb_b1,
    const float* __restrict__ bb_w2, const float* __restrict__ bb_g2, const float* __restrict__ bb_b2,
    const float* __restrict__ att_fc,
    const float* __restrict__ att_w, const float* __restrict__ att_g, const float* __restrict__ att_b,
    float* __restrict__ fagg2)
{
    __shared__ __align__(16) ushort feat[4][64][72];
    __shared__ __align__(16) ushort fcb[64][72];       // att2_fc bf16
    __shared__ __align__(16) ushort aggb[16][72];
    __shared__ __align__(16) float  b2s[H];
    __shared__ __align__(16) float  abf[D];

    int tid = threadIdx.x;
    for (int i = tid; i < D * D; i += 256) fcb[i >> 6][i & 63] = f2b(att_fc[i]);
    if (tid < H) b2s[tid] = bb_b2[tid];
    if (tid < D) abf[tid] = att_b[tid];
    __syncthreads();

    int wid = tid >> 6, lane = tid & 63;
    int g = lane >> 4, c16 = lane & 15;
    int g4 = g << 2, g8 = g << 3;
    f32x4 zf4 = {0.f, 0.f, 0.f, 0.f};

    int pb = (blockIdx.x << 4) + (wid << 2) + g;
    int b = pb >> 15, n = pb & (NPTS - 1);
    int nb = nidx[((size_t)pb << 4) + c16];

    const bf16x8* gsrc = (const bf16x8*)(f_agg + (((size_t)(b * NPTS + nb)) << 5));
    bf16x8 gv0 = gsrc[0], gv1 = gsrc[1], gv2 = gsrc[2], gv3 = gsrc[3];

    const float* cx = xyz + (size_t)(b * NPTS + n) * 3;
    const float* nx = xyz + (size_t)(b * NPTS + nb) * 3;
    float c0 = cx[0], c1 = cx[1], c2 = cx[2];
    float x0 = nx[0], x1 = nx[1], x2 = nx[2];
    float r0 = c0 - x0, r1 = c1 - x1, r2 = c2 - x2;
    float dist = sqrtf(r0 * r0 + r1 * r1 + r2 * r2);
    float fx[H];
    FXYZ4X(0) FXYZ4X(4) FXYZ4X(8) FXYZ4X(12) FXYZ4X(16) FXYZ4X(20) FXYZ4X(24) FXYZ4X(28)
    // stage fx (pre-bb_w2) into slots 32..63
#pragma unroll
    for (int j = 0; j < 4; ++j) {
        bf16x8 v;
#pragma unroll
        for (int i = 0; i < 8; ++i) v[i] = (short)f2b(fx[8 * j + i]);
        *(bf16x8*)&feat[wid][lane][32 + 8 * j] = v;
    }

    // bb_w2 A-fragments from global (folded, bf16); mi = 0,1
    bf16x8 aw20, aw21;
    {
        int o = c16;
        float sc2 = bb_g2[o] * BN_RS;
        const float* wr = bb_w2 + o * H + g8;
#pragma unroll
        for (int i = 0; i < 8; ++i) aw20[i] = (short)f2b(wr[i] * sc2);
    }
    {
        int o = 16 + c16;
        float sc2 = bb_g2[o] * BN_RS;
        const float* wr = bb_w2 + o * H + g8;
#pragma unroll
        for (int i = 0; i < 8; ++i) aw21[i] = (short)f2b(wr[i] * sc2);
    }
    // read all fx B-fragments BEFORE overwriting slots 32..63
    bf16x8 bfx0 = *(const bf16x8*)&feat[wid][ 0 + c16][32 + g8];
    bf16x8 bfx1 = *(const bf16x8*)&feat[wid][16 + c16][32 + g8];
    bf16x8 bfx2 = *(const bf16x8*)&feat[wid][32 + c16][32 + g8];
    bf16x8 bfx3 = *(const bf16x8*)&feat[wid][48 + c16][32 + g8];
    f32x4 bi0 = *(const f32x4*)&b2s[     g4];
    f32x4 bi1 = *(const f32x4*)&b2s[16 + g4];
    f32x4 a00 = MF(aw20, bfx0, bi0);
    f32x4 a01 = MF(aw20, bfx1, bi0);
    f32x4 a02 = MF(aw20, bfx2, bi0);
    f32x4 a03 = MF(aw20, bfx3, bi0);
    f32x4 a10 = MF(aw21, bfx0, bi1);
    f32x4 a11 = MF(aw21, bfx1, bi1);
    f32x4 a12 = MF(aw21, bfx2, bi1);
    f32x4 a13 = MF(aw21, bfx3, bi1);
#define WB(mi, ni, A) { bf16x4 w;                                  \
    w[0] = (short)f2b(fmaxf(A[0], 0.f)); w[1] = (short)f2b(fmaxf(A[1], 0.f)); \
    w[2] = (short)f2b(fmaxf(A[2], 0.f)); w[3] = (short)f2b(fmaxf(A[3], 0.f)); \
    *(bf16x4*)&feat[wid][(ni) * 16 + c16][32 + (mi) * 16 + g4] = w; }
    WB(0, 0, a00) WB(0, 1, a01) WB(0, 2, a02) WB(0, 3, a03)
    WB(1, 0, a10) WB(1, 1, a11) WB(1, 2, a12) WB(1, 3, a13)
#undef WB

    // gathered f_agg neighbor features (ch 0..31)
    *(bf16x8*)&feat[wid][lane][0]  = gv0;
    *(bf16x8*)&feat[wid][lane][8]  = gv1;
    *(bf16x8*)&feat[wid][lane][16] = gv2;
    *(bf16x8*)&feat[wid][lane][24] = gv3;

    bf16x8 afc0_0 = *(const bf16x8*)&fcb[ 0 + c16][     g8];
    bf16x8 afc0_1 = *(const bf16x8*)&fcb[ 0 + c16][32 + g8];
    bf16x8 afc1_0 = *(const bf16x8*)&fcb[16 + c16][     g8];
    bf16x8 afc1_1 = *(const bf16x8*)&fcb[16 + c16][32 + g8];
    bf16x8 afc2_0 = *(const bf16x8*)&fcb[32 + c16][     g8];
    bf16x8 afc2_1 = *(const bf16x8*)&fcb[32 + c16][32 + g8];
    bf16x8 afc3_0 = *(const bf16x8*)&fcb[48 + c16][     g8];
    bf16x8 afc3_1 = *(const bf16x8*)&fcb[48 + c16][32 + g8];

    ATT_NI(0) ATT_NI(1) ATT_NI(2) ATT_NI(3)
    __syncthreads();

    // out-MLP via MFMA: out[64 x 16pts] = fold(att2_w) @ aggb; wave wid -> mi
    {
        int o = (wid << 4) + c16;
        float sc = att_g[o] * BN_RS;
        const float* wr0 = att_w + o * D + g8;
        const float* wr1 = att_w + o * D + 32 + g8;
        bf16x8 aw0, aw1;
#pragma unroll
        for (int i = 0; i < 8; ++i) {
            aw0[i] = (short)f2b(wr0[i] * sc);
            aw1[i] = (short)f2b(wr1[i] * sc);
        }
        bf16x8 bb0 = *(const bf16x8*)&aggb[c16][     g8];
        bf16x8 bb1 = *(const bf16x8*)&aggb[c16][32 + g8];
        f32x4 acc = *(const f32x4*)&abf[(wid << 4) + g4];
        acc = MF(aw0, bb0, acc);
        acc = MF(aw1, bb1, acc);
        int p = (blockIdx.x << 4) + c16;
        int o0 = (wid << 4) + g4;
        float4 st;
        st.x = fmaxf(acc[0], 0.f);
        st.y = fmaxf(acc[1], 0.f);
        st.z = fmaxf(acc[2], 0.f);
        st.w = fmaxf(acc[3], 0.f);
        *(float4*)(fagg2 + (((size_t)p) << 6) + o0) = st;
    }
}

// ---------------- Kernel 4: out = leaky(bn(mlp2@f_agg2) + bn(sc@feature)) ----------------
__global__ __launch_bounds__(256) void k4_final(
    const float* __restrict__ fagg2, const float* __restrict__ feature,
    const float* __restrict__ w_mlp2, const float* __restrict__ g_mlp2, const float* __restrict__ b_mlp2,
    const float* __restrict__ w_sc, const float* __restrict__ g_sc, const float* __restrict__ b_sc,
    float* __restrict__ out)
{
    int tid = threadIdx.x;
    int gb = blockIdx.x;
    int o0 = (gb & 3) << 5;                 // uniform (SGPR)
    int p  = ((gb >> 2) << 8) + tid;
    int b = p >> 15, n = p & (NPTS - 1);

    float xr[D];
    {
        const float4* src = (const float4*)(fagg2 + ((size_t)p << 6));
#pragma unroll
        for (int j = 0; j < D / 4; ++j) {
            float4 v = src[j];
            xr[4 * j + 0] = v.x; xr[4 * j + 1] = v.y;
            xr[4 * j + 2] = v.z; xr[4 * j + 3] = v.w;
        }
    }
    float xf[CIN];
#pragma unroll
    for (int c = 0; c < CIN; ++c)
        xf[c] = feature[((b * CIN + c) << 15) + n];

#pragma unroll 4
    for (int j = 0; j < 32; ++j) {
        int o = o0 + j;                     // uniform -> s_load weight rows
        float s0 = 0.f, s1 = 0.f, s2 = 0.f, s3 = 0.f;
        const float* wm = w_mlp2 + o * D;
#pragma unroll
        for (int c = 0; c < D; c += 4) {
            s0 = fmaf(wm[c + 0], xr[c + 0], s0);
            s1 = fmaf(wm[c + 1], xr[c + 1], s1);
            s2 = fmaf(wm[c + 2], xr[c + 2], s2);
            s3 = fmaf(wm[c + 3], xr[c + 3], s3);
        }
        float aA = (s0 + s1) + (s2 + s3);
        float t0 = 0.f, t1 = 0.f, t2 = 0.f, t3 = 0.f;
        const float* ws = w_sc + o * CIN;
#pragma unroll
        for (int c = 0; c < CIN; c += 4) {
            t0 = fmaf(ws[c + 0], xf[c + 0], t0);
            t1 = fmaf(ws[c + 1], xf[c + 1], t1);
            t2 = fmaf(ws[c + 2], xf[c + 2], t2);
            t3 = fmaf(ws[c + 3], xf[c + 3], t3);
        }
        float aB = (t0 + t1) + (t2 + t3);
        float v = fmaf(aA, g_mlp2[o] * BN_RS, b_mlp2[o])
                + fmaf(aB, g_sc[o] * BN_RS, b_sc[o]);
        v = (v >= 0.0f) ? v : 0.2f * v;
        out[((b * DOUT + o) << 15) + n] = v;
    }
}

extern "C" void kernel_launch(void* const* d_in, const int* in_sizes, int n_in,
                              void* d_out, int out_size, void* d_ws, size_t ws_size,
                              hipStream_t stream) {
    const float* feature = (const float*)d_in[0];
    const float* xyz     = (const float*)d_in[1];
    const float* w_mlp1  = (const float*)d_in[2];
    const float* g_mlp1  = (const float*)d_in[3];
    const float* b_mlp1  = (const float*)d_in[4];
    const float* bb_w1   = (const float*)d_in[5];
    const float* bb_g1   = (const float*)d_in[6];
    const float* bb_b1   = (const float*)d_in[7];
    const float* att1_fc = (const float*)d_in[8];
    const float* att1_w  = (const float*)d_in[9];
    const float* att1_g  = (const float*)d_in[10];
    const float* att1_b  = (const float*)d_in[11];
    const float* bb_w2   = (const float*)d_in[12];
    const float* bb_g2   = (const float*)d_in[13];
    const float* bb_b2   = (const float*)d_in[14];
    const float* att2_fc = (const float*)d_in[15];
    const float* att2_w  = (const float*)d_in[16];
    const float* att2_g  = (const float*)d_in[17];
    const float* att2_b  = (const float*)d_in[18];
    const float* w_mlp2  = (const float*)d_in[19];
    const float* g_mlp2  = (const float*)d_in[20];
    const float* b_mlp2  = (const float*)d_in[21];
    const float* w_sc    = (const float*)d_in[22];
    const float* g_sc    = (const float*)d_in[23];
    const float* b_sc    = (const float*)d_in[24];
    const int*   nidx    = (const int*)d_in[25];
    float* out = (float*)d_out;

    ushort* f_pc_bf  = (ushort*)d_ws;                            // B*N*32 bf16 = 4MB
    ushort* f_agg_bf = f_pc_bf + (size_t)NB * NPTS * 32;         // B*N*32 bf16 = 4MB
    float*  fagg2    = (float*)(f_agg_bf + (size_t)NB * NPTS * 32); // B*N*64 f32 = 16MB

    k1_mlp1<<<NB * NPTS / 256, 256, 0, stream>>>(feature, w_mlp1, g_mlp1, b_mlp1, f_pc_bf);
    k2_stage1<<<NB * NPTS / 16, 256, 0, stream>>>(xyz, nidx, f_pc_bf,
                                                  bb_w1, bb_g1, bb_b1,
                                                  att1_fc, att1_w, att1_g, att1_b, f_agg_bf);
    k3_stage2<<<NB * NPTS / 16, 256, 0, stream>>>(xyz, nidx, f_agg_bf,
                                                  bb_w1, bb_g1, bb_b1,
                                                  bb_w2, bb_g2, bb_b2,
                                                  att2_fc, att2_w, att2_g, att2_b, fagg2);
    k4_final<<<NB * NPTS * 4 / 256, 256, 0, stream>>>(fagg2, feature,
                                                      w_mlp2, g_mlp2, b_mlp2,
                                                      w_sc, g_sc, b_sc, out);
}

// Round 8
// 265.049 us; speedup vs baseline: 2.1313x; 1.3070x over previous
//
#include <hip/hip_runtime.h>
#include <math.h>

#define NPTS 32768
#define NB 2
#define CIN 32
#define H 32
#define D 64
#define DOUT 128
#define BN_RS 0.99999500003749981f   // 1/sqrt(1 + 1e-5)

typedef __attribute__((ext_vector_type(8))) short bf16x8;
typedef __attribute__((ext_vector_type(4))) short bf16x4;
typedef __attribute__((ext_vector_type(4))) float f32x4;

__device__ __forceinline__ ushort f2b(float f) {
    union { float f; unsigned u; } v; v.f = f;
    unsigned r = v.u + 0x7fffu + ((v.u >> 16) & 1u);   // RNE
    return (ushort)(r >> 16);
}
__device__ __forceinline__ float b2f(ushort u) {
    union { unsigned u; float f; } v; v.u = ((unsigned)u) << 16; return v.f;
}
// pack two f32 -> bf16x2 dword (round-half-up + v_perm_b32)
__device__ __forceinline__ unsigned pk2(float f0, float f1) {
    unsigned a = __builtin_bit_cast(unsigned, f0) + 0x8000u;
    unsigned b = __builtin_bit_cast(unsigned, f1) + 0x8000u;
    return __builtin_amdgcn_perm(b, a, 0x07060302);
}
// DPP row_ror add: x += rotate_within_16(x, N); ctrl must be immediate -> template
template <int CTRL>
__device__ __forceinline__ float dpp_add(float x) {
    int m = __builtin_amdgcn_update_dpp(0, __builtin_bit_cast(int, x), CTRL, 0xF, 0xF, true);
    return x + __builtin_bit_cast(float, m);
}
#define MF(a, b, c) __builtin_amdgcn_mfma_f32_16x16x32_bf16(a, b, c, 0, 0, 0)

// relative-pos encoding channel c -> DST
#define FXYZ(c, DST) { const float* _w = bb_w1 + (c) * 10;                        \
    float _a = _w[0] * dist; _a = fmaf(_w[1], r0, _a); _a = fmaf(_w[2], r1, _a);  \
    _a = fmaf(_w[3], r2, _a); _a = fmaf(_w[4], c0, _a); _a = fmaf(_w[5], c1, _a); \
    _a = fmaf(_w[6], c2, _a); _a = fmaf(_w[7], x0, _a); _a = fmaf(_w[8], x1, _a); \
    _a = fmaf(_w[9], x2, _a);                                                     \
    DST = fmaxf(fmaf(_a, bb_g1[(c)] * BN_RS, bb_b1[(c)]), 0.f); }
#define FXYZ4X(c) FXYZ(c, fx[(c)]) FXYZ((c)+1, fx[(c)+1]) FXYZ((c)+2, fx[(c)+2]) FXYZ((c)+3, fx[(c)+3])

// ---- attention core: MFMA logits -> exp -> 16-lane DPP ring reduce -> agg (bf16 LDS) ----
#define RED(E, Q) E = dpp_add<0x128>(E); Q = dpp_add<0x128>(Q);                   \
                  E = dpp_add<0x124>(E); Q = dpp_add<0x124>(Q);                   \
                  E = dpp_add<0x122>(E); Q = dpp_add<0x122>(Q);                   \
                  E = dpp_add<0x121>(E); Q = dpp_add<0x121>(Q);
#define AWR(mi, r, E, Q) if (c16 == (mi) * 4 + (r)) aggb[ptl][(mi) * 16 + g4 + (r)] = f2b(__fdividef(Q, E));
#define ATT_MI(mi, AC) {                                                          \
    float e0 = __expf(AC[0]), e1 = __expf(AC[1]), e2 = __expf(AC[2]), e3 = __expf(AC[3]); \
    bf16x4 fv = *(const bf16x4*)&feat[wid][prow][(mi) * 16 + g4];                 \
    float q0 = e0 * b2f((ushort)fv[0]), q1 = e1 * b2f((ushort)fv[1]);             \
    float q2 = e2 * b2f((ushort)fv[2]), q3 = e3 * b2f((ushort)fv[3]);             \
    RED(e0, q0) RED(e1, q1) RED(e2, q2) RED(e3, q3)                               \
    AWR(mi, 0, e0, q0) AWR(mi, 1, e1, q1) AWR(mi, 2, e2, q2) AWR(mi, 3, e3, q3) }
#define ATT_NI(ni) {                                                              \
    int prow = (ni) * 16 + c16;                                                   \
    int ptl  = (wid << 2) + (ni);                                                 \
    bf16x8 b0 = *(const bf16x8*)&feat[wid][prow][g8];                             \
    bf16x8 b1 = *(const bf16x8*)&feat[wid][prow][32 + g8];                        \
    f32x4 ac0 = zf4, ac1 = zf4, ac2 = zf4, ac3 = zf4;                             \
    ac0 = MF(afc0_0, b0, ac0); ac1 = MF(afc1_0, b0, ac1);                         \
    ac2 = MF(afc2_0, b0, ac2); ac3 = MF(afc3_0, b0, ac3);                         \
    ac0 = MF(afc0_1, b1, ac0); ac1 = MF(afc1_1, b1, ac1);                         \
    ac2 = MF(afc2_1, b1, ac2); ac3 = MF(afc3_1, b1, ac3);                         \
    ATT_MI(0, ac0) ATT_MI(1, ac1) ATT_MI(2, ac2) ATT_MI(3, ac3) }

// ---------------- Kernel 1: f_pc = relu(bn(w_mlp1 @ feature)) -> bf16 (B*N,32) ----------------
__global__ __launch_bounds__(256, 4) void k1_mlp1(
    const float* __restrict__ feature, const float* __restrict__ w_mlp1,
    const float* __restrict__ g_mlp1, const float* __restrict__ b_mlp1,
    ushort* __restrict__ f_pc)
{
    int tid = threadIdx.x;
    int pg = blockIdx.x * 256 + tid;
    int b = pg >> 15, n = pg & (NPTS - 1);

    float x[CIN];
#pragma unroll
    for (int c = 0; c < CIN; ++c)
        x[c] = feature[((b * CIN + c) << 15) + n];

    float outv[CIN];
#pragma unroll
    for (int o = 0; o < CIN; ++o) {
        float s0 = 0.f, s1 = 0.f, s2 = 0.f, s3 = 0.f;
        const float* w = w_mlp1 + o * CIN;
#pragma unroll
        for (int c = 0; c < CIN; c += 4) {
            s0 = fmaf(w[c + 0], x[c + 0], s0);
            s1 = fmaf(w[c + 1], x[c + 1], s1);
            s2 = fmaf(w[c + 2], x[c + 2], s2);
            s3 = fmaf(w[c + 3], x[c + 3], s3);
        }
        float acc = (s0 + s1) + (s2 + s3);
        outv[o] = fmaxf(fmaf(acc, g_mlp1[o] * BN_RS, b_mlp1[o]), 0.f);
    }
    uint4* dst = (uint4*)(f_pc + ((size_t)pg << 5));
#pragma unroll
    for (int j = 0; j < 4; ++j) {
        uint4 u;
        u.x = pk2(outv[8 * j + 0], outv[8 * j + 1]);
        u.y = pk2(outv[8 * j + 2], outv[8 * j + 3]);
        u.z = pk2(outv[8 * j + 4], outv[8 * j + 5]);
        u.w = pk2(outv[8 * j + 6], outv[8 * j + 7]);
        dst[j] = u;
    }
}

// ---------------- Kernel 2: stage-1 -> f_agg bf16 (B*N, 32) ----------------
// Block = 16 points, 4 waves; wave = 4 points x 16 neighbors (64 positions).
__global__ __launch_bounds__(256, 3) void k2_stage1(
    const float* __restrict__ xyz, const int* __restrict__ nidx,
    const ushort* __restrict__ f_pc,
    const float* __restrict__ bb_w1, const float* __restrict__ bb_g1, const float* __restrict__ bb_b1,
    const float* __restrict__ att_fc,
    const float* __restrict__ att_w, const float* __restrict__ att_g, const float* __restrict__ att_b,
    ushort* __restrict__ f_agg)
{
    __shared__ __align__(16) ushort feat[4][64][72];   // per-wave 64 pos x 64 ch bf16 (pad 72)
    __shared__ __align__(16) ushort fcb[64][72];       // att1_fc bf16
    __shared__ __align__(16) ushort aggb[16][72];      // pooled agg bf16 per point
    __shared__ __align__(16) float  abf[H];

    int tid = threadIdx.x;
    for (int i = tid; i < D * D; i += 256) fcb[i >> 6][i & 63] = f2b(att_fc[i]);
    if (tid < H) abf[tid] = att_b[tid];
    __syncthreads();

    int wid = tid >> 6, lane = tid & 63;
    int g = lane >> 4, c16 = lane & 15;
    int g4 = g << 2, g8 = g << 3;
    f32x4 zf4 = {0.f, 0.f, 0.f, 0.f};

    int pb = (blockIdx.x << 4) + (wid << 2) + g;       // this lane's build point
    int b = pb >> 15, n = pb & (NPTS - 1);
    int nb = nidx[((size_t)pb << 4) + c16];

    // issue neighbor-feature gather early (bf16, 64B row)
    const bf16x8* gsrc = (const bf16x8*)(f_pc + (((size_t)(b * NPTS + nb)) << 5));
    bf16x8 gv0 = gsrc[0], gv1 = gsrc[1], gv2 = gsrc[2], gv3 = gsrc[3];

    // f_xyz (ch 32..63)
    const float* cx = xyz + (size_t)(b * NPTS + n) * 3;
    const float* nx = xyz + (size_t)(b * NPTS + nb) * 3;
    float c0 = cx[0], c1 = cx[1], c2 = cx[2];
    float x0 = nx[0], x1 = nx[1], x2 = nx[2];
    float r0 = c0 - x0, r1 = c1 - x1, r2 = c2 - x2;
    float dist = sqrtf(r0 * r0 + r1 * r1 + r2 * r2);
    float fx[H];
    FXYZ4X(0) FXYZ4X(4) FXYZ4X(8) FXYZ4X(12) FXYZ4X(16) FXYZ4X(20) FXYZ4X(24) FXYZ4X(28)
#pragma unroll
    for (int j = 0; j < 4; ++j) {
        uint4 u;
        u.x = pk2(fx[8 * j + 0], fx[8 * j + 1]);
        u.y = pk2(fx[8 * j + 2], fx[8 * j + 3]);
        u.z = pk2(fx[8 * j + 4], fx[8 * j + 5]);
        u.w = pk2(fx[8 * j + 6], fx[8 * j + 7]);
        *(uint4*)&feat[wid][lane][32 + 8 * j] = u;
    }
    // gathered neighbor features (ch 0..31)
    *(bf16x8*)&feat[wid][lane][0]  = gv0;
    *(bf16x8*)&feat[wid][lane][8]  = gv1;
    *(bf16x8*)&feat[wid][lane][16] = gv2;
    *(bf16x8*)&feat[wid][lane][24] = gv3;

    // fc A-fragments (row = c16, k = g*8+j (+32 for ks=1))
    bf16x8 afc0_0 = *(const bf16x8*)&fcb[ 0 + c16][     g8];
    bf16x8 afc0_1 = *(const bf16x8*)&fcb[ 0 + c16][32 + g8];
    bf16x8 afc1_0 = *(const bf16x8*)&fcb[16 + c16][     g8];
    bf16x8 afc1_1 = *(const bf16x8*)&fcb[16 + c16][32 + g8];
    bf16x8 afc2_0 = *(const bf16x8*)&fcb[32 + c16][     g8];
    bf16x8 afc2_1 = *(const bf16x8*)&fcb[32 + c16][32 + g8];
    bf16x8 afc3_0 = *(const bf16x8*)&fcb[48 + c16][     g8];
    bf16x8 afc3_1 = *(const bf16x8*)&fcb[48 + c16][32 + g8];

    ATT_NI(0) ATT_NI(1) ATT_NI(2) ATT_NI(3)
    __syncthreads();

    // out-MLP via MFMA: out[32 x 16pts] = fold(att_w)[32x64] @ aggb[64x16]; waves 0,1 -> mi
    if (wid < 2) {
        int o = (wid << 4) + c16;
        float sc = att_g[o] * BN_RS;
        const float* wr0 = att_w + o * D + g8;
        const float* wr1 = att_w + o * D + 32 + g8;
        union { bf16x8 v; uint4 u; } aw0, aw1;
        aw0.u.x = pk2(wr0[0] * sc, wr0[1] * sc);
        aw0.u.y = pk2(wr0[2] * sc, wr0[3] * sc);
        aw0.u.z = pk2(wr0[4] * sc, wr0[5] * sc);
        aw0.u.w = pk2(wr0[6] * sc, wr0[7] * sc);
        aw1.u.x = pk2(wr1[0] * sc, wr1[1] * sc);
        aw1.u.y = pk2(wr1[2] * sc, wr1[3] * sc);
        aw1.u.z = pk2(wr1[4] * sc, wr1[5] * sc);
        aw1.u.w = pk2(wr1[6] * sc, wr1[7] * sc);
        bf16x8 bb0 = *(const bf16x8*)&aggb[c16][     g8];
        bf16x8 bb1 = *(const bf16x8*)&aggb[c16][32 + g8];
        f32x4 acc = *(const f32x4*)&abf[(wid << 4) + g4];
        acc = MF(aw0.v, bb0, acc);
        acc = MF(aw1.v, bb1, acc);
        int p = (blockIdx.x << 4) + c16;
        int o0 = (wid << 4) + g4;
        uint2 st;
        st.x = pk2(fmaxf(acc[0], 0.f), fmaxf(acc[1], 0.f));
        st.y = pk2(fmaxf(acc[2], 0.f), fmaxf(acc[3], 0.f));
        *(uint2*)(f_agg + (((size_t)p) << 5) + o0) = st;
    }
}

// ---------------- Kernel 3: stage-2 -> f_agg2 f32 point-major (B*N, 64) ----------------
__global__ __launch_bounds__(256, 3) void k3_stage2(
    const float* __restrict__ xyz, const int* __restrict__ nidx,
    const ushort* __restrict__ f_agg,
    const float* __restrict__ bb_w1, const float* __restrict__ bb_g1, const float* __restrict__ bb_b1,
    const float* __restrict__ bb_w2, const float* __restrict__ bb_g2, const float* __restrict__ bb_b2,
    const float* __restrict__ att_fc,
    const float* __restrict__ att_w, const float* __restrict__ att_g, const float* __restrict__ att_b,
    float* __restrict__ fagg2)
{
    __shared__ __align__(16) ushort feat[4][64][72];
    __shared__ __align__(16) ushort fcb[64][72];       // att2_fc bf16
    __shared__ __align__(16) ushort aggb[16][72];
    __shared__ __align__(16) float  b2s[H];
    __shared__ __align__(16) float  abf[D];

    int tid = threadIdx.x;
    for (int i = tid; i < D * D; i += 256) fcb[i >> 6][i & 63] = f2b(att_fc[i]);
    if (tid < H) b2s[tid] = bb_b2[tid];
    if (tid < D) abf[tid] = att_b[tid];
    __syncthreads();

    int wid = tid >> 6, lane = tid & 63;
    int g = lane >> 4, c16 = lane & 15;
    int g4 = g << 2, g8 = g << 3;
    f32x4 zf4 = {0.f, 0.f, 0.f, 0.f};

    int pb = (blockIdx.x << 4) + (wid << 2) + g;
    int b = pb >> 15, n = pb & (NPTS - 1);
    int nb = nidx[((size_t)pb << 4) + c16];

    const bf16x8* gsrc = (const bf16x8*)(f_agg + (((size_t)(b * NPTS + nb)) << 5));
    bf16x8 gv0 = gsrc[0], gv1 = gsrc[1], gv2 = gsrc[2], gv3 = gsrc[3];

    const float* cx = xyz + (size_t)(b * NPTS + n) * 3;
    const float* nx = xyz + (size_t)(b * NPTS + nb) * 3;
    float c0 = cx[0], c1 = cx[1], c2 = cx[2];
    float x0 = nx[0], x1 = nx[1], x2 = nx[2];
    float r0 = c0 - x0, r1 = c1 - x1, r2 = c2 - x2;
    float dist = sqrtf(r0 * r0 + r1 * r1 + r2 * r2);
    float fx[H];
    FXYZ4X(0) FXYZ4X(4) FXYZ4X(8) FXYZ4X(12) FXYZ4X(16) FXYZ4X(20) FXYZ4X(24) FXYZ4X(28)
    // stage fx (pre-bb_w2) into slots 32..63
#pragma unroll
    for (int j = 0; j < 4; ++j) {
        uint4 u;
        u.x = pk2(fx[8 * j + 0], fx[8 * j + 1]);
        u.y = pk2(fx[8 * j + 2], fx[8 * j + 3]);
        u.z = pk2(fx[8 * j + 4], fx[8 * j + 5]);
        u.w = pk2(fx[8 * j + 6], fx[8 * j + 7]);
        *(uint4*)&feat[wid][lane][32 + 8 * j] = u;
    }

    // bb_w2 A-fragments from global (folded, bf16); mi = 0,1
    union { bf16x8 v; uint4 u; } aw20, aw21;
    {
        int o = c16;
        float sc2 = bb_g2[o] * BN_RS;
        const float* wr = bb_w2 + o * H + g8;
        aw20.u.x = pk2(wr[0] * sc2, wr[1] * sc2);
        aw20.u.y = pk2(wr[2] * sc2, wr[3] * sc2);
        aw20.u.z = pk2(wr[4] * sc2, wr[5] * sc2);
        aw20.u.w = pk2(wr[6] * sc2, wr[7] * sc2);
    }
    {
        int o = 16 + c16;
        float sc2 = bb_g2[o] * BN_RS;
        const float* wr = bb_w2 + o * H + g8;
        aw21.u.x = pk2(wr[0] * sc2, wr[1] * sc2);
        aw21.u.y = pk2(wr[2] * sc2, wr[3] * sc2);
        aw21.u.z = pk2(wr[4] * sc2, wr[5] * sc2);
        aw21.u.w = pk2(wr[6] * sc2, wr[7] * sc2);
    }
    // read all fx B-fragments BEFORE overwriting slots 32..63
    bf16x8 bfx0 = *(const bf16x8*)&feat[wid][ 0 + c16][32 + g8];
    bf16x8 bfx1 = *(const bf16x8*)&feat[wid][16 + c16][32 + g8];
    bf16x8 bfx2 = *(const bf16x8*)&feat[wid][32 + c16][32 + g8];
    bf16x8 bfx3 = *(const bf16x8*)&feat[wid][48 + c16][32 + g8];
    f32x4 bi0 = *(const f32x4*)&b2s[     g4];
    f32x4 bi1 = *(const f32x4*)&b2s[16 + g4];
    f32x4 a00 = MF(aw20.v, bfx0, bi0);
    f32x4 a01 = MF(aw20.v, bfx1, bi0);
    f32x4 a02 = MF(aw20.v, bfx2, bi0);
    f32x4 a03 = MF(aw20.v, bfx3, bi0);
    f32x4 a10 = MF(aw21.v, bfx0, bi1);
    f32x4 a11 = MF(aw21.v, bfx1, bi1);
    f32x4 a12 = MF(aw21.v, bfx2, bi1);
    f32x4 a13 = MF(aw21.v, bfx3, bi1);
#define WB(mi, ni, A) { uint2 w;                                                  \
    w.x = pk2(fmaxf(A[0], 0.f), fmaxf(A[1], 0.f));                                \
    w.y = pk2(fmaxf(A[2], 0.f), fmaxf(A[3], 0.f));                                \
    *(uint2*)&feat[wid][(ni) * 16 + c16][32 + (mi) * 16 + g4] = w; }
    WB(0, 0, a00) WB(0, 1, a01) WB(0, 2, a02) WB(0, 3, a03)
    WB(1, 0, a10) WB(1, 1, a11) WB(1, 2, a12) WB(1, 3, a13)
#undef WB

    // gathered f_agg neighbor features (ch 0..31)
    *(bf16x8*)&feat[wid][lane][0]  = gv0;
    *(bf16x8*)&feat[wid][lane][8]  = gv1;
    *(bf16x8*)&feat[wid][lane][16] = gv2;
    *(bf16x8*)&feat[wid][lane][24] = gv3;

    bf16x8 afc0_0 = *(const bf16x8*)&fcb[ 0 + c16][     g8];
    bf16x8 afc0_1 = *(const bf16x8*)&fcb[ 0 + c16][32 + g8];
    bf16x8 afc1_0 = *(const bf16x8*)&fcb[16 + c16][     g8];
    bf16x8 afc1_1 = *(const bf16x8*)&fcb[16 + c16][32 + g8];
    bf16x8 afc2_0 = *(const bf16x8*)&fcb[32 + c16][     g8];
    bf16x8 afc2_1 = *(const bf16x8*)&fcb[32 + c16][32 + g8];
    bf16x8 afc3_0 = *(const bf16x8*)&fcb[48 + c16][     g8];
    bf16x8 afc3_1 = *(const bf16x8*)&fcb[48 + c16][32 + g8];

    ATT_NI(0) ATT_NI(1) ATT_NI(2) ATT_NI(3)
    __syncthreads();

    // out-MLP via MFMA: out[64 x 16pts] = fold(att2_w) @ aggb; wave wid -> mi
    {
        int o = (wid << 4) + c16;
        float sc = att_g[o] * BN_RS;
        const float* wr0 = att_w + o * D + g8;
        const float* wr1 = att_w + o * D + 32 + g8;
        union { bf16x8 v; uint4 u; } aw0, aw1;
        aw0.u.x = pk2(wr0[0] * sc, wr0[1] * sc);
        aw0.u.y = pk2(wr0[2] * sc, wr0[3] * sc);
        aw0.u.z = pk2(wr0[4] * sc, wr0[5] * sc);
        aw0.u.w = pk2(wr0[6] * sc, wr0[7] * sc);
        aw1.u.x = pk2(wr1[0] * sc, wr1[1] * sc);
        aw1.u.y = pk2(wr1[2] * sc, wr1[3] * sc);
        aw1.u.z = pk2(wr1[4] * sc, wr1[5] * sc);
        aw1.u.w = pk2(wr1[6] * sc, wr1[7] * sc);
        bf16x8 bb0 = *(const bf16x8*)&aggb[c16][     g8];
        bf16x8 bb1 = *(const bf16x8*)&aggb[c16][32 + g8];
        f32x4 acc = *(const f32x4*)&abf[(wid << 4) + g4];
        acc = MF(aw0.v, bb0, acc);
        acc = MF(aw1.v, bb1, acc);
        int p = (blockIdx.x << 4) + c16;
        int o0 = (wid << 4) + g4;
        float4 st;
        st.x = fmaxf(acc[0], 0.f);
        st.y = fmaxf(acc[1], 0.f);
        st.z = fmaxf(acc[2], 0.f);
        st.w = fmaxf(acc[3], 0.f);
        *(float4*)(fagg2 + (((size_t)p) << 6) + o0) = st;
    }
}

// ---------------- Kernel 4: out = leaky(bn(mlp2@f_agg2) + bn(sc@feature)) ----------------
__global__ __launch_bounds__(256) void k4_final(
    const float* __restrict__ fagg2, const float* __restrict__ feature,
    const float* __restrict__ w_mlp2, const float* __restrict__ g_mlp2, const float* __restrict__ b_mlp2,
    const float* __restrict__ w_sc, const float* __restrict__ g_sc, const float* __restrict__ b_sc,
    float* __restrict__ out)
{
    int tid = threadIdx.x;
    int gb = blockIdx.x;
    int o0 = (gb & 3) << 5;                 // uniform (SGPR)
    int p  = ((gb >> 2) << 8) + tid;
    int b = p >> 15, n = p & (NPTS - 1);

    float xr[D];
    {
        const float4* src = (const float4*)(fagg2 + ((size_t)p << 6));
#pragma unroll
        for (int j = 0; j < D / 4; ++j) {
            float4 v = src[j];
            xr[4 * j + 0] = v.x; xr[4 * j + 1] = v.y;
            xr[4 * j + 2] = v.z; xr[4 * j + 3] = v.w;
        }
    }
    float xf[CIN];
#pragma unroll
    for (int c = 0; c < CIN; ++c)
        xf[c] = feature[((b * CIN + c) << 15) + n];

#pragma unroll 4
    for (int j = 0; j < 32; ++j) {
        int o = o0 + j;                     // uniform -> s_load weight rows
        float s0 = 0.f, s1 = 0.f, s2 = 0.f, s3 = 0.f;
        const float* wm = w_mlp2 + o * D;
#pragma unroll
        for (int c = 0; c < D; c += 4) {
            s0 = fmaf(wm[c + 0], xr[c + 0], s0);
            s1 = fmaf(wm[c + 1], xr[c + 1], s1);
            s2 = fmaf(wm[c + 2], xr[c + 2], s2);
            s3 = fmaf(wm[c + 3], xr[c + 3], s3);
        }
        float aA = (s0 + s1) + (s2 + s3);
        float t0 = 0.f, t1 = 0.f, t2 = 0.f, t3 = 0.f;
        const float* ws = w_sc + o * CIN;
#pragma unroll
        for (int c = 0; c < CIN; c += 4) {
            t0 = fmaf(ws[c + 0], xf[c + 0], t0);
            t1 = fmaf(ws[c + 1], xf[c + 1], t1);
            t2 = fmaf(ws[c + 2], xf[c + 2], t2);
            t3 = fmaf(ws[c + 3], xf[c + 3], t3);
        }
        float aB = (t0 + t1) + (t2 + t3);
        float v = fmaf(aA, g_mlp2[o] * BN_RS, b_mlp2[o])
                + fmaf(aB, g_sc[o] * BN_RS, b_sc[o]);
        v = (v >= 0.0f) ? v : 0.2f * v;
        out[((b * DOUT + o) << 15) + n] = v;
    }
}

extern "C" void kernel_launch(void* const* d_in, const int* in_sizes, int n_in,
                              void* d_out, int out_size, void* d_ws, size_t ws_size,
                              hipStream_t stream) {
    const float* feature = (const float*)d_in[0];
    const float* xyz     = (const float*)d_in[1];
    const float* w_mlp1  = (const float*)d_in[2];
    const float* g_mlp1  = (const float*)d_in[3];
    const float* b_mlp1  = (const float*)d_in[4];
    const float* bb_w1   = (const float*)d_in[5];
    const float* bb_g1   = (const float*)d_in[6];
    const float* bb_b1   = (const float*)d_in[7];
    const float* att1_fc = (const float*)d_in[8];
    const float* att1_w  = (const float*)d_in[9];
    const float* att1_g  = (const float*)d_in[10];
    const float* att1_b  = (const float*)d_in[11];
    const float* bb_w2   = (const float*)d_in[12];
    const float* bb_g2   = (const float*)d_in[13];
    const float* bb_b2   = (const float*)d_in[14];
    const float* att2_fc = (const float*)d_in[15];
    const float* att2_w  = (const float*)d_in[16];
    const float* att2_g  = (const float*)d_in[17];
    const float* att2_b  = (const float*)d_in[18];
    const float* w_mlp2  = (const float*)d_in[19];
    const float* g_mlp2  = (const float*)d_in[20];
    const float* b_mlp2  = (const float*)d_in[21];
    const float* w_sc    = (const float*)d_in[22];
    const float* g_sc    = (const float*)d_in[23];
    const float* b_sc    = (const float*)d_in[24];
    const int*   nidx    = (const int*)d_in[25];
    float* out = (float*)d_out;

    ushort* f_pc_bf  = (ushort*)d_ws;                            // B*N*32 bf16 = 4MB
    ushort* f_agg_bf = f_pc_bf + (size_t)NB * NPTS * 32;         // B*N*32 bf16 = 4MB
    float*  fagg2    = (float*)(f_agg_bf + (size_t)NB * NPTS * 32); // B*N*64 f32 = 16MB

    k1_mlp1<<<NB * NPTS / 256, 256, 0, stream>>>(feature, w_mlp1, g_mlp1, b_mlp1, f_pc_bf);
    k2_stage1<<<NB * NPTS / 16, 256, 0, stream>>>(xyz, nidx, f_pc_bf,
                                                  bb_w1, bb_g1, bb_b1,
                                                  att1_fc, att1_w, att1_g, att1_b, f_agg_bf);
    k3_stage2<<<NB * NPTS / 16, 256, 0, stream>>>(xyz, nidx, f_agg_bf,
                                                  bb_w1, bb_g1, bb_b1,
                                                  bb_w2, bb_g2, bb_b2,
                                                  att2_fc, att2_w, att2_g, att2_b, fagg2);
    k4_final<<<NB * NPTS * 4 / 256, 256, 0, stream>>>(fagg2, feature,
                                                      w_mlp2, g_mlp2, b_mlp2,
                                                      w_sc, g_sc, b_sc, out);
}

// Round 9
// 189.802 us; speedup vs baseline: 2.9763x; 1.3965x over previous
//
#include <hip/hip_runtime.h>
#include <math.h>

#define NPTS 32768
#define NB 2
#define CIN 32
#define H 32
#define D 64
#define DOUT 128
#define BN_RS 0.99999500003749981f   // 1/sqrt(1 + 1e-5)

typedef __attribute__((ext_vector_type(8))) short bf16x8;
typedef __attribute__((ext_vector_type(4))) short bf16x4;
typedef __attribute__((ext_vector_type(4))) float f32x4;

__device__ __forceinline__ ushort f2b(float f) {
    union { float f; unsigned u; } v; v.f = f;
    unsigned r = v.u + 0x7fffu + ((v.u >> 16) & 1u);   // RNE
    return (ushort)(r >> 16);
}
__device__ __forceinline__ float b2f(ushort u) {
    union { unsigned u; float f; } v; v.u = ((unsigned)u) << 16; return v.f;
}
// pack two f32 -> bf16x2 dword (round-half-up + v_perm_b32)
__device__ __forceinline__ unsigned pk2(float f0, float f1) {
    unsigned a = __builtin_bit_cast(unsigned, f0) + 0x8000u;
    unsigned b = __builtin_bit_cast(unsigned, f1) + 0x8000u;
    return __builtin_amdgcn_perm(b, a, 0x07060302);
}
// DPP row_ror add: x += rotate_within_16(x, N); ctrl immediate via template
template <int CTRL>
__device__ __forceinline__ float dpp_add(float x) {
    int m = __builtin_amdgcn_update_dpp(0, __builtin_bit_cast(int, x), CTRL, 0xF, 0xF, true);
    return x + __builtin_bit_cast(float, m);
}
#define MF(a, b, c) __builtin_amdgcn_mfma_f32_16x16x32_bf16(a, b, c, 0, 0, 0)

// relative-pos encoding channel c -> DST
#define FXYZ(c, DST) { const float* _w = bb_w1 + (c) * 10;                        \
    float _a = _w[0] * dist; _a = fmaf(_w[1], r0, _a); _a = fmaf(_w[2], r1, _a);  \
    _a = fmaf(_w[3], r2, _a); _a = fmaf(_w[4], c0, _a); _a = fmaf(_w[5], c1, _a); \
    _a = fmaf(_w[6], c2, _a); _a = fmaf(_w[7], x0, _a); _a = fmaf(_w[8], x1, _a); \
    _a = fmaf(_w[9], x2, _a);                                                     \
    DST = fmaxf(fmaf(_a, bb_g1[(c)] * BN_RS, bb_b1[(c)]), 0.f); }
#define FXYZ4X(c) FXYZ(c, fx[(c)]) FXYZ((c)+1, fx[(c)+1]) FXYZ((c)+2, fx[(c)+2]) FXYZ((c)+3, fx[(c)+3])

// A-fragment load from global fc weights (no fold), row c16 + 16*mi, k-slice ks
#define LDA(mi, ks, DST) {                                                        \
    const float* _wr = att_fc + ((mi) * 16 + c16) * D + (ks) * 32 + g8;           \
    float4 _wa = *(const float4*)&_wr[0];                                         \
    float4 _wb = *(const float4*)&_wr[4];                                         \
    union { bf16x8 v; uint4 u; } _t;                                              \
    _t.u.x = pk2(_wa.x, _wa.y); _t.u.y = pk2(_wa.z, _wa.w);                       \
    _t.u.z = pk2(_wb.x, _wb.y); _t.u.w = pk2(_wb.z, _wb.w);                       \
    DST = _t.v; }

// ---- attention core: MFMA logits -> exp -> 16-lane DPP ring reduce -> agg (bf16 LDS) ----
#define RED(E, Q) E = dpp_add<0x128>(E); Q = dpp_add<0x128>(Q);                   \
                  E = dpp_add<0x124>(E); Q = dpp_add<0x124>(Q);                   \
                  E = dpp_add<0x122>(E); Q = dpp_add<0x122>(Q);                   \
                  E = dpp_add<0x121>(E); Q = dpp_add<0x121>(Q);
#define AWR(mi, r, E, Q) if (c16 == (mi) * 4 + (r)) aggb[ptl][(mi) * 16 + g4 + (r)] = f2b(__fdividef(Q, E));
#define ATT_MI(mi, AC) {                                                          \
    float e0 = __expf(AC[0]), e1 = __expf(AC[1]), e2 = __expf(AC[2]), e3 = __expf(AC[3]); \
    bf16x4 fv = *(const bf16x4*)&feat[wid][prow][(mi) * 16 + g4];                 \
    float q0 = e0 * b2f((ushort)fv[0]), q1 = e1 * b2f((ushort)fv[1]);             \
    float q2 = e2 * b2f((ushort)fv[2]), q3 = e3 * b2f((ushort)fv[3]);             \
    RED(e0, q0) RED(e1, q1) RED(e2, q2) RED(e3, q3)                               \
    AWR(mi, 0, e0, q0) AWR(mi, 1, e1, q1) AWR(mi, 2, e2, q2) AWR(mi, 3, e3, q3) }
#define ATT_NI(ni) {                                                              \
    int prow = (ni) * 16 + c16;                                                   \
    int ptl  = (wid << 2) + (ni);                                                 \
    bf16x8 b0 = *(const bf16x8*)&feat[wid][prow][g8];                             \
    bf16x8 b1 = *(const bf16x8*)&feat[wid][prow][32 + g8];                        \
    f32x4 ac0 = zf4, ac1 = zf4, ac2 = zf4, ac3 = zf4;                             \
    ac0 = MF(afc0_0, b0, ac0); ac1 = MF(afc1_0, b0, ac1);                         \
    ac2 = MF(afc2_0, b0, ac2); ac3 = MF(afc3_0, b0, ac3);                         \
    ac0 = MF(afc0_1, b1, ac0); ac1 = MF(afc1_1, b1, ac1);                         \
    ac2 = MF(afc2_1, b1, ac2); ac3 = MF(afc3_1, b1, ac3);                         \
    ATT_MI(0, ac0) ATT_MI(1, ac1) ATT_MI(2, ac2) ATT_MI(3, ac3) }

// ---------------- Kernel 1: f_pc = relu(bn(w_mlp1 @ feature)) -> bf16 (B*N,32) ----------------
// Also emits featpm: point-major bf16 copy of the raw feature (for k4's shortcut B-frags).
__global__ __launch_bounds__(256, 4) void k1_mlp1(
    const float* __restrict__ feature, const float* __restrict__ w_mlp1,
    const float* __restrict__ g_mlp1, const float* __restrict__ b_mlp1,
    ushort* __restrict__ f_pc, ushort* __restrict__ featpm)
{
    int tid = threadIdx.x;
    int pg = blockIdx.x * 256 + tid;
    int b = pg >> 15, n = pg & (NPTS - 1);

    float x[CIN];
#pragma unroll
    for (int c = 0; c < CIN; ++c)
        x[c] = feature[((b * CIN + c) << 15) + n];

    float outv[CIN];
#pragma unroll
    for (int o = 0; o < CIN; ++o) {
        float s0 = 0.f, s1 = 0.f, s2 = 0.f, s3 = 0.f;
        const float* w = w_mlp1 + o * CIN;
#pragma unroll
        for (int c = 0; c < CIN; c += 4) {
            s0 = fmaf(w[c + 0], x[c + 0], s0);
            s1 = fmaf(w[c + 1], x[c + 1], s1);
            s2 = fmaf(w[c + 2], x[c + 2], s2);
            s3 = fmaf(w[c + 3], x[c + 3], s3);
        }
        float acc = (s0 + s1) + (s2 + s3);
        outv[o] = fmaxf(fmaf(acc, g_mlp1[o] * BN_RS, b_mlp1[o]), 0.f);
    }
    uint4* dst = (uint4*)(f_pc + ((size_t)pg << 5));
    uint4* dst2 = (uint4*)(featpm + ((size_t)pg << 5));
#pragma unroll
    for (int j = 0; j < 4; ++j) {
        uint4 u;
        u.x = pk2(outv[8 * j + 0], outv[8 * j + 1]);
        u.y = pk2(outv[8 * j + 2], outv[8 * j + 3]);
        u.z = pk2(outv[8 * j + 4], outv[8 * j + 5]);
        u.w = pk2(outv[8 * j + 6], outv[8 * j + 7]);
        dst[j] = u;
        uint4 v;
        v.x = pk2(x[8 * j + 0], x[8 * j + 1]);
        v.y = pk2(x[8 * j + 2], x[8 * j + 3]);
        v.z = pk2(x[8 * j + 4], x[8 * j + 5]);
        v.w = pk2(x[8 * j + 6], x[8 * j + 7]);
        dst2[j] = v;
    }
}

// ---------------- Kernel 2: stage-1 -> f_agg bf16 (B*N, 32) ----------------
// Block = 16 points, 4 waves; wave = 4 points x 16 neighbors (64 positions).
__global__ __launch_bounds__(256, 4) void k2_stage1(
    const float* __restrict__ xyz, const int* __restrict__ nidx,
    const ushort* __restrict__ f_pc,
    const float* __restrict__ bb_w1, const float* __restrict__ bb_g1, const float* __restrict__ bb_b1,
    const float* __restrict__ att_fc,
    const float* __restrict__ att_w, const float* __restrict__ att_g, const float* __restrict__ att_b,
    ushort* __restrict__ f_agg)
{
    __shared__ __align__(16) ushort feat[4][64][72];   // per-wave 64 pos x 64 ch bf16 (pad 72)
    __shared__ __align__(16) ushort aggb[16][72];      // pooled agg bf16 per point

    int tid = threadIdx.x;
    int wid = tid >> 6, lane = tid & 63;
    int g = lane >> 4, c16 = lane & 15;
    int g4 = g << 2, g8 = g << 3;
    f32x4 zf4 = {0.f, 0.f, 0.f, 0.f};

    int pb = (blockIdx.x << 4) + (wid << 2) + g;       // this lane's build point
    int b = pb >> 15, n = pb & (NPTS - 1);
    int nb = nidx[((size_t)pb << 4) + c16];

    // issue neighbor-feature gather early (bf16, 64B row)
    const bf16x8* gsrc = (const bf16x8*)(f_pc + (((size_t)(b * NPTS + nb)) << 5));
    bf16x8 gv0 = gsrc[0], gv1 = gsrc[1], gv2 = gsrc[2], gv3 = gsrc[3];

    // f_xyz (ch 32..63)
    const float* cx = xyz + (size_t)(b * NPTS + n) * 3;
    const float* nx = xyz + (size_t)(b * NPTS + nb) * 3;
    float c0 = cx[0], c1 = cx[1], c2 = cx[2];
    float x0 = nx[0], x1 = nx[1], x2 = nx[2];
    float r0 = c0 - x0, r1 = c1 - x1, r2 = c2 - x2;
    float dist = sqrtf(r0 * r0 + r1 * r1 + r2 * r2);
    float fx[H];
    FXYZ4X(0) FXYZ4X(4) FXYZ4X(8) FXYZ4X(12) FXYZ4X(16) FXYZ4X(20) FXYZ4X(24) FXYZ4X(28)
#pragma unroll
    for (int j = 0; j < 4; ++j) {
        uint4 u;
        u.x = pk2(fx[8 * j + 0], fx[8 * j + 1]);
        u.y = pk2(fx[8 * j + 2], fx[8 * j + 3]);
        u.z = pk2(fx[8 * j + 4], fx[8 * j + 5]);
        u.w = pk2(fx[8 * j + 6], fx[8 * j + 7]);
        *(uint4*)&feat[wid][lane][32 + 8 * j] = u;
    }
    // gathered neighbor features (ch 0..31)
    *(bf16x8*)&feat[wid][lane][0]  = gv0;
    *(bf16x8*)&feat[wid][lane][8]  = gv1;
    *(bf16x8*)&feat[wid][lane][16] = gv2;
    *(bf16x8*)&feat[wid][lane][24] = gv3;

    // fc A-fragments from global (L2-resident weights)
    bf16x8 afc0_0, afc0_1, afc1_0, afc1_1, afc2_0, afc2_1, afc3_0, afc3_1;
    LDA(0, 0, afc0_0) LDA(0, 1, afc0_1)
    LDA(1, 0, afc1_0) LDA(1, 1, afc1_1)
    LDA(2, 0, afc2_0) LDA(2, 1, afc2_1)
    LDA(3, 0, afc3_0) LDA(3, 1, afc3_1)

    ATT_NI(0) ATT_NI(1) ATT_NI(2) ATT_NI(3)
    __syncthreads();

    // out-MLP via MFMA: out[32 x 16pts] = fold(att_w)[32x64] @ aggb[64x16]; waves 0,1 -> mi
    if (wid < 2) {
        int o = (wid << 4) + c16;
        float sc = att_g[o] * BN_RS;
        const float* wr0 = att_w + o * D + g8;
        const float* wr1 = att_w + o * D + 32 + g8;
        union { bf16x8 v; uint4 u; } aw0, aw1;
        aw0.u.x = pk2(wr0[0] * sc, wr0[1] * sc);
        aw0.u.y = pk2(wr0[2] * sc, wr0[3] * sc);
        aw0.u.z = pk2(wr0[4] * sc, wr0[5] * sc);
        aw0.u.w = pk2(wr0[6] * sc, wr0[7] * sc);
        aw1.u.x = pk2(wr1[0] * sc, wr1[1] * sc);
        aw1.u.y = pk2(wr1[2] * sc, wr1[3] * sc);
        aw1.u.z = pk2(wr1[4] * sc, wr1[5] * sc);
        aw1.u.w = pk2(wr1[6] * sc, wr1[7] * sc);
        bf16x8 bb0 = *(const bf16x8*)&aggb[c16][     g8];
        bf16x8 bb1 = *(const bf16x8*)&aggb[c16][32 + g8];
        f32x4 acc = *(const f32x4*)&att_b[(wid << 4) + g4];
        acc = MF(aw0.v, bb0, acc);
        acc = MF(aw1.v, bb1, acc);
        int p = (blockIdx.x << 4) + c16;
        int o0 = (wid << 4) + g4;
        uint2 st;
        st.x = pk2(fmaxf(acc[0], 0.f), fmaxf(acc[1], 0.f));
        st.y = pk2(fmaxf(acc[2], 0.f), fmaxf(acc[3], 0.f));
        *(uint2*)(f_agg + (((size_t)p) << 5) + o0) = st;
    }
}

// ---------------- Kernel 3: stage-2 -> fagg2 bf16 point-major (B*N, 64) ----------------
__global__ __launch_bounds__(256, 4) void k3_stage2(
    const float* __restrict__ xyz, const int* __restrict__ nidx,
    const ushort* __restrict__ f_agg,
    const float* __restrict__ bb_w1, const float* __restrict__ bb_g1, const float* __restrict__ bb_b1,
    const float* __restrict__ bb_w2, const float* __restrict__ bb_g2, const float* __restrict__ bb_b2,
    const float* __restrict__ att_fc,
    const float* __restrict__ att_w, const float* __restrict__ att_g, const float* __restrict__ att_b,
    ushort* __restrict__ fagg2b)
{
    __shared__ __align__(16) ushort feat[4][64][72];
    __shared__ __align__(16) ushort aggb[16][72];

    int tid = threadIdx.x;
    int wid = tid >> 6, lane = tid & 63;
    int g = lane >> 4, c16 = lane & 15;
    int g4 = g << 2, g8 = g << 3;
    f32x4 zf4 = {0.f, 0.f, 0.f, 0.f};

    int pb = (blockIdx.x << 4) + (wid << 2) + g;
    int b = pb >> 15, n = pb & (NPTS - 1);
    int nb = nidx[((size_t)pb << 4) + c16];

    const bf16x8* gsrc = (const bf16x8*)(f_agg + (((size_t)(b * NPTS + nb)) << 5));
    bf16x8 gv0 = gsrc[0], gv1 = gsrc[1], gv2 = gsrc[2], gv3 = gsrc[3];

    const float* cx = xyz + (size_t)(b * NPTS + n) * 3;
    const float* nx = xyz + (size_t)(b * NPTS + nb) * 3;
    float c0 = cx[0], c1 = cx[1], c2 = cx[2];
    float x0 = nx[0], x1 = nx[1], x2 = nx[2];
    float r0 = c0 - x0, r1 = c1 - x1, r2 = c2 - x2;
    float dist = sqrtf(r0 * r0 + r1 * r1 + r2 * r2);
    float fx[H];
    FXYZ4X(0) FXYZ4X(4) FXYZ4X(8) FXYZ4X(12) FXYZ4X(16) FXYZ4X(20) FXYZ4X(24) FXYZ4X(28)
    // stage fx (pre-bb_w2) into slots 32..63
#pragma unroll
    for (int j = 0; j < 4; ++j) {
        uint4 u;
        u.x = pk2(fx[8 * j + 0], fx[8 * j + 1]);
        u.y = pk2(fx[8 * j + 2], fx[8 * j + 3]);
        u.z = pk2(fx[8 * j + 4], fx[8 * j + 5]);
        u.w = pk2(fx[8 * j + 6], fx[8 * j + 7]);
        *(uint4*)&feat[wid][lane][32 + 8 * j] = u;
    }

    // bb_w2 A-fragments from global (folded, bf16); mi = 0,1
    union { bf16x8 v; uint4 u; } aw20, aw21;
    {
        int o = c16;
        float sc2 = bb_g2[o] * BN_RS;
        const float* wr = bb_w2 + o * H + g8;
        aw20.u.x = pk2(wr[0] * sc2, wr[1] * sc2);
        aw20.u.y = pk2(wr[2] * sc2, wr[3] * sc2);
        aw20.u.z = pk2(wr[4] * sc2, wr[5] * sc2);
        aw20.u.w = pk2(wr[6] * sc2, wr[7] * sc2);
    }
    {
        int o = 16 + c16;
        float sc2 = bb_g2[o] * BN_RS;
        const float* wr = bb_w2 + o * H + g8;
        aw21.u.x = pk2(wr[0] * sc2, wr[1] * sc2);
        aw21.u.y = pk2(wr[2] * sc2, wr[3] * sc2);
        aw21.u.z = pk2(wr[4] * sc2, wr[5] * sc2);
        aw21.u.w = pk2(wr[6] * sc2, wr[7] * sc2);
    }
    // read all fx B-fragments BEFORE overwriting slots 32..63
    bf16x8 bfx0 = *(const bf16x8*)&feat[wid][ 0 + c16][32 + g8];
    bf16x8 bfx1 = *(const bf16x8*)&feat[wid][16 + c16][32 + g8];
    bf16x8 bfx2 = *(const bf16x8*)&feat[wid][32 + c16][32 + g8];
    bf16x8 bfx3 = *(const bf16x8*)&feat[wid][48 + c16][32 + g8];
    f32x4 bi0 = *(const f32x4*)&bb_b2[     g4];
    f32x4 bi1 = *(const f32x4*)&bb_b2[16 + g4];
    f32x4 a00 = MF(aw20.v, bfx0, bi0);
    f32x4 a01 = MF(aw20.v, bfx1, bi0);
    f32x4 a02 = MF(aw20.v, bfx2, bi0);
    f32x4 a03 = MF(aw20.v, bfx3, bi0);
    f32x4 a10 = MF(aw21.v, bfx0, bi1);
    f32x4 a11 = MF(aw21.v, bfx1, bi1);
    f32x4 a12 = MF(aw21.v, bfx2, bi1);
    f32x4 a13 = MF(aw21.v, bfx3, bi1);
#define WB(mi, ni, A) { uint2 w;                                                  \
    w.x = pk2(fmaxf(A[0], 0.f), fmaxf(A[1], 0.f));                                \
    w.y = pk2(fmaxf(A[2], 0.f), fmaxf(A[3], 0.f));                                \
    *(uint2*)&feat[wid][(ni) * 16 + c16][32 + (mi) * 16 + g4] = w; }
    WB(0, 0, a00) WB(0, 1, a01) WB(0, 2, a02) WB(0, 3, a03)
    WB(1, 0, a10) WB(1, 1, a11) WB(1, 2, a12) WB(1, 3, a13)
#undef WB

    // gathered f_agg neighbor features (ch 0..31)
    *(bf16x8*)&feat[wid][lane][0]  = gv0;
    *(bf16x8*)&feat[wid][lane][8]  = gv1;
    *(bf16x8*)&feat[wid][lane][16] = gv2;
    *(bf16x8*)&feat[wid][lane][24] = gv3;

    bf16x8 afc0_0, afc0_1, afc1_0, afc1_1, afc2_0, afc2_1, afc3_0, afc3_1;
    LDA(0, 0, afc0_0) LDA(0, 1, afc0_1)
    LDA(1, 0, afc1_0) LDA(1, 1, afc1_1)
    LDA(2, 0, afc2_0) LDA(2, 1, afc2_1)
    LDA(3, 0, afc3_0) LDA(3, 1, afc3_1)

    ATT_NI(0) ATT_NI(1) ATT_NI(2) ATT_NI(3)
    __syncthreads();

    // out-MLP via MFMA: out[64 x 16pts] = fold(att2_w) @ aggb; wave wid -> mi; bf16 store
    {
        int o = (wid << 4) + c16;
        float sc = att_g[o] * BN_RS;
        const float* wr0 = att_w + o * D + g8;
        const float* wr1 = att_w + o * D + 32 + g8;
        union { bf16x8 v; uint4 u; } aw0, aw1;
        aw0.u.x = pk2(wr0[0] * sc, wr0[1] * sc);
        aw0.u.y = pk2(wr0[2] * sc, wr0[3] * sc);
        aw0.u.z = pk2(wr0[4] * sc, wr0[5] * sc);
        aw0.u.w = pk2(wr0[6] * sc, wr0[7] * sc);
        aw1.u.x = pk2(wr1[0] * sc, wr1[1] * sc);
        aw1.u.y = pk2(wr1[2] * sc, wr1[3] * sc);
        aw1.u.z = pk2(wr1[4] * sc, wr1[5] * sc);
        aw1.u.w = pk2(wr1[6] * sc, wr1[7] * sc);
        bf16x8 bb0 = *(const bf16x8*)&aggb[c16][     g8];
        bf16x8 bb1 = *(const bf16x8*)&aggb[c16][32 + g8];
        f32x4 acc = *(const f32x4*)&att_b[(wid << 4) + g4];
        acc = MF(aw0.v, bb0, acc);
        acc = MF(aw1.v, bb1, acc);
        int p = (blockIdx.x << 4) + c16;
        int o0 = (wid << 4) + g4;
        uint2 st;
        st.x = pk2(fmaxf(acc[0], 0.f), fmaxf(acc[1], 0.f));
        st.y = pk2(fmaxf(acc[2], 0.f), fmaxf(acc[3], 0.f));
        *(uint2*)(fagg2b + (((size_t)p) << 6) + o0) = st;
    }
}

// ---------------- Kernel 4: MFMA GEMM out[128 x pts] = Wcat[128x96] @ X[96 x pts] ----------------
// Block = 64 points, 4 waves; wave wid -> output rows [wid*32, wid*32+32).
__global__ __launch_bounds__(256, 4) void k4_final(
    const ushort* __restrict__ fagg2b, const ushort* __restrict__ featpm,
    const float* __restrict__ w_mlp2, const float* __restrict__ g_mlp2, const float* __restrict__ b_mlp2,
    const float* __restrict__ w_sc, const float* __restrict__ g_sc, const float* __restrict__ b_sc,
    float* __restrict__ out)
{
    int tid = threadIdx.x;
    int wid = tid >> 6, lane = tid & 63;
    int c16 = lane & 15, g = lane >> 4;
    int g4 = g << 2, g8 = g << 3;
    int p0 = blockIdx.x << 6;
    int o0 = wid << 5;

    // A-fragments: mi in {0,1}, ks in {0,1,2}; folded bf16
    union { bf16x8 v; uint4 u; } A[2][3];
#pragma unroll
    for (int mi = 0; mi < 2; ++mi) {
        int o = o0 + mi * 16 + c16;
        float sm = g_mlp2[o] * BN_RS, ss = g_sc[o] * BN_RS;
        const float* wm = w_mlp2 + o * D;
        const float* ws = w_sc + o * CIN;
#pragma unroll
        for (int ks = 0; ks < 2; ++ks) {
            float4 wa = *(const float4*)&wm[ks * 32 + g8];
            float4 wb = *(const float4*)&wm[ks * 32 + g8 + 4];
            A[mi][ks].u.x = pk2(wa.x * sm, wa.y * sm);
            A[mi][ks].u.y = pk2(wa.z * sm, wa.w * sm);
            A[mi][ks].u.z = pk2(wb.x * sm, wb.y * sm);
            A[mi][ks].u.w = pk2(wb.z * sm, wb.w * sm);
        }
        float4 wa = *(const float4*)&ws[g8];
        float4 wb = *(const float4*)&ws[g8 + 4];
        A[mi][2].u.x = pk2(wa.x * ss, wa.y * ss);
        A[mi][2].u.y = pk2(wa.z * ss, wa.w * ss);
        A[mi][2].u.z = pk2(wb.x * ss, wb.y * ss);
        A[mi][2].u.w = pk2(wb.z * ss, wb.w * ss);
    }
    // bias per C-reg row
    float bias0[4], bias1[4];
#pragma unroll
    for (int r = 0; r < 4; ++r) {
        int oa = o0 + g4 + r;
        int ob = o0 + 16 + g4 + r;
        bias0[r] = b_mlp2[oa] + b_sc[oa];
        bias1[r] = b_mlp2[ob] + b_sc[ob];
    }

    int bb = p0 >> 15;                      // whole block same batch (p0 64-aligned)
#pragma unroll
    for (int ni = 0; ni < 4; ++ni) {
        int pt = p0 + ni * 16 + c16;
        bf16x8 B0 = *(const bf16x8*)&fagg2b[((size_t)pt << 6) + g8];
        bf16x8 B1 = *(const bf16x8*)&fagg2b[((size_t)pt << 6) + 32 + g8];
        bf16x8 B2 = *(const bf16x8*)&featpm[((size_t)pt << 5) + g8];
        f32x4 acc0 = {bias0[0], bias0[1], bias0[2], bias0[3]};
        f32x4 acc1 = {bias1[0], bias1[1], bias1[2], bias1[3]};
        acc0 = MF(A[0][0].v, B0, acc0);
        acc0 = MF(A[0][1].v, B1, acc0);
        acc0 = MF(A[0][2].v, B2, acc0);
        acc1 = MF(A[1][0].v, B0, acc1);
        acc1 = MF(A[1][1].v, B1, acc1);
        acc1 = MF(A[1][2].v, B2, acc1);
        int nn = pt & (NPTS - 1);
#pragma unroll
        for (int r = 0; r < 4; ++r) {
            float v0 = acc0[r];
            v0 = (v0 >= 0.f) ? v0 : 0.2f * v0;
            out[((bb * DOUT + o0 + g4 + r) << 15) + nn] = v0;
            float v1 = acc1[r];
            v1 = (v1 >= 0.f) ? v1 : 0.2f * v1;
            out[((bb * DOUT + o0 + 16 + g4 + r) << 15) + nn] = v1;
        }
    }
}

extern "C" void kernel_launch(void* const* d_in, const int* in_sizes, int n_in,
                              void* d_out, int out_size, void* d_ws, size_t ws_size,
                              hipStream_t stream) {
    const float* feature = (const float*)d_in[0];
    const float* xyz     = (const float*)d_in[1];
    const float* w_mlp1  = (const float*)d_in[2];
    const float* g_mlp1  = (const float*)d_in[3];
    const float* b_mlp1  = (const float*)d_in[4];
    const float* bb_w1   = (const float*)d_in[5];
    const float* bb_g1   = (const float*)d_in[6];
    const float* bb_b1   = (const float*)d_in[7];
    const float* att1_fc = (const float*)d_in[8];
    const float* att1_w  = (const float*)d_in[9];
    const float* att1_g  = (const float*)d_in[10];
    const float* att1_b  = (const float*)d_in[11];
    const float* bb_w2   = (const float*)d_in[12];
    const float* bb_g2   = (const float*)d_in[13];
    const float* bb_b2   = (const float*)d_in[14];
    const float* att2_fc = (const float*)d_in[15];
    const float* att2_w  = (const float*)d_in[16];
    const float* att2_g  = (const float*)d_in[17];
    const float* att2_b  = (const float*)d_in[18];
    const float* w_mlp2  = (const float*)d_in[19];
    const float* g_mlp2  = (const float*)d_in[20];
    const float* b_mlp2  = (const float*)d_in[21];
    const float* w_sc    = (const float*)d_in[22];
    const float* g_sc    = (const float*)d_in[23];
    const float* b_sc    = (const float*)d_in[24];
    const int*   nidx    = (const int*)d_in[25];
    float* out = (float*)d_out;

    ushort* f_pc_bf  = (ushort*)d_ws;                              // B*N*32 bf16 = 4MB
    ushort* f_agg_bf = f_pc_bf + (size_t)NB * NPTS * 32;           // B*N*32 bf16 = 4MB
    ushort* featpm   = f_agg_bf + (size_t)NB * NPTS * 32;          // B*N*32 bf16 = 4MB
    ushort* fagg2b   = featpm + (size_t)NB * NPTS * 32;            // B*N*64 bf16 = 8MB

    k1_mlp1<<<NB * NPTS / 256, 256, 0, stream>>>(feature, w_mlp1, g_mlp1, b_mlp1,
                                                 f_pc_bf, featpm);
    k2_stage1<<<NB * NPTS / 16, 256, 0, stream>>>(xyz, nidx, f_pc_bf,
                                                  bb_w1, bb_g1, bb_b1,
                                                  att1_fc, att1_w, att1_g, att1_b, f_agg_bf);
    k3_stage2<<<NB * NPTS / 16, 256, 0, stream>>>(xyz, nidx, f_agg_bf,
                                                  bb_w1, bb_g1, bb_b1,
                                                  bb_w2, bb_g2, bb_b2,
                                                  att2_fc, att2_w, att2_g, att2_b, fagg2b);
    k4_final<<<NB * NPTS / 64, 256, 0, stream>>>(fagg2b, featpm,
                                                 w_mlp2, g_mlp2, b_mlp2,
                                                 w_sc, g_sc, b_sc, out);
}

// Round 10
// 167.360 us; speedup vs baseline: 3.3754x; 1.1341x over previous
//
#include <hip/hip_runtime.h>
#include <math.h>

#define NPTS 32768
#define NB 2
#define CIN 32
#define H 32
#define D 64
#define DOUT 128
#define BN_RS 0.99999500003749981f   // 1/sqrt(1 + 1e-5)

typedef __attribute__((ext_vector_type(8))) short bf16x8;
typedef __attribute__((ext_vector_type(4))) short bf16x4;
typedef __attribute__((ext_vector_type(4))) float f32x4;

__device__ __forceinline__ ushort f2b(float f) {
    union { float f; unsigned u; } v; v.f = f;
    unsigned r = v.u + 0x7fffu + ((v.u >> 16) & 1u);   // RNE
    return (ushort)(r >> 16);
}
__device__ __forceinline__ float b2f(ushort u) {
    union { unsigned u; float f; } v; v.u = ((unsigned)u) << 16; return v.f;
}
// pack two f32 -> bf16x2 dword (round-half-up + v_perm_b32); lo = f0, hi = f1
__device__ __forceinline__ unsigned pk2(float f0, float f1) {
    unsigned a = __builtin_bit_cast(unsigned, f0) + 0x8000u;
    unsigned b = __builtin_bit_cast(unsigned, f1) + 0x8000u;
    return __builtin_amdgcn_perm(b, a, 0x07060302);
}
// unpack (Q,E) dword -> Q/E
__device__ __forceinline__ float qdiv(unsigned u) {
    float q = __builtin_bit_cast(float, u << 16);
    float e = __builtin_bit_cast(float, u & 0xffff0000u);
    return __fdividef(q, e);
}
// DPP row_ror add: x += rotate_within_16(x, N); ctrl immediate via template
template <int CTRL>
__device__ __forceinline__ float dpp_add(float x) {
    int m = __builtin_amdgcn_update_dpp(0, __builtin_bit_cast(int, x), CTRL, 0xF, 0xF, true);
    return x + __builtin_bit_cast(float, m);
}
#define MF(a, b, c) __builtin_amdgcn_mfma_f32_16x16x32_bf16(a, b, c, 0, 0, 0)

// ---- FXYZ via MFMA: in10 staged bf16 at feat[..][32..63], w1p LDS A-frags ----
// WBX: write relu'd C tile (mi,ni) to feat cols 32..63
#define WBX(mi, ni, A) { uint2 _w;                                                \
    _w.x = pk2(fmaxf(A[0], 0.f), fmaxf(A[1], 0.f));                               \
    _w.y = pk2(fmaxf(A[2], 0.f), fmaxf(A[3], 0.f));                               \
    *(uint2*)&feat[wid][(ni) * 16 + c16][32 + (mi) * 16 + g4] = _w; }

// ---- attention core: MFMA logits -> exp -> DPP reduce -> packed (Q,E) in LDS ----
#define RED(E, Q) E = dpp_add<0x128>(E); Q = dpp_add<0x128>(Q);                   \
                  E = dpp_add<0x124>(E); Q = dpp_add<0x124>(Q);                   \
                  E = dpp_add<0x122>(E); Q = dpp_add<0x122>(Q);                   \
                  E = dpp_add<0x121>(E); Q = dpp_add<0x121>(Q);
#define AWR(mi, r, E, Q) if (c16 == (mi) * 4 + (r)) qe[ptl][(mi) * 16 + g4 + (r)] = pk2(Q, E);
#define ATT_MI(mi, AC) {                                                          \
    float e0 = __expf(AC[0]), e1 = __expf(AC[1]), e2 = __expf(AC[2]), e3 = __expf(AC[3]); \
    bf16x4 fv = *(const bf16x4*)&feat[wid][prow][(mi) * 16 + g4];                 \
    float q0 = e0 * b2f((ushort)fv[0]), q1 = e1 * b2f((ushort)fv[1]);             \
    float q2 = e2 * b2f((ushort)fv[2]), q3 = e3 * b2f((ushort)fv[3]);             \
    RED(e0, q0) RED(e1, q1) RED(e2, q2) RED(e3, q3)                               \
    AWR(mi, 0, e0, q0) AWR(mi, 1, e1, q1) AWR(mi, 2, e2, q2) AWR(mi, 3, e3, q3) }
#define ATT_NI(ni) {                                                              \
    int prow = (ni) * 16 + c16;                                                   \
    int ptl  = (wid << 2) + (ni);                                                 \
    bf16x8 b0 = *(const bf16x8*)&feat[wid][prow][g8];                             \
    bf16x8 b1 = *(const bf16x8*)&feat[wid][prow][32 + g8];                        \
    f32x4 ac0 = zf4, ac1 = zf4, ac2 = zf4, ac3 = zf4;                             \
    ac0 = MF(afc0_0, b0, ac0); ac1 = MF(afc1_0, b0, ac1);                         \
    ac2 = MF(afc2_0, b0, ac2); ac3 = MF(afc3_0, b0, ac3);                         \
    ac0 = MF(afc0_1, b1, ac0); ac1 = MF(afc1_1, b1, ac1);                         \
    ac2 = MF(afc2_1, b1, ac2); ac3 = MF(afc3_1, b1, ac3);                         \
    ATT_MI(0, ac0) ATT_MI(1, ac1) ATT_MI(2, ac2) ATT_MI(3, ac3) }

// build agg B-frags from qe (divide deferred to here)
#define QFRAG(bbv, base) {                                                        \
    uint4 _qa = *(const uint4*)&qe[c16][(base) + g8];                             \
    uint4 _qb = *(const uint4*)&qe[c16][(base) + g8 + 4];                         \
    bbv.u.x = pk2(qdiv(_qa.x), qdiv(_qa.y));                                      \
    bbv.u.y = pk2(qdiv(_qa.z), qdiv(_qa.w));                                      \
    bbv.u.z = pk2(qdiv(_qb.x), qdiv(_qb.y));                                      \
    bbv.u.w = pk2(qdiv(_qb.z), qdiv(_qb.w)); }

// ---------------- Kernel 1: f_pc = relu(bn(w_mlp1 @ feature)) -> bf16 (B*N,32) ----------------
__global__ __launch_bounds__(256, 4) void k1_mlp1(
    const float* __restrict__ feature, const float* __restrict__ w_mlp1,
    const float* __restrict__ g_mlp1, const float* __restrict__ b_mlp1,
    ushort* __restrict__ f_pc, ushort* __restrict__ featpm)
{
    int tid = threadIdx.x;
    int pg = blockIdx.x * 256 + tid;
    int b = pg >> 15, n = pg & (NPTS - 1);

    float x[CIN];
#pragma unroll
    for (int c = 0; c < CIN; ++c)
        x[c] = feature[((b * CIN + c) << 15) + n];

    float outv[CIN];
#pragma unroll
    for (int o = 0; o < CIN; ++o) {
        float s0 = 0.f, s1 = 0.f, s2 = 0.f, s3 = 0.f;
        const float* w = w_mlp1 + o * CIN;
#pragma unroll
        for (int c = 0; c < CIN; c += 4) {
            s0 = fmaf(w[c + 0], x[c + 0], s0);
            s1 = fmaf(w[c + 1], x[c + 1], s1);
            s2 = fmaf(w[c + 2], x[c + 2], s2);
            s3 = fmaf(w[c + 3], x[c + 3], s3);
        }
        float acc = (s0 + s1) + (s2 + s3);
        outv[o] = fmaxf(fmaf(acc, g_mlp1[o] * BN_RS, b_mlp1[o]), 0.f);
    }
    uint4* dst = (uint4*)(f_pc + ((size_t)pg << 5));
    uint4* dst2 = (uint4*)(featpm + ((size_t)pg << 5));
#pragma unroll
    for (int j = 0; j < 4; ++j) {
        uint4 u;
        u.x = pk2(outv[8 * j + 0], outv[8 * j + 1]);
        u.y = pk2(outv[8 * j + 2], outv[8 * j + 3]);
        u.z = pk2(outv[8 * j + 4], outv[8 * j + 5]);
        u.w = pk2(outv[8 * j + 6], outv[8 * j + 7]);
        dst[j] = u;
        uint4 v;
        v.x = pk2(x[8 * j + 0], x[8 * j + 1]);
        v.y = pk2(x[8 * j + 2], x[8 * j + 3]);
        v.z = pk2(x[8 * j + 4], x[8 * j + 5]);
        v.w = pk2(x[8 * j + 6], x[8 * j + 7]);
        dst2[j] = v;
    }
}

// ---------------- Kernel 2: stage-1 -> f_agg bf16 (B*N, 32) ----------------
__global__ __launch_bounds__(256, 3) void k2_stage1(
    const float* __restrict__ xyz, const int* __restrict__ nidx,
    const ushort* __restrict__ f_pc,
    const float* __restrict__ bb_w1, const float* __restrict__ bb_g1, const float* __restrict__ bb_b1,
    const float* __restrict__ att_fc,
    const float* __restrict__ att_w, const float* __restrict__ att_g, const float* __restrict__ att_b,
    ushort* __restrict__ f_agg)
{
    __shared__ __align__(16) ushort feat[4][64][72];   // per-wave 64 pos x 64 ch bf16
    __shared__ __align__(16) unsigned qe[16][68];      // packed (Q,E) per point x channel
    __shared__ __align__(16) ushort fcb[64][72];       // att1_fc bf16
    __shared__ __align__(16) ushort w1p[32][40];       // folded bb_w1, K-padded to 32

    int tid = threadIdx.x;
    for (int i = tid; i < D * D; i += 256) fcb[i >> 6][i & 63] = f2b(att_fc[i]);
    for (int i = tid; i < 32 * 32; i += 256) {
        int o = i >> 5, k = i & 31;
        w1p[o][k] = (k < 10) ? f2b(bb_w1[o * 10 + k] * (bb_g1[o] * BN_RS)) : (ushort)0;
    }
    __syncthreads();

    int wid = tid >> 6, lane = tid & 63;
    int g = lane >> 4, c16 = lane & 15;
    int g4 = g << 2, g8 = g << 3;
    f32x4 zf4 = {0.f, 0.f, 0.f, 0.f};

    int pb = (blockIdx.x << 4) + (wid << 2) + g;       // this lane's build point
    int b = pb >> 15, n = pb & (NPTS - 1);
    int nb = nidx[((size_t)pb << 4) + c16];

    // issue neighbor-feature gather early
    const bf16x8* gsrc = (const bf16x8*)(f_pc + (((size_t)(b * NPTS + nb)) << 5));
    bf16x8 gv0 = gsrc[0], gv1 = gsrc[1], gv2 = gsrc[2], gv3 = gsrc[3];

    // rel-pos inputs
    const float* cx = xyz + (size_t)(b * NPTS + n) * 3;
    const float* nx = xyz + (size_t)(b * NPTS + nb) * 3;
    float c0 = cx[0], c1 = cx[1], c2 = cx[2];
    float x0 = nx[0], x1 = nx[1], x2 = nx[2];
    float r0 = c0 - x0, r1 = c1 - x1, r2 = c2 - x2;
    float dist = sqrtf(r0 * r0 + r1 * r1 + r2 * r2);

    // stage in10 bf16 (zero-padded to 32) into feat cols 32..63
    {
        uint4 u0; u0.x = pk2(dist, r0); u0.y = pk2(r1, r2); u0.z = pk2(c0, c1); u0.w = pk2(c2, x0);
        uint4 u1; u1.x = pk2(x1, x2); u1.y = 0; u1.z = 0; u1.w = 0;
        uint4 z4; z4.x = 0; z4.y = 0; z4.z = 0; z4.w = 0;
        *(uint4*)&feat[wid][lane][32] = u0;
        *(uint4*)&feat[wid][lane][40] = u1;
        *(uint4*)&feat[wid][lane][48] = z4;
        *(uint4*)&feat[wid][lane][56] = z4;
    }
    // FXYZ MFMA: read all B-frags before overwrite
    {
        bf16x8 xb0 = *(const bf16x8*)&feat[wid][ 0 + c16][32 + g8];
        bf16x8 xb1 = *(const bf16x8*)&feat[wid][16 + c16][32 + g8];
        bf16x8 xb2 = *(const bf16x8*)&feat[wid][32 + c16][32 + g8];
        bf16x8 xb3 = *(const bf16x8*)&feat[wid][48 + c16][32 + g8];
        bf16x8 wa0 = *(const bf16x8*)&w1p[     c16][g8];
        bf16x8 wa1 = *(const bf16x8*)&w1p[16 + c16][g8];
        f32x4 bi0 = *(const f32x4*)&bb_b1[g4];
        f32x4 bi1 = *(const f32x4*)&bb_b1[16 + g4];
        f32x4 f00 = MF(wa0, xb0, bi0);
        f32x4 f01 = MF(wa0, xb1, bi0);
        f32x4 f02 = MF(wa0, xb2, bi0);
        f32x4 f03 = MF(wa0, xb3, bi0);
        f32x4 f10 = MF(wa1, xb0, bi1);
        f32x4 f11 = MF(wa1, xb1, bi1);
        f32x4 f12 = MF(wa1, xb2, bi1);
        f32x4 f13 = MF(wa1, xb3, bi1);
        WBX(0, 0, f00) WBX(0, 1, f01) WBX(0, 2, f02) WBX(0, 3, f03)
        WBX(1, 0, f10) WBX(1, 1, f11) WBX(1, 2, f12) WBX(1, 3, f13)
    }
    // gathered neighbor features (ch 0..31)
    *(bf16x8*)&feat[wid][lane][0]  = gv0;
    *(bf16x8*)&feat[wid][lane][8]  = gv1;
    *(bf16x8*)&feat[wid][lane][16] = gv2;
    *(bf16x8*)&feat[wid][lane][24] = gv3;

    // fc A-fragments from LDS
    bf16x8 afc0_0 = *(const bf16x8*)&fcb[ 0 + c16][     g8];
    bf16x8 afc0_1 = *(const bf16x8*)&fcb[ 0 + c16][32 + g8];
    bf16x8 afc1_0 = *(const bf16x8*)&fcb[16 + c16][     g8];
    bf16x8 afc1_1 = *(const bf16x8*)&fcb[16 + c16][32 + g8];
    bf16x8 afc2_0 = *(const bf16x8*)&fcb[32 + c16][     g8];
    bf16x8 afc2_1 = *(const bf16x8*)&fcb[32 + c16][32 + g8];
    bf16x8 afc3_0 = *(const bf16x8*)&fcb[48 + c16][     g8];
    bf16x8 afc3_1 = *(const bf16x8*)&fcb[48 + c16][32 + g8];

    ATT_NI(0) ATT_NI(1) ATT_NI(2) ATT_NI(3)
    __syncthreads();

    // out-MLP via MFMA: waves 0,1 -> mi; B-frags built with deferred divide
    if (wid < 2) {
        union { bf16x8 v; uint4 u; } bb0, bb1;
        QFRAG(bb0, 0)
        QFRAG(bb1, 32)
        int o = (wid << 4) + c16;
        float sc = att_g[o] * BN_RS;
        const float* wr0 = att_w + o * D + g8;
        const float* wr1 = att_w + o * D + 32 + g8;
        union { bf16x8 v; uint4 u; } aw0, aw1;
        aw0.u.x = pk2(wr0[0] * sc, wr0[1] * sc);
        aw0.u.y = pk2(wr0[2] * sc, wr0[3] * sc);
        aw0.u.z = pk2(wr0[4] * sc, wr0[5] * sc);
        aw0.u.w = pk2(wr0[6] * sc, wr0[7] * sc);
        aw1.u.x = pk2(wr1[0] * sc, wr1[1] * sc);
        aw1.u.y = pk2(wr1[2] * sc, wr1[3] * sc);
        aw1.u.z = pk2(wr1[4] * sc, wr1[5] * sc);
        aw1.u.w = pk2(wr1[6] * sc, wr1[7] * sc);
        f32x4 acc = *(const f32x4*)&att_b[(wid << 4) + g4];
        acc = MF(aw0.v, bb0.v, acc);
        acc = MF(aw1.v, bb1.v, acc);
        int p = (blockIdx.x << 4) + c16;
        int o0 = (wid << 4) + g4;
        uint2 st;
        st.x = pk2(fmaxf(acc[0], 0.f), fmaxf(acc[1], 0.f));
        st.y = pk2(fmaxf(acc[2], 0.f), fmaxf(acc[3], 0.f));
        *(uint2*)(f_agg + (((size_t)p) << 5) + o0) = st;
    }
}

// ---------------- Kernel 3: stage-2 -> fagg2 bf16 point-major (B*N, 64) ----------------
__global__ __launch_bounds__(256, 3) void k3_stage2(
    const float* __restrict__ xyz, const int* __restrict__ nidx,
    const ushort* __restrict__ f_agg,
    const float* __restrict__ bb_w1, const float* __restrict__ bb_g1, const float* __restrict__ bb_b1,
    const float* __restrict__ bb_w2, const float* __restrict__ bb_g2, const float* __restrict__ bb_b2,
    const float* __restrict__ att_fc,
    const float* __restrict__ att_w, const float* __restrict__ att_g, const float* __restrict__ att_b,
    ushort* __restrict__ fagg2b)
{
    __shared__ __align__(16) ushort feat[4][64][72];
    __shared__ __align__(16) unsigned qe[16][68];
    __shared__ __align__(16) ushort fcb[64][72];
    __shared__ __align__(16) ushort w1p[32][40];

    int tid = threadIdx.x;
    for (int i = tid; i < D * D; i += 256) fcb[i >> 6][i & 63] = f2b(att_fc[i]);
    for (int i = tid; i < 32 * 32; i += 256) {
        int o = i >> 5, k = i & 31;
        w1p[o][k] = (k < 10) ? f2b(bb_w1[o * 10 + k] * (bb_g1[o] * BN_RS)) : (ushort)0;
    }
    __syncthreads();

    int wid = tid >> 6, lane = tid & 63;
    int g = lane >> 4, c16 = lane & 15;
    int g4 = g << 2, g8 = g << 3;
    f32x4 zf4 = {0.f, 0.f, 0.f, 0.f};

    int pb = (blockIdx.x << 4) + (wid << 2) + g;
    int b = pb >> 15, n = pb & (NPTS - 1);
    int nb = nidx[((size_t)pb << 4) + c16];

    const bf16x8* gsrc = (const bf16x8*)(f_agg + (((size_t)(b * NPTS + nb)) << 5));
    bf16x8 gv0 = gsrc[0], gv1 = gsrc[1], gv2 = gsrc[2], gv3 = gsrc[3];

    const float* cx = xyz + (size_t)(b * NPTS + n) * 3;
    const float* nx = xyz + (size_t)(b * NPTS + nb) * 3;
    float c0 = cx[0], c1 = cx[1], c2 = cx[2];
    float x0 = nx[0], x1 = nx[1], x2 = nx[2];
    float r0 = c0 - x0, r1 = c1 - x1, r2 = c2 - x2;
    float dist = sqrtf(r0 * r0 + r1 * r1 + r2 * r2);

    // stage in10
    {
        uint4 u0; u0.x = pk2(dist, r0); u0.y = pk2(r1, r2); u0.z = pk2(c0, c1); u0.w = pk2(c2, x0);
        uint4 u1; u1.x = pk2(x1, x2); u1.y = 0; u1.z = 0; u1.w = 0;
        uint4 z4; z4.x = 0; z4.y = 0; z4.z = 0; z4.w = 0;
        *(uint4*)&feat[wid][lane][32] = u0;
        *(uint4*)&feat[wid][lane][40] = u1;
        *(uint4*)&feat[wid][lane][48] = z4;
        *(uint4*)&feat[wid][lane][56] = z4;
    }
    // FXYZ MFMA -> stage-1 fx in cols 32..63
    {
        bf16x8 xb0 = *(const bf16x8*)&feat[wid][ 0 + c16][32 + g8];
        bf16x8 xb1 = *(const bf16x8*)&feat[wid][16 + c16][32 + g8];
        bf16x8 xb2 = *(const bf16x8*)&feat[wid][32 + c16][32 + g8];
        bf16x8 xb3 = *(const bf16x8*)&feat[wid][48 + c16][32 + g8];
        bf16x8 wa0 = *(const bf16x8*)&w1p[     c16][g8];
        bf16x8 wa1 = *(const bf16x8*)&w1p[16 + c16][g8];
        f32x4 bi0 = *(const f32x4*)&bb_b1[g4];
        f32x4 bi1 = *(const f32x4*)&bb_b1[16 + g4];
        f32x4 f00 = MF(wa0, xb0, bi0);
        f32x4 f01 = MF(wa0, xb1, bi0);
        f32x4 f02 = MF(wa0, xb2, bi0);
        f32x4 f03 = MF(wa0, xb3, bi0);
        f32x4 f10 = MF(wa1, xb0, bi1);
        f32x4 f11 = MF(wa1, xb1, bi1);
        f32x4 f12 = MF(wa1, xb2, bi1);
        f32x4 f13 = MF(wa1, xb3, bi1);
        WBX(0, 0, f00) WBX(0, 1, f01) WBX(0, 2, f02) WBX(0, 3, f03)
        WBX(1, 0, f10) WBX(1, 1, f11) WBX(1, 2, f12) WBX(1, 3, f13)
    }
    // bb_w2 A-fragments (in-register fold)
    union { bf16x8 v; uint4 u; } aw20, aw21;
    {
        int o = c16;
        float sc2 = bb_g2[o] * BN_RS;
        const float* wr = bb_w2 + o * H + g8;
        aw20.u.x = pk2(wr[0] * sc2, wr[1] * sc2);
        aw20.u.y = pk2(wr[2] * sc2, wr[3] * sc2);
        aw20.u.z = pk2(wr[4] * sc2, wr[5] * sc2);
        aw20.u.w = pk2(wr[6] * sc2, wr[7] * sc2);
    }
    {
        int o = 16 + c16;
        float sc2 = bb_g2[o] * BN_RS;
        const float* wr = bb_w2 + o * H + g8;
        aw21.u.x = pk2(wr[0] * sc2, wr[1] * sc2);
        aw21.u.y = pk2(wr[2] * sc2, wr[3] * sc2);
        aw21.u.z = pk2(wr[4] * sc2, wr[5] * sc2);
        aw21.u.w = pk2(wr[6] * sc2, wr[7] * sc2);
    }
    // fx B-frags (read before overwrite), then f_xyz2 = relu(bn(bb_w2 @ fx))
    {
        bf16x8 bfx0 = *(const bf16x8*)&feat[wid][ 0 + c16][32 + g8];
        bf16x8 bfx1 = *(const bf16x8*)&feat[wid][16 + c16][32 + g8];
        bf16x8 bfx2 = *(const bf16x8*)&feat[wid][32 + c16][32 + g8];
        bf16x8 bfx3 = *(const bf16x8*)&feat[wid][48 + c16][32 + g8];
        f32x4 bi0 = *(const f32x4*)&bb_b2[     g4];
        f32x4 bi1 = *(const f32x4*)&bb_b2[16 + g4];
        f32x4 a00 = MF(aw20.v, bfx0, bi0);
        f32x4 a01 = MF(aw20.v, bfx1, bi0);
        f32x4 a02 = MF(aw20.v, bfx2, bi0);
        f32x4 a03 = MF(aw20.v, bfx3, bi0);
        f32x4 a10 = MF(aw21.v, bfx0, bi1);
        f32x4 a11 = MF(aw21.v, bfx1, bi1);
        f32x4 a12 = MF(aw21.v, bfx2, bi1);
        f32x4 a13 = MF(aw21.v, bfx3, bi1);
        WBX(0, 0, a00) WBX(0, 1, a01) WBX(0, 2, a02) WBX(0, 3, a03)
        WBX(1, 0, a10) WBX(1, 1, a11) WBX(1, 2, a12) WBX(1, 3, a13)
    }
    // gathered f_agg neighbor features (ch 0..31)
    *(bf16x8*)&feat[wid][lane][0]  = gv0;
    *(bf16x8*)&feat[wid][lane][8]  = gv1;
    *(bf16x8*)&feat[wid][lane][16] = gv2;
    *(bf16x8*)&feat[wid][lane][24] = gv3;

    bf16x8 afc0_0 = *(const bf16x8*)&fcb[ 0 + c16][     g8];
    bf16x8 afc0_1 = *(const bf16x8*)&fcb[ 0 + c16][32 + g8];
    bf16x8 afc1_0 = *(const bf16x8*)&fcb[16 + c16][     g8];
    bf16x8 afc1_1 = *(const bf16x8*)&fcb[16 + c16][32 + g8];
    bf16x8 afc2_0 = *(const bf16x8*)&fcb[32 + c16][     g8];
    bf16x8 afc2_1 = *(const bf16x8*)&fcb[32 + c16][32 + g8];
    bf16x8 afc3_0 = *(const bf16x8*)&fcb[48 + c16][     g8];
    bf16x8 afc3_1 = *(const bf16x8*)&fcb[48 + c16][32 + g8];

    ATT_NI(0) ATT_NI(1) ATT_NI(2) ATT_NI(3)
    __syncthreads();

    // out-MLP via MFMA: wave wid -> mi; bf16 store
    {
        union { bf16x8 v; uint4 u; } bb0, bb1;
        QFRAG(bb0, 0)
        QFRAG(bb1, 32)
        int o = (wid << 4) + c16;
        float sc = att_g[o] * BN_RS;
        const float* wr0 = att_w + o * D + g8;
        const float* wr1 = att_w + o * D + 32 + g8;
        union { bf16x8 v; uint4 u; } aw0, aw1;
        aw0.u.x = pk2(wr0[0] * sc, wr0[1] * sc);
        aw0.u.y = pk2(wr0[2] * sc, wr0[3] * sc);
        aw0.u.z = pk2(wr0[4] * sc, wr0[5] * sc);
        aw0.u.w = pk2(wr0[6] * sc, wr0[7] * sc);
        aw1.u.x = pk2(wr1[0] * sc, wr1[1] * sc);
        aw1.u.y = pk2(wr1[2] * sc, wr1[3] * sc);
        aw1.u.z = pk2(wr1[4] * sc, wr1[5] * sc);
        aw1.u.w = pk2(wr1[6] * sc, wr1[7] * sc);
        f32x4 acc = *(const f32x4*)&att_b[(wid << 4) + g4];
        acc = MF(aw0.v, bb0.v, acc);
        acc = MF(aw1.v, bb1.v, acc);
        int p = (blockIdx.x << 4) + c16;
        int o0 = (wid << 4) + g4;
        uint2 st;
        st.x = pk2(fmaxf(acc[0], 0.f), fmaxf(acc[1], 0.f));
        st.y = pk2(fmaxf(acc[2], 0.f), fmaxf(acc[3], 0.f));
        *(uint2*)(fagg2b + (((size_t)p) << 6) + o0) = st;
    }
}

// ---------------- Kernel 4: MFMA GEMM out[128 x pts] = Wcat[128x96] @ X[96 x pts] ----------------
__global__ __launch_bounds__(256, 4) void k4_final(
    const ushort* __restrict__ fagg2b, const ushort* __restrict__ featpm,
    const float* __restrict__ w_mlp2, const float* __restrict__ g_mlp2, const float* __restrict__ b_mlp2,
    const float* __restrict__ w_sc, const float* __restrict__ g_sc, const float* __restrict__ b_sc,
    float* __restrict__ out)
{
    int tid = threadIdx.x;
    int wid = tid >> 6, lane = tid & 63;
    int c16 = lane & 15, g = lane >> 4;
    int g4 = g << 2, g8 = g << 3;
    int p0 = blockIdx.x << 6;
    int o0 = wid << 5;

    union { bf16x8 v; uint4 u; } A[2][3];
#pragma unroll
    for (int mi = 0; mi < 2; ++mi) {
        int o = o0 + mi * 16 + c16;
        float sm = g_mlp2[o] * BN_RS, ss = g_sc[o] * BN_RS;
        const float* wm = w_mlp2 + o * D;
        const float* ws = w_sc + o * CIN;
#pragma unroll
        for (int ks = 0; ks < 2; ++ks) {
            float4 wa = *(const float4*)&wm[ks * 32 + g8];
            float4 wb = *(const float4*)&wm[ks * 32 + g8 + 4];
            A[mi][ks].u.x = pk2(wa.x * sm, wa.y * sm);
            A[mi][ks].u.y = pk2(wa.z * sm, wa.w * sm);
            A[mi][ks].u.z = pk2(wb.x * sm, wb.y * sm);
            A[mi][ks].u.w = pk2(wb.z * sm, wb.w * sm);
        }
        float4 wa = *(const float4*)&ws[g8];
        float4 wb = *(const float4*)&ws[g8 + 4];
        A[mi][2].u.x = pk2(wa.x * ss, wa.y * ss);
        A[mi][2].u.y = pk2(wa.z * ss, wa.w * ss);
        A[mi][2].u.z = pk2(wb.x * ss, wb.y * ss);
        A[mi][2].u.w = pk2(wb.z * ss, wb.w * ss);
    }
    float bias0[4], bias1[4];
#pragma unroll
    for (int r = 0; r < 4; ++r) {
        int oa = o0 + g4 + r;
        int ob = o0 + 16 + g4 + r;
        bias0[r] = b_mlp2[oa] + b_sc[oa];
        bias1[r] = b_mlp2[ob] + b_sc[ob];
    }

    int bb = p0 >> 15;
#pragma unroll
    for (int ni = 0; ni < 4; ++ni) {
        int pt = p0 + ni * 16 + c16;
        bf16x8 B0 = *(const bf16x8*)&fagg2b[((size_t)pt << 6) + g8];
        bf16x8 B1 = *(const bf16x8*)&fagg2b[((size_t)pt << 6) + 32 + g8];
        bf16x8 B2 = *(const bf16x8*)&featpm[((size_t)pt << 5) + g8];
        f32x4 acc0 = {bias0[0], bias0[1], bias0[2], bias0[3]};
        f32x4 acc1 = {bias1[0], bias1[1], bias1[2], bias1[3]};
        acc0 = MF(A[0][0].v, B0, acc0);
        acc0 = MF(A[0][1].v, B1, acc0);
        acc0 = MF(A[0][2].v, B2, acc0);
        acc1 = MF(A[1][0].v, B0, acc1);
        acc1 = MF(A[1][1].v, B1, acc1);
        acc1 = MF(A[1][2].v, B2, acc1);
        int nn = pt & (NPTS - 1);
#pragma unroll
        for (int r = 0; r < 4; ++r) {
            float v0 = acc0[r];
            v0 = (v0 >= 0.f) ? v0 : 0.2f * v0;
            out[((bb * DOUT + o0 + g4 + r) << 15) + nn] = v0;
            float v1 = acc1[r];
            v1 = (v1 >= 0.f) ? v1 : 0.2f * v1;
            out[((bb * DOUT + o0 + 16 + g4 + r) << 15) + nn] = v1;
        }
    }
}

extern "C" void kernel_launch(void* const* d_in, const int* in_sizes, int n_in,
                              void* d_out, int out_size, void* d_ws, size_t ws_size,
                              hipStream_t stream) {
    const float* feature = (const float*)d_in[0];
    const float* xyz     = (const float*)d_in[1];
    const float* w_mlp1  = (const float*)d_in[2];
    const float* g_mlp1  = (const float*)d_in[3];
    const float* b_mlp1  = (const float*)d_in[4];
    const float* bb_w1   = (const float*)d_in[5];
    const float* bb_g1   = (const float*)d_in[6];
    const float* bb_b1   = (const float*)d_in[7];
    const float* att1_fc = (const float*)d_in[8];
    const float* att1_w  = (const float*)d_in[9];
    const float* att1_g  = (const float*)d_in[10];
    const float* att1_b  = (const float*)d_in[11];
    const float* bb_w2   = (const float*)d_in[12];
    const float* bb_g2   = (const float*)d_in[13];
    const float* bb_b2   = (const float*)d_in[14];
    const float* att2_fc = (const float*)d_in[15];
    const float* att2_w  = (const float*)d_in[16];
    const float* att2_g  = (const float*)d_in[17];
    const float* att2_b  = (const float*)d_in[18];
    const float* w_mlp2  = (const float*)d_in[19];
    const float* g_mlp2  = (const float*)d_in[20];
    const float* b_mlp2  = (const float*)d_in[21];
    const float* w_sc    = (const float*)d_in[22];
    const float* g_sc    = (const float*)d_in[23];
    const float* b_sc    = (const float*)d_in[24];
    const int*   nidx    = (const int*)d_in[25];
    float* out = (float*)d_out;

    ushort* f_pc_bf  = (ushort*)d_ws;                              // B*N*32 bf16
    ushort* f_agg_bf = f_pc_bf + (size_t)NB * NPTS * 32;           // B*N*32 bf16
    ushort* featpm   = f_agg_bf + (size_t)NB * NPTS * 32;          // B*N*32 bf16
    ushort* fagg2b   = featpm + (size_t)NB * NPTS * 32;            // B*N*64 bf16

    k1_mlp1<<<NB * NPTS / 256, 256, 0, stream>>>(feature, w_mlp1, g_mlp1, b_mlp1,
                                                 f_pc_bf, featpm);
    k2_stage1<<<NB * NPTS / 16, 256, 0, stream>>>(xyz, nidx, f_pc_bf,
                                                  bb_w1, bb_g1, bb_b1,
                                                  att1_fc, att1_w, att1_g, att1_b, f_agg_bf);
    k3_stage2<<<NB * NPTS / 16, 256, 0, stream>>>(xyz, nidx, f_agg_bf,
                                                  bb_w1, bb_g1, bb_b1,
                                                  bb_w2, bb_g2, bb_b2,
                                                  att2_fc, att2_w, att2_g, att2_b, fagg2b);
    k4_final<<<NB * NPTS / 64, 256, 0, stream>>>(fagg2b, featpm,
                                                 w_mlp2, g_mlp2, b_mlp2,
                                                 w_sc, g_sc, b_sc, out);
}

// Round 11
// 145.383 us; speedup vs baseline: 3.8857x; 1.1512x over previous
//
#include <hip/hip_runtime.h>
#include <math.h>

#define NPTS 32768
#define NB 2
#define CIN 32
#define H 32
#define D 64
#define DOUT 128
#define BN_RS 0.99999500003749981f   // 1/sqrt(1 + 1e-5)
#define LOG2E 1.44269504088896341f

typedef __attribute__((ext_vector_type(8))) short bf16x8;
typedef __attribute__((ext_vector_type(4))) short bf16x4;
typedef __attribute__((ext_vector_type(4))) float f32x4;

__device__ __forceinline__ ushort f2b(float f) {
    union { float f; unsigned u; } v; v.f = f;
    unsigned r = v.u + 0x7fffu + ((v.u >> 16) & 1u);   // RNE
    return (ushort)(r >> 16);
}
__device__ __forceinline__ float b2f(ushort u) {
    union { unsigned u; float f; } v; v.u = ((unsigned)u) << 16; return v.f;
}
// pack two f32 -> bf16x2 dword (round-half-up + v_perm_b32); lo = f0, hi = f1
__device__ __forceinline__ unsigned pk2(float f0, float f1) {
    unsigned a = __builtin_bit_cast(unsigned, f0) + 0x8000u;
    unsigned b = __builtin_bit_cast(unsigned, f1) + 0x8000u;
    return __builtin_amdgcn_perm(b, a, 0x07060302);
}
// unpack (Q,E) dword -> Q/E
__device__ __forceinline__ float qdiv(unsigned u) {
    float q = __builtin_bit_cast(float, u << 16);
    float e = __builtin_bit_cast(float, u & 0xffff0000u);
    return __fdividef(q, e);
}
// raw 2^x (weights pre-scaled by log2e)
__device__ __forceinline__ float ex2(float x) {
    float r; asm("v_exp_f32 %0, %1" : "=v"(r) : "v"(x)); return r;
}
#define MF(a, b, c) __builtin_amdgcn_mfma_f32_16x16x32_bf16(a, b, c, 0, 0, 0)

// WBX: write relu'd C tile (mi,ni) to feat cols 32..63  (C: row=channel, col=position)
#define WBX(mi, ni, A) { uint2 _w;                                                \
    _w.x = pk2(fmaxf(A[0], 0.f), fmaxf(A[1], 0.f));                               \
    _w.y = pk2(fmaxf(A[2], 0.f), fmaxf(A[3], 0.f));                               \
    *(uint2*)&feat[wid][(ni) * 16 + c16][32 + (mi) * 16 + g4] = _w; }

// ---- transposed attention core: L^T = feat @ fc^T -> k on rows ----
// lane holds L[pos = ni*16 + g4 + r][o = cg*16 + c16]; reduce over r (in-reg) + g (xor16/32)
#define ATT_CG(ni, cg, F0, F1) {                                                  \
    f32x4 ac = zf4;                                                               \
    ac = MF(a0_, F0, ac);                                                         \
    ac = MF(a1_, F1, ac);                                                         \
    float e0 = ex2(ac[0]), e1 = ex2(ac[1]), e2 = ex2(ac[2]), e3 = ex2(ac[3]);     \
    float E = (e0 + e1) + (e2 + e3);                                              \
    float f0 = b2f(feat[wid][(ni) * 16 + g4 + 0][(cg) * 16 + c16]);               \
    float f1 = b2f(feat[wid][(ni) * 16 + g4 + 1][(cg) * 16 + c16]);               \
    float f2 = b2f(feat[wid][(ni) * 16 + g4 + 2][(cg) * 16 + c16]);               \
    float f3 = b2f(feat[wid][(ni) * 16 + g4 + 3][(cg) * 16 + c16]);               \
    float Q = e0 * f0; Q = fmaf(e1, f1, Q); Q = fmaf(e2, f2, Q); Q = fmaf(e3, f3, Q); \
    E += __shfl_xor(E, 16); Q += __shfl_xor(Q, 16);                               \
    E += __shfl_xor(E, 32); Q += __shfl_xor(Q, 32);                               \
    if (g == 0) qe[(wid << 2) + (ni)][(cg) * 16 + c16] = pk2(Q, E); }
#define ATT_NI(ni) {                                                              \
    bf16x8 a0_ = *(const bf16x8*)&feat[wid][(ni) * 16 + c16][g8];                 \
    bf16x8 a1_ = *(const bf16x8*)&feat[wid][(ni) * 16 + c16][32 + g8];            \
    ATT_CG(ni, 0, afc0_0, afc0_1) ATT_CG(ni, 1, afc1_0, afc1_1)                   \
    ATT_CG(ni, 2, afc2_0, afc2_1) ATT_CG(ni, 3, afc3_0, afc3_1) }

// build agg B-frags from qe (divide deferred to here)
#define QFRAG(bbv, base) {                                                        \
    uint4 _qa = *(const uint4*)&qe[c16][(base) + g8];                             \
    uint4 _qb = *(const uint4*)&qe[c16][(base) + g8 + 4];                         \
    bbv.u.x = pk2(qdiv(_qa.x), qdiv(_qa.y));                                      \
    bbv.u.y = pk2(qdiv(_qa.z), qdiv(_qa.w));                                      \
    bbv.u.z = pk2(qdiv(_qb.x), qdiv(_qb.y));                                      \
    bbv.u.w = pk2(qdiv(_qb.z), qdiv(_qb.w)); }

// ---------------- Kernel 1: f_pc = relu(bn(w_mlp1 @ feature)) -> bf16 (B*N,32) ----------------
__global__ __launch_bounds__(256, 4) void k1_mlp1(
    const float* __restrict__ feature, const float* __restrict__ w_mlp1,
    const float* __restrict__ g_mlp1, const float* __restrict__ b_mlp1,
    ushort* __restrict__ f_pc, ushort* __restrict__ featpm)
{
    int tid = threadIdx.x;
    int pg = blockIdx.x * 256 + tid;
    int b = pg >> 15, n = pg & (NPTS - 1);

    float x[CIN];
#pragma unroll
    for (int c = 0; c < CIN; ++c)
        x[c] = feature[((b * CIN + c) << 15) + n];

    float outv[CIN];
#pragma unroll
    for (int o = 0; o < CIN; ++o) {
        float s0 = 0.f, s1 = 0.f, s2 = 0.f, s3 = 0.f;
        const float* w = w_mlp1 + o * CIN;
#pragma unroll
        for (int c = 0; c < CIN; c += 4) {
            s0 = fmaf(w[c + 0], x[c + 0], s0);
            s1 = fmaf(w[c + 1], x[c + 1], s1);
            s2 = fmaf(w[c + 2], x[c + 2], s2);
            s3 = fmaf(w[c + 3], x[c + 3], s3);
        }
        float acc = (s0 + s1) + (s2 + s3);
        outv[o] = fmaxf(fmaf(acc, g_mlp1[o] * BN_RS, b_mlp1[o]), 0.f);
    }
    uint4* dst = (uint4*)(f_pc + ((size_t)pg << 5));
    uint4* dst2 = (uint4*)(featpm + ((size_t)pg << 5));
#pragma unroll
    for (int j = 0; j < 4; ++j) {
        uint4 u;
        u.x = pk2(outv[8 * j + 0], outv[8 * j + 1]);
        u.y = pk2(outv[8 * j + 2], outv[8 * j + 3]);
        u.z = pk2(outv[8 * j + 4], outv[8 * j + 5]);
        u.w = pk2(outv[8 * j + 6], outv[8 * j + 7]);
        dst[j] = u;
        uint4 v;
        v.x = pk2(x[8 * j + 0], x[8 * j + 1]);
        v.y = pk2(x[8 * j + 2], x[8 * j + 3]);
        v.z = pk2(x[8 * j + 4], x[8 * j + 5]);
        v.w = pk2(x[8 * j + 6], x[8 * j + 7]);
        dst2[j] = v;
    }
}

// ---------------- Kernel 2: stage-1 -> f_agg bf16 (B*N, 32) ----------------
__global__ __launch_bounds__(256, 3) void k2_stage1(
    const float* __restrict__ xyz, const int* __restrict__ nidx,
    const ushort* __restrict__ f_pc,
    const float* __restrict__ bb_w1, const float* __restrict__ bb_g1, const float* __restrict__ bb_b1,
    const float* __restrict__ att_fc,
    const float* __restrict__ att_w, const float* __restrict__ att_g, const float* __restrict__ att_b,
    ushort* __restrict__ f_agg)
{
    __shared__ __align__(16) ushort feat[4][64][72];   // per-wave 64 pos x 64 ch bf16
    __shared__ __align__(16) unsigned qe[16][68];      // packed (Q,E) per point x channel
    __shared__ __align__(16) ushort fcb[64][72];       // att1_fc * log2e, bf16
    __shared__ __align__(16) ushort w1p[32][40];       // folded bb_w1, K-padded to 32

    int tid = threadIdx.x;
    for (int i = tid; i < D * D; i += 256) fcb[i >> 6][i & 63] = f2b(att_fc[i] * LOG2E);
    for (int i = tid; i < 32 * 32; i += 256) {
        int o = i >> 5, k = i & 31;
        w1p[o][k] = (k < 10) ? f2b(bb_w1[o * 10 + k] * (bb_g1[o] * BN_RS)) : (ushort)0;
    }
    __syncthreads();

    int wid = tid >> 6, lane = tid & 63;
    int g = lane >> 4, c16 = lane & 15;
    int g4 = g << 2, g8 = g << 3;
    f32x4 zf4 = {0.f, 0.f, 0.f, 0.f};

    int pb = (blockIdx.x << 4) + (wid << 2) + g;       // this lane's build point
    int b = pb >> 15, n = pb & (NPTS - 1);
    int nb = nidx[((size_t)pb << 4) + c16];

    // issue neighbor-feature gather early
    const bf16x8* gsrc = (const bf16x8*)(f_pc + (((size_t)(b * NPTS + nb)) << 5));
    bf16x8 gv0 = gsrc[0], gv1 = gsrc[1], gv2 = gsrc[2], gv3 = gsrc[3];

    // rel-pos inputs
    const float* cx = xyz + (size_t)(b * NPTS + n) * 3;
    const float* nx = xyz + (size_t)(b * NPTS + nb) * 3;
    float c0 = cx[0], c1 = cx[1], c2 = cx[2];
    float x0 = nx[0], x1 = nx[1], x2 = nx[2];
    float r0 = c0 - x0, r1 = c1 - x1, r2 = c2 - x2;
    float dist = sqrtf(r0 * r0 + r1 * r1 + r2 * r2);

    // stage in10 bf16 (zero-padded to 32) into feat cols 32..63
    {
        uint4 u0; u0.x = pk2(dist, r0); u0.y = pk2(r1, r2); u0.z = pk2(c0, c1); u0.w = pk2(c2, x0);
        uint4 u1; u1.x = pk2(x1, x2); u1.y = 0; u1.z = 0; u1.w = 0;
        uint4 z4; z4.x = 0; z4.y = 0; z4.z = 0; z4.w = 0;
        *(uint4*)&feat[wid][lane][32] = u0;
        *(uint4*)&feat[wid][lane][40] = u1;
        *(uint4*)&feat[wid][lane][48] = z4;
        *(uint4*)&feat[wid][lane][56] = z4;
    }
    // FXYZ MFMA: read all B-frags before overwrite
    {
        bf16x8 xb0 = *(const bf16x8*)&feat[wid][ 0 + c16][32 + g8];
        bf16x8 xb1 = *(const bf16x8*)&feat[wid][16 + c16][32 + g8];
        bf16x8 xb2 = *(const bf16x8*)&feat[wid][32 + c16][32 + g8];
        bf16x8 xb3 = *(const bf16x8*)&feat[wid][48 + c16][32 + g8];
        bf16x8 wa0 = *(const bf16x8*)&w1p[     c16][g8];
        bf16x8 wa1 = *(const bf16x8*)&w1p[16 + c16][g8];
        f32x4 bi0 = *(const f32x4*)&bb_b1[g4];
        f32x4 bi1 = *(const f32x4*)&bb_b1[16 + g4];
        f32x4 f00 = MF(wa0, xb0, bi0);
        f32x4 f01 = MF(wa0, xb1, bi0);
        f32x4 f02 = MF(wa0, xb2, bi0);
        f32x4 f03 = MF(wa0, xb3, bi0);
        f32x4 f10 = MF(wa1, xb0, bi1);
        f32x4 f11 = MF(wa1, xb1, bi1);
        f32x4 f12 = MF(wa1, xb2, bi1);
        f32x4 f13 = MF(wa1, xb3, bi1);
        WBX(0, 0, f00) WBX(0, 1, f01) WBX(0, 2, f02) WBX(0, 3, f03)
        WBX(1, 0, f10) WBX(1, 1, f11) WBX(1, 2, f12) WBX(1, 3, f13)
    }
    // gathered neighbor features (ch 0..31)
    *(bf16x8*)&feat[wid][lane][0]  = gv0;
    *(bf16x8*)&feat[wid][lane][8]  = gv1;
    *(bf16x8*)&feat[wid][lane][16] = gv2;
    *(bf16x8*)&feat[wid][lane][24] = gv3;

    // fc B-fragments from LDS (transposed MFMA: B cols = output channels)
    bf16x8 afc0_0 = *(const bf16x8*)&fcb[ 0 + c16][     g8];
    bf16x8 afc0_1 = *(const bf16x8*)&fcb[ 0 + c16][32 + g8];
    bf16x8 afc1_0 = *(const bf16x8*)&fcb[16 + c16][     g8];
    bf16x8 afc1_1 = *(const bf16x8*)&fcb[16 + c16][32 + g8];
    bf16x8 afc2_0 = *(const bf16x8*)&fcb[32 + c16][     g8];
    bf16x8 afc2_1 = *(const bf16x8*)&fcb[32 + c16][32 + g8];
    bf16x8 afc3_0 = *(const bf16x8*)&fcb[48 + c16][     g8];
    bf16x8 afc3_1 = *(const bf16x8*)&fcb[48 + c16][32 + g8];

    ATT_NI(0) ATT_NI(1) ATT_NI(2) ATT_NI(3)
    __syncthreads();

    // out-MLP via MFMA: waves 0,1 -> mi; B-frags built with deferred divide
    if (wid < 2) {
        union { bf16x8 v; uint4 u; } bb0, bb1;
        QFRAG(bb0, 0)
        QFRAG(bb1, 32)
        int o = (wid << 4) + c16;
        float sc = att_g[o] * BN_RS;
        const float* wr0 = att_w + o * D + g8;
        const float* wr1 = att_w + o * D + 32 + g8;
        union { bf16x8 v; uint4 u; } aw0, aw1;
        aw0.u.x = pk2(wr0[0] * sc, wr0[1] * sc);
        aw0.u.y = pk2(wr0[2] * sc, wr0[3] * sc);
        aw0.u.z = pk2(wr0[4] * sc, wr0[5] * sc);
        aw0.u.w = pk2(wr0[6] * sc, wr0[7] * sc);
        aw1.u.x = pk2(wr1[0] * sc, wr1[1] * sc);
        aw1.u.y = pk2(wr1[2] * sc, wr1[3] * sc);
        aw1.u.z = pk2(wr1[4] * sc, wr1[5] * sc);
        aw1.u.w = pk2(wr1[6] * sc, wr1[7] * sc);
        f32x4 acc = *(const f32x4*)&att_b[(wid << 4) + g4];
        acc = MF(aw0.v, bb0.v, acc);
        acc = MF(aw1.v, bb1.v, acc);
        int p = (blockIdx.x << 4) + c16;
        int o0 = (wid << 4) + g4;
        uint2 st;
        st.x = pk2(fmaxf(acc[0], 0.f), fmaxf(acc[1], 0.f));
        st.y = pk2(fmaxf(acc[2], 0.f), fmaxf(acc[3], 0.f));
        *(uint2*)(f_agg + (((size_t)p) << 5) + o0) = st;
    }
}

// ---------------- Kernel 3: stage-2 -> fagg2 bf16 point-major (B*N, 64) ----------------
__global__ __launch_bounds__(256, 3) void k3_stage2(
    const float* __restrict__ xyz, const int* __restrict__ nidx,
    const ushort* __restrict__ f_agg,
    const float* __restrict__ bb_w1, const float* __restrict__ bb_g1, const float* __restrict__ bb_b1,
    const float* __restrict__ bb_w2, const float* __restrict__ bb_g2, const float* __restrict__ bb_b2,
    const float* __restrict__ att_fc,
    const float* __restrict__ att_w, const float* __restrict__ att_g, const float* __restrict__ att_b,
    ushort* __restrict__ fagg2b)
{
    __shared__ __align__(16) ushort feat[4][64][72];
    __shared__ __align__(16) unsigned qe[16][68];
    __shared__ __align__(16) ushort fcb[64][72];
    __shared__ __align__(16) ushort w1p[32][40];

    int tid = threadIdx.x;
    for (int i = tid; i < D * D; i += 256) fcb[i >> 6][i & 63] = f2b(att_fc[i] * LOG2E);
    for (int i = tid; i < 32 * 32; i += 256) {
        int o = i >> 5, k = i & 31;
        w1p[o][k] = (k < 10) ? f2b(bb_w1[o * 10 + k] * (bb_g1[o] * BN_RS)) : (ushort)0;
    }
    __syncthreads();

    int wid = tid >> 6, lane = tid & 63;
    int g = lane >> 4, c16 = lane & 15;
    int g4 = g << 2, g8 = g << 3;
    f32x4 zf4 = {0.f, 0.f, 0.f, 0.f};

    int pb = (blockIdx.x << 4) + (wid << 2) + g;
    int b = pb >> 15, n = pb & (NPTS - 1);
    int nb = nidx[((size_t)pb << 4) + c16];

    const bf16x8* gsrc = (const bf16x8*)(f_agg + (((size_t)(b * NPTS + nb)) << 5));
    bf16x8 gv0 = gsrc[0], gv1 = gsrc[1], gv2 = gsrc[2], gv3 = gsrc[3];

    const float* cx = xyz + (size_t)(b * NPTS + n) * 3;
    const float* nx = xyz + (size_t)(b * NPTS + nb) * 3;
    float c0 = cx[0], c1 = cx[1], c2 = cx[2];
    float x0 = nx[0], x1 = nx[1], x2 = nx[2];
    float r0 = c0 - x0, r1 = c1 - x1, r2 = c2 - x2;
    float dist = sqrtf(r0 * r0 + r1 * r1 + r2 * r2);

    // stage in10
    {
        uint4 u0; u0.x = pk2(dist, r0); u0.y = pk2(r1, r2); u0.z = pk2(c0, c1); u0.w = pk2(c2, x0);
        uint4 u1; u1.x = pk2(x1, x2); u1.y = 0; u1.z = 0; u1.w = 0;
        uint4 z4; z4.x = 0; z4.y = 0; z4.z = 0; z4.w = 0;
        *(uint4*)&feat[wid][lane][32] = u0;
        *(uint4*)&feat[wid][lane][40] = u1;
        *(uint4*)&feat[wid][lane][48] = z4;
        *(uint4*)&feat[wid][lane][56] = z4;
    }
    // FXYZ MFMA -> stage-1 fx in cols 32..63
    {
        bf16x8 xb0 = *(const bf16x8*)&feat[wid][ 0 + c16][32 + g8];
        bf16x8 xb1 = *(const bf16x8*)&feat[wid][16 + c16][32 + g8];
        bf16x8 xb2 = *(const bf16x8*)&feat[wid][32 + c16][32 + g8];
        bf16x8 xb3 = *(const bf16x8*)&feat[wid][48 + c16][32 + g8];
        bf16x8 wa0 = *(const bf16x8*)&w1p[     c16][g8];
        bf16x8 wa1 = *(const bf16x8*)&w1p[16 + c16][g8];
        f32x4 bi0 = *(const f32x4*)&bb_b1[g4];
        f32x4 bi1 = *(const f32x4*)&bb_b1[16 + g4];
        f32x4 f00 = MF(wa0, xb0, bi0);
        f32x4 f01 = MF(wa0, xb1, bi0);
        f32x4 f02 = MF(wa0, xb2, bi0);
        f32x4 f03 = MF(wa0, xb3, bi0);
        f32x4 f10 = MF(wa1, xb0, bi1);
        f32x4 f11 = MF(wa1, xb1, bi1);
        f32x4 f12 = MF(wa1, xb2, bi1);
        f32x4 f13 = MF(wa1, xb3, bi1);
        WBX(0, 0, f00) WBX(0, 1, f01) WBX(0, 2, f02) WBX(0, 3, f03)
        WBX(1, 0, f10) WBX(1, 1, f11) WBX(1, 2, f12) WBX(1, 3, f13)
    }
    // bb_w2 A-fragments (in-register fold)
    union { bf16x8 v; uint4 u; } aw20, aw21;
    {
        int o = c16;
        float sc2 = bb_g2[o] * BN_RS;
        const float* wr = bb_w2 + o * H + g8;
        aw20.u.x = pk2(wr[0] * sc2, wr[1] * sc2);
        aw20.u.y = pk2(wr[2] * sc2, wr[3] * sc2);
        aw20.u.z = pk2(wr[4] * sc2, wr[5] * sc2);
        aw20.u.w = pk2(wr[6] * sc2, wr[7] * sc2);
    }
    {
        int o = 16 + c16;
        float sc2 = bb_g2[o] * BN_RS;
        const float* wr = bb_w2 + o * H + g8;
        aw21.u.x = pk2(wr[0] * sc2, wr[1] * sc2);
        aw21.u.y = pk2(wr[2] * sc2, wr[3] * sc2);
        aw21.u.z = pk2(wr[4] * sc2, wr[5] * sc2);
        aw21.u.w = pk2(wr[6] * sc2, wr[7] * sc2);
    }
    // fx B-frags (read before overwrite), then f_xyz2 = relu(bn(bb_w2 @ fx))
    {
        bf16x8 bfx0 = *(const bf16x8*)&feat[wid][ 0 + c16][32 + g8];
        bf16x8 bfx1 = *(const bf16x8*)&feat[wid][16 + c16][32 + g8];
        bf16x8 bfx2 = *(const bf16x8*)&feat[wid][32 + c16][32 + g8];
        bf16x8 bfx3 = *(const bf16x8*)&feat[wid][48 + c16][32 + g8];
        f32x4 bi0 = *(const f32x4*)&bb_b2[     g4];
        f32x4 bi1 = *(const f32x4*)&bb_b2[16 + g4];
        f32x4 a00 = MF(aw20.v, bfx0, bi0);
        f32x4 a01 = MF(aw20.v, bfx1, bi0);
        f32x4 a02 = MF(aw20.v, bfx2, bi0);
        f32x4 a03 = MF(aw20.v, bfx3, bi0);
        f32x4 a10 = MF(aw21.v, bfx0, bi1);
        f32x4 a11 = MF(aw21.v, bfx1, bi1);
        f32x4 a12 = MF(aw21.v, bfx2, bi1);
        f32x4 a13 = MF(aw21.v, bfx3, bi1);
        WBX(0, 0, a00) WBX(0, 1, a01) WBX(0, 2, a02) WBX(0, 3, a03)
        WBX(1, 0, a10) WBX(1, 1, a11) WBX(1, 2, a12) WBX(1, 3, a13)
    }
    // gathered f_agg neighbor features (ch 0..31)
    *(bf16x8*)&feat[wid][lane][0]  = gv0;
    *(bf16x8*)&feat[wid][lane][8]  = gv1;
    *(bf16x8*)&feat[wid][lane][16] = gv2;
    *(bf16x8*)&feat[wid][lane][24] = gv3;

    bf16x8 afc0_0 = *(const bf16x8*)&fcb[ 0 + c16][     g8];
    bf16x8 afc0_1 = *(const bf16x8*)&fcb[ 0 + c16][32 + g8];
    bf16x8 afc1_0 = *(const bf16x8*)&fcb[16 + c16][     g8];
    bf16x8 afc1_1 = *(const bf16x8*)&fcb[16 + c16][32 + g8];
    bf16x8 afc2_0 = *(const bf16x8*)&fcb[32 + c16][     g8];
    bf16x8 afc2_1 = *(const bf16x8*)&fcb[32 + c16][32 + g8];
    bf16x8 afc3_0 = *(const bf16x8*)&fcb[48 + c16][     g8];
    bf16x8 afc3_1 = *(const bf16x8*)&fcb[48 + c16][32 + g8];

    ATT_NI(0) ATT_NI(1) ATT_NI(2) ATT_NI(3)
    __syncthreads();

    // out-MLP via MFMA: wave wid -> mi; bf16 store
    {
        union { bf16x8 v; uint4 u; } bb0, bb1;
        QFRAG(bb0, 0)
        QFRAG(bb1, 32)
        int o = (wid << 4) + c16;
        float sc = att_g[o] * BN_RS;
        const float* wr0 = att_w + o * D + g8;
        const float* wr1 = att_w + o * D + 32 + g8;
        union { bf16x8 v; uint4 u; } aw0, aw1;
        aw0.u.x = pk2(wr0[0] * sc, wr0[1] * sc);
        aw0.u.y = pk2(wr0[2] * sc, wr0[3] * sc);
        aw0.u.z = pk2(wr0[4] * sc, wr0[5] * sc);
        aw0.u.w = pk2(wr0[6] * sc, wr0[7] * sc);
        aw1.u.x = pk2(wr1[0] * sc, wr1[1] * sc);
        aw1.u.y = pk2(wr1[2] * sc, wr1[3] * sc);
        aw1.u.z = pk2(wr1[4] * sc, wr1[5] * sc);
        aw1.u.w = pk2(wr1[6] * sc, wr1[7] * sc);
        f32x4 acc = *(const f32x4*)&att_b[(wid << 4) + g4];
        acc = MF(aw0.v, bb0.v, acc);
        acc = MF(aw1.v, bb1.v, acc);
        int p = (blockIdx.x << 4) + c16;
        int o0 = (wid << 4) + g4;
        uint2 st;
        st.x = pk2(fmaxf(acc[0], 0.f), fmaxf(acc[1], 0.f));
        st.y = pk2(fmaxf(acc[2], 0.f), fmaxf(acc[3], 0.f));
        *(uint2*)(fagg2b + (((size_t)p) << 6) + o0) = st;
    }
}

// ---------------- Kernel 4: MFMA GEMM out[128 x pts] = Wcat[128x96] @ X[96 x pts] ----------------
__global__ __launch_bounds__(256, 4) void k4_final(
    const ushort* __restrict__ fagg2b, const ushort* __restrict__ featpm,
    const float* __restrict__ w_mlp2, const float* __restrict__ g_mlp2, const float* __restrict__ b_mlp2,
    const float* __restrict__ w_sc, const float* __restrict__ g_sc, const float* __restrict__ b_sc,
    float* __restrict__ out)
{
    int tid = threadIdx.x;
    int wid = tid >> 6, lane = tid & 63;
    int c16 = lane & 15, g = lane >> 4;
    int g4 = g << 2, g8 = g << 3;
    int p0 = blockIdx.x << 6;
    int o0 = wid << 5;

    union { bf16x8 v; uint4 u; } A[2][3];
#pragma unroll
    for (int mi = 0; mi < 2; ++mi) {
        int o = o0 + mi * 16 + c16;
        float sm = g_mlp2[o] * BN_RS, ss = g_sc[o] * BN_RS;
        const float* wm = w_mlp2 + o * D;
        const float* ws = w_sc + o * CIN;
#pragma unroll
        for (int ks = 0; ks < 2; ++ks) {
            float4 wa = *(const float4*)&wm[ks * 32 + g8];
            float4 wb = *(const float4*)&wm[ks * 32 + g8 + 4];
            A[mi][ks].u.x = pk2(wa.x * sm, wa.y * sm);
            A[mi][ks].u.y = pk2(wa.z * sm, wa.w * sm);
            A[mi][ks].u.z = pk2(wb.x * sm, wb.y * sm);
            A[mi][ks].u.w = pk2(wb.z * sm, wb.w * sm);
        }
        float4 wa = *(const float4*)&ws[g8];
        float4 wb = *(const float4*)&ws[g8 + 4];
        A[mi][2].u.x = pk2(wa.x * ss, wa.y * ss);
        A[mi][2].u.y = pk2(wa.z * ss, wa.w * ss);
        A[mi][2].u.z = pk2(wb.x * ss, wb.y * ss);
        A[mi][2].u.w = pk2(wb.z * ss, wb.w * ss);
    }
    float bias0[4], bias1[4];
#pragma unroll
    for (int r = 0; r < 4; ++r) {
        int oa = o0 + g4 + r;
        int ob = o0 + 16 + g4 + r;
        bias0[r] = b_mlp2[oa] + b_sc[oa];
        bias1[r] = b_mlp2[ob] + b_sc[ob];
    }

    int bb = p0 >> 15;
#pragma unroll
    for (int ni = 0; ni < 4; ++ni) {
        int pt = p0 + ni * 16 + c16;
        bf16x8 B0 = *(const bf16x8*)&fagg2b[((size_t)pt << 6) + g8];
        bf16x8 B1 = *(const bf16x8*)&fagg2b[((size_t)pt << 6) + 32 + g8];
        bf16x8 B2 = *(const bf16x8*)&featpm[((size_t)pt << 5) + g8];
        f32x4 acc0 = {bias0[0], bias0[1], bias0[2], bias0[3]};
        f32x4 acc1 = {bias1[0], bias1[1], bias1[2], bias1[3]};
        acc0 = MF(A[0][0].v, B0, acc0);
        acc0 = MF(A[0][1].v, B1, acc0);
        acc0 = MF(A[0][2].v, B2, acc0);
        acc1 = MF(A[1][0].v, B0, acc1);
        acc1 = MF(A[1][1].v, B1, acc1);
        acc1 = MF(A[1][2].v, B2, acc1);
        int nn = pt & (NPTS - 1);
#pragma unroll
        for (int r = 0; r < 4; ++r) {
            float v0 = acc0[r];
            v0 = (v0 >= 0.f) ? v0 : 0.2f * v0;
            out[((bb * DOUT + o0 + g4 + r) << 15) + nn] = v0;
            float v1 = acc1[r];
            v1 = (v1 >= 0.f) ? v1 : 0.2f * v1;
            out[((bb * DOUT + o0 + 16 + g4 + r) << 15) + nn] = v1;
        }
    }
}

extern "C" void kernel_launch(void* const* d_in, const int* in_sizes, int n_in,
                              void* d_out, int out_size, void* d_ws, size_t ws_size,
                              hipStream_t stream) {
    const float* feature = (const float*)d_in[0];
    const float* xyz     = (const float*)d_in[1];
    const float* w_mlp1  = (const float*)d_in[2];
    const float* g_mlp1  = (const float*)d_in[3];
    const float* b_mlp1  = (const float*)d_in[4];
    const float* bb_w1   = (const float*)d_in[5];
    const float* bb_g1   = (const float*)d_in[6];
    const float* bb_b1   = (const float*)d_in[7];
    const float* att1_fc = (const float*)d_in[8];
    const float* att1_w  = (const float*)d_in[9];
    const float* att1_g  = (const float*)d_in[10];
    const float* att1_b  = (const float*)d_in[11];
    const float* bb_w2   = (const float*)d_in[12];
    const float* bb_g2   = (const float*)d_in[13];
    const float* bb_b2   = (const float*)d_in[14];
    const float* att2_fc = (const float*)d_in[15];
    const float* att2_w  = (const float*)d_in[16];
    const float* att2_g  = (const float*)d_in[17];
    const float* att2_b  = (const float*)d_in[18];
    const float* w_mlp2  = (const float*)d_in[19];
    const float* g_mlp2  = (const float*)d_in[20];
    const float* b_mlp2  = (const float*)d_in[21];
    const float* w_sc    = (const float*)d_in[22];
    const float* g_sc    = (const float*)d_in[23];
    const float* b_sc    = (const float*)d_in[24];
    const int*   nidx    = (const int*)d_in[25];
    float* out = (float*)d_out;

    ushort* f_pc_bf  = (ushort*)d_ws;                              // B*N*32 bf16
    ushort* f_agg_bf = f_pc_bf + (size_t)NB * NPTS * 32;           // B*N*32 bf16
    ushort* featpm   = f_agg_bf + (size_t)NB * NPTS * 32;          // B*N*32 bf16
    ushort* fagg2b   = featpm + (size_t)NB * NPTS * 32;            // B*N*64 bf16

    k1_mlp1<<<NB * NPTS / 256, 256, 0, stream>>>(feature, w_mlp1, g_mlp1, b_mlp1,
                                                 f_pc_bf, featpm);
    k2_stage1<<<NB * NPTS / 16, 256, 0, stream>>>(xyz, nidx, f_pc_bf,
                                                  bb_w1, bb_g1, bb_b1,
                                                  att1_fc, att1_w, att1_g, att1_b, f_agg_bf);
    k3_stage2<<<NB * NPTS / 16, 256, 0, stream>>>(xyz, nidx, f_agg_bf,
                                                  bb_w1, bb_g1, bb_b1,
                                                  bb_w2, bb_g2, bb_b2,
                                                  att2_fc, att2_w, att2_g, att2_b, fagg2b);
    k4_final<<<NB * NPTS / 64, 256, 0, stream>>>(fagg2b, featpm,
                                                 w_mlp2, g_mlp2, b_mlp2,
                                                 w_sc, g_sc, b_sc, out);
}

// Round 12
// 138.491 us; speedup vs baseline: 4.0790x; 1.0498x over previous
//
#include <hip/hip_runtime.h>
#include <math.h>

#define NPTS 32768
#define NB 2
#define CIN 32
#define H 32
#define D 64
#define DOUT 128
#define BN_RS 0.99999500003749981f   // 1/sqrt(1 + 1e-5)
#define LOG2E 1.44269504088896341f

typedef __attribute__((ext_vector_type(8))) short bf16x8;
typedef __attribute__((ext_vector_type(4))) short bf16x4;
typedef __attribute__((ext_vector_type(4))) float f32x4;

__device__ __forceinline__ ushort f2b(float f) {
    union { float f; unsigned u; } v; v.f = f;
    unsigned r = v.u + 0x7fffu + ((v.u >> 16) & 1u);   // RNE
    return (ushort)(r >> 16);
}
__device__ __forceinline__ float b2f(ushort u) {
    union { unsigned u; float f; } v; v.u = ((unsigned)u) << 16; return v.f;
}
// pack two f32 -> bf16x2 dword (round-half-up + v_perm_b32); lo = f0, hi = f1
__device__ __forceinline__ unsigned pk2(float f0, float f1) {
    unsigned a = __builtin_bit_cast(unsigned, f0) + 0x8000u;
    unsigned b = __builtin_bit_cast(unsigned, f1) + 0x8000u;
    return __builtin_amdgcn_perm(b, a, 0x07060302);
}
// unpack (Q,E) dword -> Q/E
__device__ __forceinline__ float qdiv(unsigned u) {
    float q = __builtin_bit_cast(float, u << 16);
    float e = __builtin_bit_cast(float, u & 0xffff0000u);
    return __fdividef(q, e);
}
// raw 2^x (weights pre-scaled by log2e)
__device__ __forceinline__ float ex2(float x) {
    float r; asm("v_exp_f32 %0, %1" : "=v"(r) : "v"(x)); return r;
}
// cross-row sums via gfx950 permlane swaps (VALU pipe, no DS):
// {a,b} = permlaneN_swap(x,x); a+b == x[l] + x[l^N] in every lane
__device__ __forceinline__ float xsum16(float x) {
    float a = x, b = x;
    asm("v_permlane16_swap_b32 %0, %1" : "+v"(a), "+v"(b));
    return a + b;
}
__device__ __forceinline__ float xsum32(float x) {
    float a = x, b = x;
    asm("v_permlane32_swap_b32 %0, %1" : "+v"(a), "+v"(b));
    return a + b;
}
#define MF(a, b, c) __builtin_amdgcn_mfma_f32_16x16x32_bf16(a, b, c, 0, 0, 0)

// WBX: write relu'd C tile (mi,ni) to feat cols 32..63  (C: row=channel, col=position)
#define WBX(mi, ni, A) { uint2 _w;                                                \
    _w.x = pk2(fmaxf(A[0], 0.f), fmaxf(A[1], 0.f));                               \
    _w.y = pk2(fmaxf(A[2], 0.f), fmaxf(A[3], 0.f));                               \
    *(uint2*)&feat[wid][(ni) * 16 + c16][32 + (mi) * 16 + g4] = _w; }

// ---- transposed attention core: L^T = feat @ fc^T -> k on rows ----
// lane holds L[pos = ni*16 + g4 + r][o = cg*16 + c16]; reduce over r (in-reg) + g (permlane)
#define ATT_CG(ni, cg, F0, F1) {                                                  \
    f32x4 ac = zf4;                                                               \
    ac = MF(a0_, F0, ac);                                                         \
    ac = MF(a1_, F1, ac);                                                         \
    float e0 = ex2(ac[0]), e1 = ex2(ac[1]), e2 = ex2(ac[2]), e3 = ex2(ac[3]);     \
    float E = (e0 + e1) + (e2 + e3);                                              \
    float f0 = b2f(feat[wid][(ni) * 16 + g4 + 0][(cg) * 16 + c16]);               \
    float f1 = b2f(feat[wid][(ni) * 16 + g4 + 1][(cg) * 16 + c16]);               \
    float f2 = b2f(feat[wid][(ni) * 16 + g4 + 2][(cg) * 16 + c16]);               \
    float f3 = b2f(feat[wid][(ni) * 16 + g4 + 3][(cg) * 16 + c16]);               \
    float Q = e0 * f0; Q = fmaf(e1, f1, Q); Q = fmaf(e2, f2, Q); Q = fmaf(e3, f3, Q); \
    E = xsum32(xsum16(E));                                                        \
    Q = xsum32(xsum16(Q));                                                        \
    if (g == 0) qe[(wid << 2) + (ni)][(cg) * 16 + c16] = pk2(Q, E); }
#define ATT_NI(ni) {                                                              \
    bf16x8 a0_ = *(const bf16x8*)&feat[wid][(ni) * 16 + c16][g8];                 \
    bf16x8 a1_ = *(const bf16x8*)&feat[wid][(ni) * 16 + c16][32 + g8];            \
    ATT_CG(ni, 0, afc0_0, afc0_1) ATT_CG(ni, 1, afc1_0, afc1_1)                   \
    ATT_CG(ni, 2, afc2_0, afc2_1) ATT_CG(ni, 3, afc3_0, afc3_1) }

// build agg B-frags from qe (divide deferred to here)
#define QFRAG(bbv, base) {                                                        \
    uint4 _qa = *(const uint4*)&qe[c16][(base) + g8];                             \
    uint4 _qb = *(const uint4*)&qe[c16][(base) + g8 + 4];                         \
    bbv.u.x = pk2(qdiv(_qa.x), qdiv(_qa.y));                                      \
    bbv.u.y = pk2(qdiv(_qa.z), qdiv(_qa.w));                                      \
    bbv.u.z = pk2(qdiv(_qb.x), qdiv(_qb.y));                                      \
    bbv.u.w = pk2(qdiv(_qb.z), qdiv(_qb.w)); }

// ---------------- Kernel 1: f_pc = relu(bn(w_mlp1 @ feature)) -> bf16 (B*N,32) ----------------
__global__ __launch_bounds__(256, 4) void k1_mlp1(
    const float* __restrict__ feature, const float* __restrict__ w_mlp1,
    const float* __restrict__ g_mlp1, const float* __restrict__ b_mlp1,
    ushort* __restrict__ f_pc, ushort* __restrict__ featpm)
{
    int tid = threadIdx.x;
    int pg = blockIdx.x * 256 + tid;
    int b = pg >> 15, n = pg & (NPTS - 1);

    float x[CIN];
#pragma unroll
    for (int c = 0; c < CIN; ++c)
        x[c] = feature[((b * CIN + c) << 15) + n];

    float outv[CIN];
#pragma unroll
    for (int o = 0; o < CIN; ++o) {
        float s0 = 0.f, s1 = 0.f, s2 = 0.f, s3 = 0.f;
        const float* w = w_mlp1 + o * CIN;
#pragma unroll
        for (int c = 0; c < CIN; c += 4) {
            s0 = fmaf(w[c + 0], x[c + 0], s0);
            s1 = fmaf(w[c + 1], x[c + 1], s1);
            s2 = fmaf(w[c + 2], x[c + 2], s2);
            s3 = fmaf(w[c + 3], x[c + 3], s3);
        }
        float acc = (s0 + s1) + (s2 + s3);
        outv[o] = fmaxf(fmaf(acc, g_mlp1[o] * BN_RS, b_mlp1[o]), 0.f);
    }
    uint4* dst = (uint4*)(f_pc + ((size_t)pg << 5));
    uint4* dst2 = (uint4*)(featpm + ((size_t)pg << 5));
#pragma unroll
    for (int j = 0; j < 4; ++j) {
        uint4 u;
        u.x = pk2(outv[8 * j + 0], outv[8 * j + 1]);
        u.y = pk2(outv[8 * j + 2], outv[8 * j + 3]);
        u.z = pk2(outv[8 * j + 4], outv[8 * j + 5]);
        u.w = pk2(outv[8 * j + 6], outv[8 * j + 7]);
        dst[j] = u;
        uint4 v;
        v.x = pk2(x[8 * j + 0], x[8 * j + 1]);
        v.y = pk2(x[8 * j + 2], x[8 * j + 3]);
        v.z = pk2(x[8 * j + 4], x[8 * j + 5]);
        v.w = pk2(x[8 * j + 6], x[8 * j + 7]);
        dst2[j] = v;
    }
}

// ---------------- Kernel 2: stage-1 -> f_agg bf16 (B*N, 32) ----------------
__global__ __launch_bounds__(256, 3) void k2_stage1(
    const float* __restrict__ xyz, const int* __restrict__ nidx,
    const ushort* __restrict__ f_pc,
    const float* __restrict__ bb_w1, const float* __restrict__ bb_g1, const float* __restrict__ bb_b1,
    const float* __restrict__ att_fc,
    const float* __restrict__ att_w, const float* __restrict__ att_g, const float* __restrict__ att_b,
    ushort* __restrict__ f_agg)
{
    __shared__ __align__(16) ushort feat[4][64][72];   // per-wave 64 pos x 64 ch bf16
    __shared__ __align__(16) unsigned qe[16][68];      // packed (Q,E) per point x channel
    __shared__ __align__(16) ushort fcb[64][72];       // att1_fc * log2e, bf16
    __shared__ __align__(16) ushort w1p[32][40];       // folded bb_w1, K-padded to 32

    int tid = threadIdx.x;
    for (int i = tid; i < D * D; i += 256) fcb[i >> 6][i & 63] = f2b(att_fc[i] * LOG2E);
    for (int i = tid; i < 32 * 32; i += 256) {
        int o = i >> 5, k = i & 31;
        w1p[o][k] = (k < 10) ? f2b(bb_w1[o * 10 + k] * (bb_g1[o] * BN_RS)) : (ushort)0;
    }
    __syncthreads();

    int wid = tid >> 6, lane = tid & 63;
    int g = lane >> 4, c16 = lane & 15;
    int g4 = g << 2, g8 = g << 3;
    f32x4 zf4 = {0.f, 0.f, 0.f, 0.f};

    int pb = (blockIdx.x << 4) + (wid << 2) + g;       // this lane's build point
    int b = pb >> 15, n = pb & (NPTS - 1);
    int nb = nidx[((size_t)pb << 4) + c16];

    // issue neighbor-feature gather early
    const bf16x8* gsrc = (const bf16x8*)(f_pc + (((size_t)(b * NPTS + nb)) << 5));
    bf16x8 gv0 = gsrc[0], gv1 = gsrc[1], gv2 = gsrc[2], gv3 = gsrc[3];

    // rel-pos inputs
    const float* cx = xyz + (size_t)(b * NPTS + n) * 3;
    const float* nx = xyz + (size_t)(b * NPTS + nb) * 3;
    float c0 = cx[0], c1 = cx[1], c2 = cx[2];
    float x0 = nx[0], x1 = nx[1], x2 = nx[2];
    float r0 = c0 - x0, r1 = c1 - x1, r2 = c2 - x2;
    float dist = sqrtf(r0 * r0 + r1 * r1 + r2 * r2);

    // stage in10 bf16 (zero-padded to 32) into feat cols 32..63
    {
        uint4 u0; u0.x = pk2(dist, r0); u0.y = pk2(r1, r2); u0.z = pk2(c0, c1); u0.w = pk2(c2, x0);
        uint4 u1; u1.x = pk2(x1, x2); u1.y = 0; u1.z = 0; u1.w = 0;
        uint4 z4; z4.x = 0; z4.y = 0; z4.z = 0; z4.w = 0;
        *(uint4*)&feat[wid][lane][32] = u0;
        *(uint4*)&feat[wid][lane][40] = u1;
        *(uint4*)&feat[wid][lane][48] = z4;
        *(uint4*)&feat[wid][lane][56] = z4;
    }
    // FXYZ MFMA: read all B-frags before overwrite
    {
        bf16x8 xb0 = *(const bf16x8*)&feat[wid][ 0 + c16][32 + g8];
        bf16x8 xb1 = *(const bf16x8*)&feat[wid][16 + c16][32 + g8];
        bf16x8 xb2 = *(const bf16x8*)&feat[wid][32 + c16][32 + g8];
        bf16x8 xb3 = *(const bf16x8*)&feat[wid][48 + c16][32 + g8];
        bf16x8 wa0 = *(const bf16x8*)&w1p[     c16][g8];
        bf16x8 wa1 = *(const bf16x8*)&w1p[16 + c16][g8];
        f32x4 bi0 = *(const f32x4*)&bb_b1[g4];
        f32x4 bi1 = *(const f32x4*)&bb_b1[16 + g4];
        f32x4 f00 = MF(wa0, xb0, bi0);
        f32x4 f01 = MF(wa0, xb1, bi0);
        f32x4 f02 = MF(wa0, xb2, bi0);
        f32x4 f03 = MF(wa0, xb3, bi0);
        f32x4 f10 = MF(wa1, xb0, bi1);
        f32x4 f11 = MF(wa1, xb1, bi1);
        f32x4 f12 = MF(wa1, xb2, bi1);
        f32x4 f13 = MF(wa1, xb3, bi1);
        WBX(0, 0, f00) WBX(0, 1, f01) WBX(0, 2, f02) WBX(0, 3, f03)
        WBX(1, 0, f10) WBX(1, 1, f11) WBX(1, 2, f12) WBX(1, 3, f13)
    }
    // gathered neighbor features (ch 0..31)
    *(bf16x8*)&feat[wid][lane][0]  = gv0;
    *(bf16x8*)&feat[wid][lane][8]  = gv1;
    *(bf16x8*)&feat[wid][lane][16] = gv2;
    *(bf16x8*)&feat[wid][lane][24] = gv3;

    // fc B-fragments from LDS (transposed MFMA: B cols = output channels)
    bf16x8 afc0_0 = *(const bf16x8*)&fcb[ 0 + c16][     g8];
    bf16x8 afc0_1 = *(const bf16x8*)&fcb[ 0 + c16][32 + g8];
    bf16x8 afc1_0 = *(const bf16x8*)&fcb[16 + c16][     g8];
    bf16x8 afc1_1 = *(const bf16x8*)&fcb[16 + c16][32 + g8];
    bf16x8 afc2_0 = *(const bf16x8*)&fcb[32 + c16][     g8];
    bf16x8 afc2_1 = *(const bf16x8*)&fcb[32 + c16][32 + g8];
    bf16x8 afc3_0 = *(const bf16x8*)&fcb[48 + c16][     g8];
    bf16x8 afc3_1 = *(const bf16x8*)&fcb[48 + c16][32 + g8];

    ATT_NI(0) ATT_NI(1) ATT_NI(2) ATT_NI(3)
    __syncthreads();

    // out-MLP via MFMA: waves 0,1 -> mi; B-frags built with deferred divide
    if (wid < 2) {
        union { bf16x8 v; uint4 u; } bb0, bb1;
        QFRAG(bb0, 0)
        QFRAG(bb1, 32)
        int o = (wid << 4) + c16;
        float sc = att_g[o] * BN_RS;
        const float* wr0 = att_w + o * D + g8;
        const float* wr1 = att_w + o * D + 32 + g8;
        union { bf16x8 v; uint4 u; } aw0, aw1;
        aw0.u.x = pk2(wr0[0] * sc, wr0[1] * sc);
        aw0.u.y = pk2(wr0[2] * sc, wr0[3] * sc);
        aw0.u.z = pk2(wr0[4] * sc, wr0[5] * sc);
        aw0.u.w = pk2(wr0[6] * sc, wr0[7] * sc);
        aw1.u.x = pk2(wr1[0] * sc, wr1[1] * sc);
        aw1.u.y = pk2(wr1[2] * sc, wr1[3] * sc);
        aw1.u.z = pk2(wr1[4] * sc, wr1[5] * sc);
        aw1.u.w = pk2(wr1[6] * sc, wr1[7] * sc);
        f32x4 acc = *(const f32x4*)&att_b[(wid << 4) + g4];
        acc = MF(aw0.v, bb0.v, acc);
        acc = MF(aw1.v, bb1.v, acc);
        int p = (blockIdx.x << 4) + c16;
        int o0 = (wid << 4) + g4;
        uint2 st;
        st.x = pk2(fmaxf(acc[0], 0.f), fmaxf(acc[1], 0.f));
        st.y = pk2(fmaxf(acc[2], 0.f), fmaxf(acc[3], 0.f));
        *(uint2*)(f_agg + (((size_t)p) << 5) + o0) = st;
    }
}

// ---------------- Kernel 3: stage-2 -> fagg2 bf16 point-major (B*N, 64) ----------------
__global__ __launch_bounds__(256, 3) void k3_stage2(
    const float* __restrict__ xyz, const int* __restrict__ nidx,
    const ushort* __restrict__ f_agg,
    const float* __restrict__ bb_w1, const float* __restrict__ bb_g1, const float* __restrict__ bb_b1,
    const float* __restrict__ bb_w2, const float* __restrict__ bb_g2, const float* __restrict__ bb_b2,
    const float* __restrict__ att_fc,
    const float* __restrict__ att_w, const float* __restrict__ att_g, const float* __restrict__ att_b,
    ushort* __restrict__ fagg2b)
{
    __shared__ __align__(16) ushort feat[4][64][72];
    __shared__ __align__(16) unsigned qe[16][68];
    __shared__ __align__(16) ushort fcb[64][72];
    __shared__ __align__(16) ushort w1p[32][40];

    int tid = threadIdx.x;
    for (int i = tid; i < D * D; i += 256) fcb[i >> 6][i & 63] = f2b(att_fc[i] * LOG2E);
    for (int i = tid; i < 32 * 32; i += 256) {
        int o = i >> 5, k = i & 31;
        w1p[o][k] = (k < 10) ? f2b(bb_w1[o * 10 + k] * (bb_g1[o] * BN_RS)) : (ushort)0;
    }
    __syncthreads();

    int wid = tid >> 6, lane = tid & 63;
    int g = lane >> 4, c16 = lane & 15;
    int g4 = g << 2, g8 = g << 3;
    f32x4 zf4 = {0.f, 0.f, 0.f, 0.f};

    int pb = (blockIdx.x << 4) + (wid << 2) + g;
    int b = pb >> 15, n = pb & (NPTS - 1);
    int nb = nidx[((size_t)pb << 4) + c16];

    const bf16x8* gsrc = (const bf16x8*)(f_agg + (((size_t)(b * NPTS + nb)) << 5));
    bf16x8 gv0 = gsrc[0], gv1 = gsrc[1], gv2 = gsrc[2], gv3 = gsrc[3];

    const float* cx = xyz + (size_t)(b * NPTS + n) * 3;
    const float* nx = xyz + (size_t)(b * NPTS + nb) * 3;
    float c0 = cx[0], c1 = cx[1], c2 = cx[2];
    float x0 = nx[0], x1 = nx[1], x2 = nx[2];
    float r0 = c0 - x0, r1 = c1 - x1, r2 = c2 - x2;
    float dist = sqrtf(r0 * r0 + r1 * r1 + r2 * r2);

    // stage in10
    {
        uint4 u0; u0.x = pk2(dist, r0); u0.y = pk2(r1, r2); u0.z = pk2(c0, c1); u0.w = pk2(c2, x0);
        uint4 u1; u1.x = pk2(x1, x2); u1.y = 0; u1.z = 0; u1.w = 0;
        uint4 z4; z4.x = 0; z4.y = 0; z4.z = 0; z4.w = 0;
        *(uint4*)&feat[wid][lane][32] = u0;
        *(uint4*)&feat[wid][lane][40] = u1;
        *(uint4*)&feat[wid][lane][48] = z4;
        *(uint4*)&feat[wid][lane][56] = z4;
    }
    // FXYZ MFMA -> stage-1 fx in cols 32..63
    {
        bf16x8 xb0 = *(const bf16x8*)&feat[wid][ 0 + c16][32 + g8];
        bf16x8 xb1 = *(const bf16x8*)&feat[wid][16 + c16][32 + g8];
        bf16x8 xb2 = *(const bf16x8*)&feat[wid][32 + c16][32 + g8];
        bf16x8 xb3 = *(const bf16x8*)&feat[wid][48 + c16][32 + g8];
        bf16x8 wa0 = *(const bf16x8*)&w1p[     c16][g8];
        bf16x8 wa1 = *(const bf16x8*)&w1p[16 + c16][g8];
        f32x4 bi0 = *(const f32x4*)&bb_b1[g4];
        f32x4 bi1 = *(const f32x4*)&bb_b1[16 + g4];
        f32x4 f00 = MF(wa0, xb0, bi0);
        f32x4 f01 = MF(wa0, xb1, bi0);
        f32x4 f02 = MF(wa0, xb2, bi0);
        f32x4 f03 = MF(wa0, xb3, bi0);
        f32x4 f10 = MF(wa1, xb0, bi1);
        f32x4 f11 = MF(wa1, xb1, bi1);
        f32x4 f12 = MF(wa1, xb2, bi1);
        f32x4 f13 = MF(wa1, xb3, bi1);
        WBX(0, 0, f00) WBX(0, 1, f01) WBX(0, 2, f02) WBX(0, 3, f03)
        WBX(1, 0, f10) WBX(1, 1, f11) WBX(1, 2, f12) WBX(1, 3, f13)
    }
    // bb_w2 A-fragments (in-register fold)
    union { bf16x8 v; uint4 u; } aw20, aw21;
    {
        int o = c16;
        float sc2 = bb_g2[o] * BN_RS;
        const float* wr = bb_w2 + o * H + g8;
        aw20.u.x = pk2(wr[0] * sc2, wr[1] * sc2);
        aw20.u.y = pk2(wr[2] * sc2, wr[3] * sc2);
        aw20.u.z = pk2(wr[4] * sc2, wr[5] * sc2);
        aw20.u.w = pk2(wr[6] * sc2, wr[7] * sc2);
    }
    {
        int o = 16 + c16;
        float sc2 = bb_g2[o] * BN_RS;
        const float* wr = bb_w2 + o * H + g8;
        aw21.u.x = pk2(wr[0] * sc2, wr[1] * sc2);
        aw21.u.y = pk2(wr[2] * sc2, wr[3] * sc2);
        aw21.u.z = pk2(wr[4] * sc2, wr[5] * sc2);
        aw21.u.w = pk2(wr[6] * sc2, wr[7] * sc2);
    }
    // fx B-frags (read before overwrite), then f_xyz2 = relu(bn(bb_w2 @ fx))
    {
        bf16x8 bfx0 = *(const bf16x8*)&feat[wid][ 0 + c16][32 + g8];
        bf16x8 bfx1 = *(const bf16x8*)&feat[wid][16 + c16][32 + g8];
        bf16x8 bfx2 = *(const bf16x8*)&feat[wid][32 + c16][32 + g8];
        bf16x8 bfx3 = *(const bf16x8*)&feat[wid][48 + c16][32 + g8];
        f32x4 bi0 = *(const f32x4*)&bb_b2[     g4];
        f32x4 bi1 = *(const f32x4*)&bb_b2[16 + g4];
        f32x4 a00 = MF(aw20.v, bfx0, bi0);
        f32x4 a01 = MF(aw20.v, bfx1, bi0);
        f32x4 a02 = MF(aw20.v, bfx2, bi0);
        f32x4 a03 = MF(aw20.v, bfx3, bi0);
        f32x4 a10 = MF(aw21.v, bfx0, bi1);
        f32x4 a11 = MF(aw21.v, bfx1, bi1);
        f32x4 a12 = MF(aw21.v, bfx2, bi1);
        f32x4 a13 = MF(aw21.v, bfx3, bi1);
        WBX(0, 0, a00) WBX(0, 1, a01) WBX(0, 2, a02) WBX(0, 3, a03)
        WBX(1, 0, a10) WBX(1, 1, a11) WBX(1, 2, a12) WBX(1, 3, a13)
    }
    // gathered f_agg neighbor features (ch 0..31)
    *(bf16x8*)&feat[wid][lane][0]  = gv0;
    *(bf16x8*)&feat[wid][lane][8]  = gv1;
    *(bf16x8*)&feat[wid][lane][16] = gv2;
    *(bf16x8*)&feat[wid][lane][24] = gv3;

    bf16x8 afc0_0 = *(const bf16x8*)&fcb[ 0 + c16][     g8];
    bf16x8 afc0_1 = *(const bf16x8*)&fcb[ 0 + c16][32 + g8];
    bf16x8 afc1_0 = *(const bf16x8*)&fcb[16 + c16][     g8];
    bf16x8 afc1_1 = *(const bf16x8*)&fcb[16 + c16][32 + g8];
    bf16x8 afc2_0 = *(const bf16x8*)&fcb[32 + c16][     g8];
    bf16x8 afc2_1 = *(const bf16x8*)&fcb[32 + c16][32 + g8];
    bf16x8 afc3_0 = *(const bf16x8*)&fcb[48 + c16][     g8];
    bf16x8 afc3_1 = *(const bf16x8*)&fcb[48 + c16][32 + g8];

    ATT_NI(0) ATT_NI(1) ATT_NI(2) ATT_NI(3)
    __syncthreads();

    // out-MLP via MFMA: wave wid -> mi; bf16 store
    {
        union { bf16x8 v; uint4 u; } bb0, bb1;
        QFRAG(bb0, 0)
        QFRAG(bb1, 32)
        int o = (wid << 4) + c16;
        float sc = att_g[o] * BN_RS;
        const float* wr0 = att_w + o * D + g8;
        const float* wr1 = att_w + o * D + 32 + g8;
        union { bf16x8 v; uint4 u; } aw0, aw1;
        aw0.u.x = pk2(wr0[0] * sc, wr0[1] * sc);
        aw0.u.y = pk2(wr0[2] * sc, wr0[3] * sc);
        aw0.u.z = pk2(wr0[4] * sc, wr0[5] * sc);
        aw0.u.w = pk2(wr0[6] * sc, wr0[7] * sc);
        aw1.u.x = pk2(wr1[0] * sc, wr1[1] * sc);
        aw1.u.y = pk2(wr1[2] * sc, wr1[3] * sc);
        aw1.u.z = pk2(wr1[4] * sc, wr1[5] * sc);
        aw1.u.w = pk2(wr1[6] * sc, wr1[7] * sc);
        f32x4 acc = *(const f32x4*)&att_b[(wid << 4) + g4];
        acc = MF(aw0.v, bb0.v, acc);
        acc = MF(aw1.v, bb1.v, acc);
        int p = (blockIdx.x << 4) + c16;
        int o0 = (wid << 4) + g4;
        uint2 st;
        st.x = pk2(fmaxf(acc[0], 0.f), fmaxf(acc[1], 0.f));
        st.y = pk2(fmaxf(acc[2], 0.f), fmaxf(acc[3], 0.f));
        *(uint2*)(fagg2b + (((size_t)p) << 6) + o0) = st;
    }
}

// ---------------- Kernel 4: MFMA GEMM out[128 x pts] = Wcat[128x96] @ X[96 x pts] ----------------
__global__ __launch_bounds__(256, 4) void k4_final(
    const ushort* __restrict__ fagg2b, const ushort* __restrict__ featpm,
    const float* __restrict__ w_mlp2, const float* __restrict__ g_mlp2, const float* __restrict__ b_mlp2,
    const float* __restrict__ w_sc, const float* __restrict__ g_sc, const float* __restrict__ b_sc,
    float* __restrict__ out)
{
    int tid = threadIdx.x;
    int wid = tid >> 6, lane = tid & 63;
    int c16 = lane & 15, g = lane >> 4;
    int g4 = g << 2, g8 = g << 3;
    int p0 = blockIdx.x << 6;
    int o0 = wid << 5;

    union { bf16x8 v; uint4 u; } A[2][3];
#pragma unroll
    for (int mi = 0; mi < 2; ++mi) {
        int o = o0 + mi * 16 + c16;
        float sm = g_mlp2[o] * BN_RS, ss = g_sc[o] * BN_RS;
        const float* wm = w_mlp2 + o * D;
        const float* ws = w_sc + o * CIN;
#pragma unroll
        for (int ks = 0; ks < 2; ++ks) {
            float4 wa = *(const float4*)&wm[ks * 32 + g8];
            float4 wb = *(const float4*)&wm[ks * 32 + g8 + 4];
            A[mi][ks].u.x = pk2(wa.x * sm, wa.y * sm);
            A[mi][ks].u.y = pk2(wa.z * sm, wa.w * sm);
            A[mi][ks].u.z = pk2(wb.x * sm, wb.y * sm);
            A[mi][ks].u.w = pk2(wb.z * sm, wb.w * sm);
        }
        float4 wa = *(const float4*)&ws[g8];
        float4 wb = *(const float4*)&ws[g8 + 4];
        A[mi][2].u.x = pk2(wa.x * ss, wa.y * ss);
        A[mi][2].u.y = pk2(wa.z * ss, wa.w * ss);
        A[mi][2].u.z = pk2(wb.x * ss, wb.y * ss);
        A[mi][2].u.w = pk2(wb.z * ss, wb.w * ss);
    }
    float bias0[4], bias1[4];
#pragma unroll
    for (int r = 0; r < 4; ++r) {
        int oa = o0 + g4 + r;
        int ob = o0 + 16 + g4 + r;
        bias0[r] = b_mlp2[oa] + b_sc[oa];
        bias1[r] = b_mlp2[ob] + b_sc[ob];
    }

    int bb = p0 >> 15;
#pragma unroll
    for (int ni = 0; ni < 4; ++ni) {
        int pt = p0 + ni * 16 + c16;
        bf16x8 B0 = *(const bf16x8*)&fagg2b[((size_t)pt << 6) + g8];
        bf16x8 B1 = *(const bf16x8*)&fagg2b[((size_t)pt << 6) + 32 + g8];
        bf16x8 B2 = *(const bf16x8*)&featpm[((size_t)pt << 5) + g8];
        f32x4 acc0 = {bias0[0], bias0[1], bias0[2], bias0[3]};
        f32x4 acc1 = {bias1[0], bias1[1], bias1[2], bias1[3]};
        acc0 = MF(A[0][0].v, B0, acc0);
        acc0 = MF(A[0][1].v, B1, acc0);
        acc0 = MF(A[0][2].v, B2, acc0);
        acc1 = MF(A[1][0].v, B0, acc1);
        acc1 = MF(A[1][1].v, B1, acc1);
        acc1 = MF(A[1][2].v, B2, acc1);
        int nn = pt & (NPTS - 1);
#pragma unroll
        for (int r = 0; r < 4; ++r) {
            float v0 = acc0[r];
            v0 = (v0 >= 0.f) ? v0 : 0.2f * v0;
            out[((bb * DOUT + o0 + g4 + r) << 15) + nn] = v0;
            float v1 = acc1[r];
            v1 = (v1 >= 0.f) ? v1 : 0.2f * v1;
            out[((bb * DOUT + o0 + 16 + g4 + r) << 15) + nn] = v1;
        }
    }
}

extern "C" void kernel_launch(void* const* d_in, const int* in_sizes, int n_in,
                              void* d_out, int out_size, void* d_ws, size_t ws_size,
                              hipStream_t stream) {
    const float* feature = (const float*)d_in[0];
    const float* xyz     = (const float*)d_in[1];
    const float* w_mlp1  = (const float*)d_in[2];
    const float* g_mlp1  = (const float*)d_in[3];
    const float* b_mlp1  = (const float*)d_in[4];
    const float* bb_w1   = (const float*)d_in[5];
    const float* bb_g1   = (const float*)d_in[6];
    const float* bb_b1   = (const float*)d_in[7];
    const float* att1_fc = (const float*)d_in[8];
    const float* att1_w  = (const float*)d_in[9];
    const float* att1_g  = (const float*)d_in[10];
    const float* att1_b  = (const float*)d_in[11];
    const float* bb_w2   = (const float*)d_in[12];
    const float* bb_g2   = (const float*)d_in[13];
    const float* bb_b2   = (const float*)d_in[14];
    const float* att2_fc = (const float*)d_in[15];
    const float* att2_w  = (const float*)d_in[16];
    const float* att2_g  = (const float*)d_in[17];
    const float* att2_b  = (const float*)d_in[18];
    const float* w_mlp2  = (const float*)d_in[19];
    const float* g_mlp2  = (const float*)d_in[20];
    const float* b_mlp2  = (const float*)d_in[21];
    const float* w_sc    = (const float*)d_in[22];
    const float* g_sc    = (const float*)d_in[23];
    const float* b_sc    = (const float*)d_in[24];
    const int*   nidx    = (const int*)d_in[25];
    float* out = (float*)d_out;

    ushort* f_pc_bf  = (ushort*)d_ws;                              // B*N*32 bf16
    ushort* f_agg_bf = f_pc_bf + (size_t)NB * NPTS * 32;           // B*N*32 bf16
    ushort* featpm   = f_agg_bf + (size_t)NB * NPTS * 32;          // B*N*32 bf16
    ushort* fagg2b   = featpm + (size_t)NB * NPTS * 32;            // B*N*64 bf16

    k1_mlp1<<<NB * NPTS / 256, 256, 0, stream>>>(feature, w_mlp1, g_mlp1, b_mlp1,
                                                 f_pc_bf, featpm);
    k2_stage1<<<NB * NPTS / 16, 256, 0, stream>>>(xyz, nidx, f_pc_bf,
                                                  bb_w1, bb_g1, bb_b1,
                                                  att1_fc, att1_w, att1_g, att1_b, f_agg_bf);
    k3_stage2<<<NB * NPTS / 16, 256, 0, stream>>>(xyz, nidx, f_agg_bf,
                                                  bb_w1, bb_g1, bb_b1,
                                                  bb_w2, bb_g2, bb_b2,
                                                  att2_fc, att2_w, att2_g, att2_b, fagg2b);
    k4_final<<<NB * NPTS / 64, 256, 0, stream>>>(fagg2b, featpm,
                                                 w_mlp2, g_mlp2, b_mlp2,
                                                 w_sc, g_sc, b_sc, out);
}

// Round 13
// 132.710 us; speedup vs baseline: 4.2567x; 1.0436x over previous
//
#include <hip/hip_runtime.h>
#include <math.h>

#define NPTS 32768
#define NB 2
#define CIN 32
#define H 32
#define D 64
#define DOUT 128
#define BN_RS 0.99999500003749981f   // 1/sqrt(1 + 1e-5)
#define LOG2E 1.44269504088896341f

typedef __attribute__((ext_vector_type(8))) short bf16x8;
typedef __attribute__((ext_vector_type(4))) short bf16x4;
typedef __attribute__((ext_vector_type(4))) float f32x4;

__device__ __forceinline__ ushort f2b(float f) {
    union { float f; unsigned u; } v; v.f = f;
    unsigned r = v.u + 0x7fffu + ((v.u >> 16) & 1u);   // RNE
    return (ushort)(r >> 16);
}
__device__ __forceinline__ float b2f(ushort u) {
    union { unsigned u; float f; } v; v.u = ((unsigned)u) << 16; return v.f;
}
// pack two f32 -> bf16x2 dword via gfx950 v_cvt_pk_bf16_f32 (1 inst); lo = f0, hi = f1
__device__ __forceinline__ unsigned pk2(float f0, float f1) {
    unsigned r;
    asm("v_cvt_pk_bf16_f32 %0, %1, %2" : "=v"(r) : "v"(f0), "v"(f1));
    return r;
}
// unpack (Q,E) dword -> Q/E
__device__ __forceinline__ float qdiv(unsigned u) {
    float q = __builtin_bit_cast(float, u << 16);
    float e = __builtin_bit_cast(float, u & 0xffff0000u);
    return __fdividef(q, e);
}
// raw 2^x (weights pre-scaled by log2e)
__device__ __forceinline__ float ex2(float x) {
    float r; asm("v_exp_f32 %0, %1" : "=v"(r) : "v"(x)); return r;
}
// cross-row sums via gfx950 permlane swaps (VALU pipe, no DS):
// {a,b} = permlaneN_swap(x,x); a+b == x[l] + x[l^N] in every lane
__device__ __forceinline__ float xsum16(float x) {
    float a = x, b = x;
    asm("v_permlane16_swap_b32 %0, %1" : "+v"(a), "+v"(b));
    return a + b;
}
__device__ __forceinline__ float xsum32(float x) {
    float a = x, b = x;
    asm("v_permlane32_swap_b32 %0, %1" : "+v"(a), "+v"(b));
    return a + b;
}
#define MF(a, b, c) __builtin_amdgcn_mfma_f32_16x16x32_bf16(a, b, c, 0, 0, 0)

// WBX: write relu'd C tile (mi,ni) to feat cols 32..63  (C: row=channel, col=position)
#define WBX(mi, ni, A) { uint2 _w;                                                \
    _w.x = pk2(fmaxf(A[0], 0.f), fmaxf(A[1], 0.f));                               \
    _w.y = pk2(fmaxf(A[2], 0.f), fmaxf(A[3], 0.f));                               \
    *(uint2*)&feat[wid][(ni) * 16 + c16][32 + (mi) * 16 + g4] = _w; }

// ---- transposed attention core: L^T = feat @ fc^T -> k on rows ----
// lane holds L[pos = ni*16 + g4 + r][o = cg*16 + c16]; reduce over r (in-reg) + g (permlane)
#define ATT_CG(ni, cg, F0, F1) {                                                  \
    f32x4 ac = zf4;                                                               \
    ac = MF(a0_, F0, ac);                                                         \
    ac = MF(a1_, F1, ac);                                                         \
    float e0 = ex2(ac[0]), e1 = ex2(ac[1]), e2 = ex2(ac[2]), e3 = ex2(ac[3]);     \
    float E = (e0 + e1) + (e2 + e3);                                              \
    float f0 = b2f(feat[wid][(ni) * 16 + g4 + 0][(cg) * 16 + c16]);               \
    float f1 = b2f(feat[wid][(ni) * 16 + g4 + 1][(cg) * 16 + c16]);               \
    float f2 = b2f(feat[wid][(ni) * 16 + g4 + 2][(cg) * 16 + c16]);               \
    float f3 = b2f(feat[wid][(ni) * 16 + g4 + 3][(cg) * 16 + c16]);               \
    float Q = e0 * f0; Q = fmaf(e1, f1, Q); Q = fmaf(e2, f2, Q); Q = fmaf(e3, f3, Q); \
    E = xsum32(xsum16(E));                                                        \
    Q = xsum32(xsum16(Q));                                                        \
    if (g == 0) qe[(wid << 2) + (ni)][(cg) * 16 + c16] = pk2(Q, E); }
#define ATT_NI(ni) {                                                              \
    bf16x8 a0_ = *(const bf16x8*)&feat[wid][(ni) * 16 + c16][g8];                 \
    bf16x8 a1_ = *(const bf16x8*)&feat[wid][(ni) * 16 + c16][32 + g8];            \
    ATT_CG(ni, 0, afc0_0, afc0_1) ATT_CG(ni, 1, afc1_0, afc1_1)                   \
    ATT_CG(ni, 2, afc2_0, afc2_1) ATT_CG(ni, 3, afc3_0, afc3_1) }

// build agg B-frags from qe (divide deferred to here)
#define QFRAG(bbv, base) {                                                        \
    uint4 _qa = *(const uint4*)&qe[c16][(base) + g8];                             \
    uint4 _qb = *(const uint4*)&qe[c16][(base) + g8 + 4];                         \
    bbv.u.x = pk2(qdiv(_qa.x), qdiv(_qa.y));                                      \
    bbv.u.y = pk2(qdiv(_qa.z), qdiv(_qa.w));                                      \
    bbv.u.z = pk2(qdiv(_qb.x), qdiv(_qb.y));                                      \
    bbv.u.w = pk2(qdiv(_qb.z), qdiv(_qb.w)); }

// ---------------- Kernel 1: f_pc = relu(bn(w_mlp1 @ feature)) -> bf16 (B*N,32) ----------------
__global__ __launch_bounds__(256, 4) void k1_mlp1(
    const float* __restrict__ feature, const float* __restrict__ w_mlp1,
    const float* __restrict__ g_mlp1, const float* __restrict__ b_mlp1,
    ushort* __restrict__ f_pc, ushort* __restrict__ featpm)
{
    int tid = threadIdx.x;
    int pg = blockIdx.x * 256 + tid;
    int b = pg >> 15, n = pg & (NPTS - 1);

    float x[CIN];
#pragma unroll
    for (int c = 0; c < CIN; ++c)
        x[c] = feature[((b * CIN + c) << 15) + n];

    float outv[CIN];
#pragma unroll
    for (int o = 0; o < CIN; ++o) {
        float s0 = 0.f, s1 = 0.f, s2 = 0.f, s3 = 0.f;
        const float* w = w_mlp1 + o * CIN;
#pragma unroll
        for (int c = 0; c < CIN; c += 4) {
            s0 = fmaf(w[c + 0], x[c + 0], s0);
            s1 = fmaf(w[c + 1], x[c + 1], s1);
            s2 = fmaf(w[c + 2], x[c + 2], s2);
            s3 = fmaf(w[c + 3], x[c + 3], s3);
        }
        float acc = (s0 + s1) + (s2 + s3);
        outv[o] = fmaxf(fmaf(acc, g_mlp1[o] * BN_RS, b_mlp1[o]), 0.f);
    }
    uint4* dst = (uint4*)(f_pc + ((size_t)pg << 5));
    uint4* dst2 = (uint4*)(featpm + ((size_t)pg << 5));
#pragma unroll
    for (int j = 0; j < 4; ++j) {
        uint4 u;
        u.x = pk2(outv[8 * j + 0], outv[8 * j + 1]);
        u.y = pk2(outv[8 * j + 2], outv[8 * j + 3]);
        u.z = pk2(outv[8 * j + 4], outv[8 * j + 5]);
        u.w = pk2(outv[8 * j + 6], outv[8 * j + 7]);
        dst[j] = u;
        uint4 v;
        v.x = pk2(x[8 * j + 0], x[8 * j + 1]);
        v.y = pk2(x[8 * j + 2], x[8 * j + 3]);
        v.z = pk2(x[8 * j + 4], x[8 * j + 5]);
        v.w = pk2(x[8 * j + 6], x[8 * j + 7]);
        dst2[j] = v;
    }
}

// ---------------- Kernel 2: stage-1 -> f_agg bf16 (B*N, 32) ----------------
__global__ __launch_bounds__(256, 3) void k2_stage1(
    const float* __restrict__ xyz, const int* __restrict__ nidx,
    const ushort* __restrict__ f_pc,
    const float* __restrict__ bb_w1, const float* __restrict__ bb_g1, const float* __restrict__ bb_b1,
    const float* __restrict__ att_fc,
    const float* __restrict__ att_w, const float* __restrict__ att_g, const float* __restrict__ att_b,
    ushort* __restrict__ f_agg)
{
    __shared__ __align__(16) ushort feat[4][64][72];   // per-wave 64 pos x 64 ch bf16
    __shared__ __align__(16) unsigned qe[16][68];      // packed (Q,E) per point x channel
    __shared__ __align__(16) ushort fcb[64][72];       // att1_fc * log2e, bf16
    __shared__ __align__(16) ushort w1p[32][40];       // folded bb_w1, K-padded to 32

    int tid = threadIdx.x;
    for (int i = tid; i < D * D; i += 256) fcb[i >> 6][i & 63] = f2b(att_fc[i] * LOG2E);
    for (int i = tid; i < 32 * 32; i += 256) {
        int o = i >> 5, k = i & 31;
        w1p[o][k] = (k < 10) ? f2b(bb_w1[o * 10 + k] * (bb_g1[o] * BN_RS)) : (ushort)0;
    }
    __syncthreads();

    int wid = tid >> 6, lane = tid & 63;
    int g = lane >> 4, c16 = lane & 15;
    int g4 = g << 2, g8 = g << 3;
    f32x4 zf4 = {0.f, 0.f, 0.f, 0.f};

    int pb = (blockIdx.x << 4) + (wid << 2) + g;       // this lane's build point
    int b = pb >> 15, n = pb & (NPTS - 1);
    int nb = nidx[((size_t)pb << 4) + c16];

    // issue neighbor-feature gather early
    const bf16x8* gsrc = (const bf16x8*)(f_pc + (((size_t)(b * NPTS + nb)) << 5));
    bf16x8 gv0 = gsrc[0], gv1 = gsrc[1], gv2 = gsrc[2], gv3 = gsrc[3];

    // rel-pos inputs
    const float* cx = xyz + (size_t)(b * NPTS + n) * 3;
    const float* nx = xyz + (size_t)(b * NPTS + nb) * 3;
    float c0 = cx[0], c1 = cx[1], c2 = cx[2];
    float x0 = nx[0], x1 = nx[1], x2 = nx[2];
    float r0 = c0 - x0, r1 = c1 - x1, r2 = c2 - x2;
    float dist = sqrtf(r0 * r0 + r1 * r1 + r2 * r2);

    // stage in10 bf16 (zero-padded to 32) into feat cols 32..63
    {
        uint4 u0; u0.x = pk2(dist, r0); u0.y = pk2(r1, r2); u0.z = pk2(c0, c1); u0.w = pk2(c2, x0);
        uint4 u1; u1.x = pk2(x1, x2); u1.y = 0; u1.z = 0; u1.w = 0;
        uint4 z4; z4.x = 0; z4.y = 0; z4.z = 0; z4.w = 0;
        *(uint4*)&feat[wid][lane][32] = u0;
        *(uint4*)&feat[wid][lane][40] = u1;
        *(uint4*)&feat[wid][lane][48] = z4;
        *(uint4*)&feat[wid][lane][56] = z4;
    }
    // FXYZ MFMA: read all B-frags before overwrite
    {
        bf16x8 xb0 = *(const bf16x8*)&feat[wid][ 0 + c16][32 + g8];
        bf16x8 xb1 = *(const bf16x8*)&feat[wid][16 + c16][32 + g8];
        bf16x8 xb2 = *(const bf16x8*)&feat[wid][32 + c16][32 + g8];
        bf16x8 xb3 = *(const bf16x8*)&feat[wid][48 + c16][32 + g8];
        bf16x8 wa0 = *(const bf16x8*)&w1p[     c16][g8];
        bf16x8 wa1 = *(const bf16x8*)&w1p[16 + c16][g8];
        f32x4 bi0 = *(const f32x4*)&bb_b1[g4];
        f32x4 bi1 = *(const f32x4*)&bb_b1[16 + g4];
        f32x4 f00 = MF(wa0, xb0, bi0);
        f32x4 f01 = MF(wa0, xb1, bi0);
        f32x4 f02 = MF(wa0, xb2, bi0);
        f32x4 f03 = MF(wa0, xb3, bi0);
        f32x4 f10 = MF(wa1, xb0, bi1);
        f32x4 f11 = MF(wa1, xb1, bi1);
        f32x4 f12 = MF(wa1, xb2, bi1);
        f32x4 f13 = MF(wa1, xb3, bi1);
        WBX(0, 0, f00) WBX(0, 1, f01) WBX(0, 2, f02) WBX(0, 3, f03)
        WBX(1, 0, f10) WBX(1, 1, f11) WBX(1, 2, f12) WBX(1, 3, f13)
    }
    // gathered neighbor features (ch 0..31)
    *(bf16x8*)&feat[wid][lane][0]  = gv0;
    *(bf16x8*)&feat[wid][lane][8]  = gv1;
    *(bf16x8*)&feat[wid][lane][16] = gv2;
    *(bf16x8*)&feat[wid][lane][24] = gv3;

    // fc B-fragments from LDS (transposed MFMA: B cols = output channels)
    bf16x8 afc0_0 = *(const bf16x8*)&fcb[ 0 + c16][     g8];
    bf16x8 afc0_1 = *(const bf16x8*)&fcb[ 0 + c16][32 + g8];
    bf16x8 afc1_0 = *(const bf16x8*)&fcb[16 + c16][     g8];
    bf16x8 afc1_1 = *(const bf16x8*)&fcb[16 + c16][32 + g8];
    bf16x8 afc2_0 = *(const bf16x8*)&fcb[32 + c16][     g8];
    bf16x8 afc2_1 = *(const bf16x8*)&fcb[32 + c16][32 + g8];
    bf16x8 afc3_0 = *(const bf16x8*)&fcb[48 + c16][     g8];
    bf16x8 afc3_1 = *(const bf16x8*)&fcb[48 + c16][32 + g8];

    ATT_NI(0) ATT_NI(1) ATT_NI(2) ATT_NI(3)
    __syncthreads();

    // out-MLP via MFMA: waves 0,1 -> mi; B-frags built with deferred divide
    if (wid < 2) {
        union { bf16x8 v; uint4 u; } bb0, bb1;
        QFRAG(bb0, 0)
        QFRAG(bb1, 32)
        int o = (wid << 4) + c16;
        float sc = att_g[o] * BN_RS;
        const float* wr0 = att_w + o * D + g8;
        const float* wr1 = att_w + o * D + 32 + g8;
        union { bf16x8 v; uint4 u; } aw0, aw1;
        aw0.u.x = pk2(wr0[0] * sc, wr0[1] * sc);
        aw0.u.y = pk2(wr0[2] * sc, wr0[3] * sc);
        aw0.u.z = pk2(wr0[4] * sc, wr0[5] * sc);
        aw0.u.w = pk2(wr0[6] * sc, wr0[7] * sc);
        aw1.u.x = pk2(wr1[0] * sc, wr1[1] * sc);
        aw1.u.y = pk2(wr1[2] * sc, wr1[3] * sc);
        aw1.u.z = pk2(wr1[4] * sc, wr1[5] * sc);
        aw1.u.w = pk2(wr1[6] * sc, wr1[7] * sc);
        f32x4 acc = *(const f32x4*)&att_b[(wid << 4) + g4];
        acc = MF(aw0.v, bb0.v, acc);
        acc = MF(aw1.v, bb1.v, acc);
        int p = (blockIdx.x << 4) + c16;
        int o0 = (wid << 4) + g4;
        uint2 st;
        st.x = pk2(fmaxf(acc[0], 0.f), fmaxf(acc[1], 0.f));
        st.y = pk2(fmaxf(acc[2], 0.f), fmaxf(acc[3], 0.f));
        *(uint2*)(f_agg + (((size_t)p) << 5) + o0) = st;
    }
}

// ---------------- Kernel 3: stage-2 -> fagg2 bf16 point-major (B*N, 64) ----------------
__global__ __launch_bounds__(256, 3) void k3_stage2(
    const float* __restrict__ xyz, const int* __restrict__ nidx,
    const ushort* __restrict__ f_agg,
    const float* __restrict__ bb_w1, const float* __restrict__ bb_g1, const float* __restrict__ bb_b1,
    const float* __restrict__ bb_w2, const float* __restrict__ bb_g2, const float* __restrict__ bb_b2,
    const float* __restrict__ att_fc,
    const float* __restrict__ att_w, const float* __restrict__ att_g, const float* __restrict__ att_b,
    ushort* __restrict__ fagg2b)
{
    __shared__ __align__(16) ushort feat[4][64][72];
    __shared__ __align__(16) unsigned qe[16][68];
    __shared__ __align__(16) ushort fcb[64][72];
    __shared__ __align__(16) ushort w1p[32][40];

    int tid = threadIdx.x;
    for (int i = tid; i < D * D; i += 256) fcb[i >> 6][i & 63] = f2b(att_fc[i] * LOG2E);
    for (int i = tid; i < 32 * 32; i += 256) {
        int o = i >> 5, k = i & 31;
        w1p[o][k] = (k < 10) ? f2b(bb_w1[o * 10 + k] * (bb_g1[o] * BN_RS)) : (ushort)0;
    }
    __syncthreads();

    int wid = tid >> 6, lane = tid & 63;
    int g = lane >> 4, c16 = lane & 15;
    int g4 = g << 2, g8 = g << 3;
    f32x4 zf4 = {0.f, 0.f, 0.f, 0.f};

    int pb = (blockIdx.x << 4) + (wid << 2) + g;
    int b = pb >> 15, n = pb & (NPTS - 1);
    int nb = nidx[((size_t)pb << 4) + c16];

    const bf16x8* gsrc = (const bf16x8*)(f_agg + (((size_t)(b * NPTS + nb)) << 5));
    bf16x8 gv0 = gsrc[0], gv1 = gsrc[1], gv2 = gsrc[2], gv3 = gsrc[3];

    const float* cx = xyz + (size_t)(b * NPTS + n) * 3;
    const float* nx = xyz + (size_t)(b * NPTS + nb) * 3;
    float c0 = cx[0], c1 = cx[1], c2 = cx[2];
    float x0 = nx[0], x1 = nx[1], x2 = nx[2];
    float r0 = c0 - x0, r1 = c1 - x1, r2 = c2 - x2;
    float dist = sqrtf(r0 * r0 + r1 * r1 + r2 * r2);

    // stage in10
    {
        uint4 u0; u0.x = pk2(dist, r0); u0.y = pk2(r1, r2); u0.z = pk2(c0, c1); u0.w = pk2(c2, x0);
        uint4 u1; u1.x = pk2(x1, x2); u1.y = 0; u1.z = 0; u1.w = 0;
        uint4 z4; z4.x = 0; z4.y = 0; z4.z = 0; z4.w = 0;
        *(uint4*)&feat[wid][lane][32] = u0;
        *(uint4*)&feat[wid][lane][40] = u1;
        *(uint4*)&feat[wid][lane][48] = z4;
        *(uint4*)&feat[wid][lane][56] = z4;
    }
    // FXYZ MFMA -> stage-1 fx in cols 32..63
    {
        bf16x8 xb0 = *(const bf16x8*)&feat[wid][ 0 + c16][32 + g8];
        bf16x8 xb1 = *(const bf16x8*)&feat[wid][16 + c16][32 + g8];
        bf16x8 xb2 = *(const bf16x8*)&feat[wid][32 + c16][32 + g8];
        bf16x8 xb3 = *(const bf16x8*)&feat[wid][48 + c16][32 + g8];
        bf16x8 wa0 = *(const bf16x8*)&w1p[     c16][g8];
        bf16x8 wa1 = *(const bf16x8*)&w1p[16 + c16][g8];
        f32x4 bi0 = *(const f32x4*)&bb_b1[g4];
        f32x4 bi1 = *(const f32x4*)&bb_b1[16 + g4];
        f32x4 f00 = MF(wa0, xb0, bi0);
        f32x4 f01 = MF(wa0, xb1, bi0);
        f32x4 f02 = MF(wa0, xb2, bi0);
        f32x4 f03 = MF(wa0, xb3, bi0);
        f32x4 f10 = MF(wa1, xb0, bi1);
        f32x4 f11 = MF(wa1, xb1, bi1);
        f32x4 f12 = MF(wa1, xb2, bi1);
        f32x4 f13 = MF(wa1, xb3, bi1);
        WBX(0, 0, f00) WBX(0, 1, f01) WBX(0, 2, f02) WBX(0, 3, f03)
        WBX(1, 0, f10) WBX(1, 1, f11) WBX(1, 2, f12) WBX(1, 3, f13)
    }
    // bb_w2 A-fragments (in-register fold)
    union { bf16x8 v; uint4 u; } aw20, aw21;
    {
        int o = c16;
        float sc2 = bb_g2[o] * BN_RS;
        const float* wr = bb_w2 + o * H + g8;
        aw20.u.x = pk2(wr[0] * sc2, wr[1] * sc2);
        aw20.u.y = pk2(wr[2] * sc2, wr[3] * sc2);
        aw20.u.z = pk2(wr[4] * sc2, wr[5] * sc2);
        aw20.u.w = pk2(wr[6] * sc2, wr[7] * sc2);
    }
    {
        int o = 16 + c16;
        float sc2 = bb_g2[o] * BN_RS;
        const float* wr = bb_w2 + o * H + g8;
        aw21.u.x = pk2(wr[0] * sc2, wr[1] * sc2);
        aw21.u.y = pk2(wr[2] * sc2, wr[3] * sc2);
        aw21.u.z = pk2(wr[4] * sc2, wr[5] * sc2);
        aw21.u.w = pk2(wr[6] * sc2, wr[7] * sc2);
    }
    // fx B-frags (read before overwrite), then f_xyz2 = relu(bn(bb_w2 @ fx))
    {
        bf16x8 bfx0 = *(const bf16x8*)&feat[wid][ 0 + c16][32 + g8];
        bf16x8 bfx1 = *(const bf16x8*)&feat[wid][16 + c16][32 + g8];
        bf16x8 bfx2 = *(const bf16x8*)&feat[wid][32 + c16][32 + g8];
        bf16x8 bfx3 = *(const bf16x8*)&feat[wid][48 + c16][32 + g8];
        f32x4 bi0 = *(const f32x4*)&bb_b2[     g4];
        f32x4 bi1 = *(const f32x4*)&bb_b2[16 + g4];
        f32x4 a00 = MF(aw20.v, bfx0, bi0);
        f32x4 a01 = MF(aw20.v, bfx1, bi0);
        f32x4 a02 = MF(aw20.v, bfx2, bi0);
        f32x4 a03 = MF(aw20.v, bfx3, bi0);
        f32x4 a10 = MF(aw21.v, bfx0, bi1);
        f32x4 a11 = MF(aw21.v, bfx1, bi1);
        f32x4 a12 = MF(aw21.v, bfx2, bi1);
        f32x4 a13 = MF(aw21.v, bfx3, bi1);
        WBX(0, 0, a00) WBX(0, 1, a01) WBX(0, 2, a02) WBX(0, 3, a03)
        WBX(1, 0, a10) WBX(1, 1, a11) WBX(1, 2, a12) WBX(1, 3, a13)
    }
    // gathered f_agg neighbor features (ch 0..31)
    *(bf16x8*)&feat[wid][lane][0]  = gv0;
    *(bf16x8*)&feat[wid][lane][8]  = gv1;
    *(bf16x8*)&feat[wid][lane][16] = gv2;
    *(bf16x8*)&feat[wid][lane][24] = gv3;

    bf16x8 afc0_0 = *(const bf16x8*)&fcb[ 0 + c16][     g8];
    bf16x8 afc0_1 = *(const bf16x8*)&fcb[ 0 + c16][32 + g8];
    bf16x8 afc1_0 = *(const bf16x8*)&fcb[16 + c16][     g8];
    bf16x8 afc1_1 = *(const bf16x8*)&fcb[16 + c16][32 + g8];
    bf16x8 afc2_0 = *(const bf16x8*)&fcb[32 + c16][     g8];
    bf16x8 afc2_1 = *(const bf16x8*)&fcb[32 + c16][32 + g8];
    bf16x8 afc3_0 = *(const bf16x8*)&fcb[48 + c16][     g8];
    bf16x8 afc3_1 = *(const bf16x8*)&fcb[48 + c16][32 + g8];

    ATT_NI(0) ATT_NI(1) ATT_NI(2) ATT_NI(3)
    __syncthreads();

    // out-MLP via MFMA: wave wid -> mi; bf16 store
    {
        union { bf16x8 v; uint4 u; } bb0, bb1;
        QFRAG(bb0, 0)
        QFRAG(bb1, 32)
        int o = (wid << 4) + c16;
        float sc = att_g[o] * BN_RS;
        const float* wr0 = att_w + o * D + g8;
        const float* wr1 = att_w + o * D + 32 + g8;
        union { bf16x8 v; uint4 u; } aw0, aw1;
        aw0.u.x = pk2(wr0[0] * sc, wr0[1] * sc);
        aw0.u.y = pk2(wr0[2] * sc, wr0[3] * sc);
        aw0.u.z = pk2(wr0[4] * sc, wr0[5] * sc);
        aw0.u.w = pk2(wr0[6] * sc, wr0[7] * sc);
        aw1.u.x = pk2(wr1[0] * sc, wr1[1] * sc);
        aw1.u.y = pk2(wr1[2] * sc, wr1[3] * sc);
        aw1.u.z = pk2(wr1[4] * sc, wr1[5] * sc);
        aw1.u.w = pk2(wr1[6] * sc, wr1[7] * sc);
        f32x4 acc = *(const f32x4*)&att_b[(wid << 4) + g4];
        acc = MF(aw0.v, bb0.v, acc);
        acc = MF(aw1.v, bb1.v, acc);
        int p = (blockIdx.x << 4) + c16;
        int o0 = (wid << 4) + g4;
        uint2 st;
        st.x = pk2(fmaxf(acc[0], 0.f), fmaxf(acc[1], 0.f));
        st.y = pk2(fmaxf(acc[2], 0.f), fmaxf(acc[3], 0.f));
        *(uint2*)(fagg2b + (((size_t)p) << 6) + o0) = st;
    }
}

// ---------------- Kernel 4: MFMA GEMM out[128 x pts] = Wcat[128x96] @ X[96 x pts] ----------------
__global__ __launch_bounds__(256, 4) void k4_final(
    const ushort* __restrict__ fagg2b, const ushort* __restrict__ featpm,
    const float* __restrict__ w_mlp2, const float* __restrict__ g_mlp2, const float* __restrict__ b_mlp2,
    const float* __restrict__ w_sc, const float* __restrict__ g_sc, const float* __restrict__ b_sc,
    float* __restrict__ out)
{
    int tid = threadIdx.x;
    int wid = tid >> 6, lane = tid & 63;
    int c16 = lane & 15, g = lane >> 4;
    int g4 = g << 2, g8 = g << 3;
    int p0 = blockIdx.x << 6;
    int o0 = wid << 5;

    union { bf16x8 v; uint4 u; } A[2][3];
#pragma unroll
    for (int mi = 0; mi < 2; ++mi) {
        int o = o0 + mi * 16 + c16;
        float sm = g_mlp2[o] * BN_RS, ss = g_sc[o] * BN_RS;
        const float* wm = w_mlp2 + o * D;
        const float* ws = w_sc + o * CIN;
#pragma unroll
        for (int ks = 0; ks < 2; ++ks) {
            float4 wa = *(const float4*)&wm[ks * 32 + g8];
            float4 wb = *(const float4*)&wm[ks * 32 + g8 + 4];
            A[mi][ks].u.x = pk2(wa.x * sm, wa.y * sm);
            A[mi][ks].u.y = pk2(wa.z * sm, wa.w * sm);
            A[mi][ks].u.z = pk2(wb.x * sm, wb.y * sm);
            A[mi][ks].u.w = pk2(wb.z * sm, wb.w * sm);
        }
        float4 wa = *(const float4*)&ws[g8];
        float4 wb = *(const float4*)&ws[g8 + 4];
        A[mi][2].u.x = pk2(wa.x * ss, wa.y * ss);
        A[mi][2].u.y = pk2(wa.z * ss, wa.w * ss);
        A[mi][2].u.z = pk2(wb.x * ss, wb.y * ss);
        A[mi][2].u.w = pk2(wb.z * ss, wb.w * ss);
    }
    float bias0[4], bias1[4];
#pragma unroll
    for (int r = 0; r < 4; ++r) {
        int oa = o0 + g4 + r;
        int ob = o0 + 16 + g4 + r;
        bias0[r] = b_mlp2[oa] + b_sc[oa];
        bias1[r] = b_mlp2[ob] + b_sc[ob];
    }

    int bb = p0 >> 15;
#pragma unroll
    for (int ni = 0; ni < 4; ++ni) {
        int pt = p0 + ni * 16 + c16;
        bf16x8 B0 = *(const bf16x8*)&fagg2b[((size_t)pt << 6) + g8];
        bf16x8 B1 = *(const bf16x8*)&fagg2b[((size_t)pt << 6) + 32 + g8];
        bf16x8 B2 = *(const bf16x8*)&featpm[((size_t)pt << 5) + g8];
        f32x4 acc0 = {bias0[0], bias0[1], bias0[2], bias0[3]};
        f32x4 acc1 = {bias1[0], bias1[1], bias1[2], bias1[3]};
        acc0 = MF(A[0][0].v, B0, acc0);
        acc0 = MF(A[0][1].v, B1, acc0);
        acc0 = MF(A[0][2].v, B2, acc0);
        acc1 = MF(A[1][0].v, B0, acc1);
        acc1 = MF(A[1][1].v, B1, acc1);
        acc1 = MF(A[1][2].v, B2, acc1);
        int nn = pt & (NPTS - 1);
#pragma unroll
        for (int r = 0; r < 4; ++r) {
            float v0 = acc0[r];
            v0 = (v0 >= 0.f) ? v0 : 0.2f * v0;
            out[((bb * DOUT + o0 + g4 + r) << 15) + nn] = v0;
            float v1 = acc1[r];
            v1 = (v1 >= 0.f) ? v1 : 0.2f * v1;
            out[((bb * DOUT + o0 + 16 + g4 + r) << 15) + nn] = v1;
        }
    }
}

extern "C" void kernel_launch(void* const* d_in, const int* in_sizes, int n_in,
                              void* d_out, int out_size, void* d_ws, size_t ws_size,
                              hipStream_t stream) {
    const float* feature = (const float*)d_in[0];
    const float* xyz     = (const float*)d_in[1];
    const float* w_mlp1  = (const float*)d_in[2];
    const float* g_mlp1  = (const float*)d_in[3];
    const float* b_mlp1  = (const float*)d_in[4];
    const float* bb_w1   = (const float*)d_in[5];
    const float* bb_g1   = (const float*)d_in[6];
    const float* bb_b1   = (const float*)d_in[7];
    const float* att1_fc = (const float*)d_in[8];
    const float* att1_w  = (const float*)d_in[9];
    const float* att1_g  = (const float*)d_in[10];
    const float* att1_b  = (const float*)d_in[11];
    const float* bb_w2   = (const float*)d_in[12];
    const float* bb_g2   = (const float*)d_in[13];
    const float* bb_b2   = (const float*)d_in[14];
    const float* att2_fc = (const float*)d_in[15];
    const float* att2_w  = (const float*)d_in[16];
    const float* att2_g  = (const float*)d_in[17];
    const float* att2_b  = (const float*)d_in[18];
    const float* w_mlp2  = (const float*)d_in[19];
    const float* g_mlp2  = (const float*)d_in[20];
    const float* b_mlp2  = (const float*)d_in[21];
    const float* w_sc    = (const float*)d_in[22];
    const float* g_sc    = (const float*)d_in[23];
    const float* b_sc    = (const float*)d_in[24];
    const int*   nidx    = (const int*)d_in[25];
    float* out = (float*)d_out;

    ushort* f_pc_bf  = (ushort*)d_ws;                              // B*N*32 bf16
    ushort* f_agg_bf = f_pc_bf + (size_t)NB * NPTS * 32;           // B*N*32 bf16
    ushort* featpm   = f_agg_bf + (size_t)NB * NPTS * 32;          // B*N*32 bf16
    ushort* fagg2b   = featpm + (size_t)NB * NPTS * 32;            // B*N*64 bf16

    k1_mlp1<<<NB * NPTS / 256, 256, 0, stream>>>(feature, w_mlp1, g_mlp1, b_mlp1,
                                                 f_pc_bf, featpm);
    k2_stage1<<<NB * NPTS / 16, 256, 0, stream>>>(xyz, nidx, f_pc_bf,
                                                  bb_w1, bb_g1, bb_b1,
                                                  att1_fc, att1_w, att1_g, att1_b, f_agg_bf);
    k3_stage2<<<NB * NPTS / 16, 256, 0, stream>>>(xyz, nidx, f_agg_bf,
                                                  bb_w1, bb_g1, bb_b1,
                                                  bb_w2, bb_g2, bb_b2,
                                                  att2_fc, att2_w, att2_g, att2_b, fagg2b);
    k4_final<<<NB * NPTS / 64, 256, 0, stream>>>(fagg2b, featpm,
                                                 w_mlp2, g_mlp2, b_mlp2,
                                                 w_sc, g_sc, b_sc, out);
}